// Round 1
// baseline (1282.546 us; speedup 1.0000x reference)
//
#include <hip/hip_runtime.h>
#include <math.h>

#define B_ 4
#define C_ 128
#define N_ 2048
#define H_ 4
#define K_ 20

// ---- workspace layout (float offsets) ----
#define OFF_Y    0           // [3][B][C][N]  conv output
#define OFF_FT   3145728     // [3][B][N][C]  filtered features, row-major per point
#define OFF_SC   6291456     // [3*B*C] IN scale
#define OFF_SH   6292992     // [3*B*C] IN shift
#define OFF_XX   6294528     // [3*B*N] squared norms
#define OFF_IDX  6319104     // [3*B*N*K] int neighbor indices
#define OFF_P    6810624     // [3][B][N][C]  P = (W1a+W1b)·f
#define OFF_Q    9956352     // [3][B][N][C]  Q = -W1b·f
#define OFF_GT   13102080    // [3][B][N][C]  gcn out (point-major)
#define OFF_G    16247808    // [3][B][C][N]  gcn out (channel-major)
#define OFF_NRM  19393536    // [2*B*C] l2 norms for q,k
#define OFF_ATT  19394560    // [B][H][32][32] softmaxed attention
#define OFF_AV   19410944    // [B][C][N] attention output
#define OFF_PD   20459520    // [N][N] pairwise dist scratch (reused per i,b)
// total = 24,653,824 floats = 98.6 MB

// ---------------- filter: 1x1 conv ----------------
__global__ __launch_bounds__(256) void k_filter_conv(
    const float* __restrict__ x, const float* __restrict__ fW,
    const float* __restrict__ fb, float* __restrict__ y)
{
    __shared__ float Ws[8][C_];
    const int n = blockIdx.x * 256 + threadIdx.x;
    const int o0 = blockIdx.y * 8;
    const int iz = blockIdx.z;                 // i*B + b
    const int i = iz >> 2, b = iz & 3;
    for (int t = threadIdx.x; t < 8 * C_; t += 256) {
        const int j = t >> 7, c = t & 127;
        Ws[j][c] = fW[((size_t)i * C_ + o0 + j) * C_ + c];
    }
    __syncthreads();
    float acc[8] = {};
    const float* xb = x + ((size_t)b * C_) * N_ + n;
    #pragma unroll 4
    for (int c = 0; c < C_; ++c) {
        const float xv = xb[(size_t)c * N_];
        #pragma unroll
        for (int j = 0; j < 8; ++j) acc[j] += Ws[j][c] * xv;
    }
    float* yb = y + ((size_t)iz * C_ + o0) * N_ + n;
    #pragma unroll
    for (int j = 0; j < 8; ++j) yb[(size_t)j * N_] = acc[j] + fb[i * C_ + o0 + j];
}

// ---------------- instance-norm row stats ----------------
__global__ __launch_bounds__(256) void k_rowstats(
    const float* __restrict__ y, const float* __restrict__ fg,
    const float* __restrict__ fbe, float* __restrict__ scale, float* __restrict__ shift)
{
    const int r = blockIdx.x;                  // (i*B+b)*C + o
    const int i = r >> 9, o = r & 127;
    const float* row = y + (size_t)r * N_;
    float s = 0.f, ss = 0.f;
    for (int n = threadIdx.x; n < N_; n += 256) {
        const float v = row[n];
        s += v; ss += v * v;
    }
    #pragma unroll
    for (int off = 32; off > 0; off >>= 1) {
        s += __shfl_down(s, off);
        ss += __shfl_down(ss, off);
    }
    __shared__ float red[2][4];
    const int wid = threadIdx.x >> 6;
    if ((threadIdx.x & 63) == 0) { red[0][wid] = s; red[1][wid] = ss; }
    __syncthreads();
    if (threadIdx.x == 0) {
        s = red[0][0] + red[0][1] + red[0][2] + red[0][3];
        ss = red[1][0] + red[1][1] + red[1][2] + red[1][3];
        const float mean = s * (1.f / N_);
        const float var = ss * (1.f / N_) - mean * mean;
        const float bn = sqrtf(1.00001f);
        const float sc = fg[i * C_ + o] / (bn * sqrtf(var + 1e-3f));
        scale[r] = sc;
        shift[r] = fbe[i * C_ + o] - mean * sc;
    }
}

// ---------------- normalize + relu + transpose to [n][c] ----------------
__global__ __launch_bounds__(256) void k_norm_transpose(
    const float* __restrict__ y, const float* __restrict__ scale,
    const float* __restrict__ shift, float* __restrict__ fT)
{
    __shared__ float tile[32][33];
    const int n0 = blockIdx.x * 32, o0 = blockIdx.y * 32;
    const int iz = blockIdx.z;
    const int tx = threadIdx.x, ty = threadIdx.y;
    #pragma unroll
    for (int q = 0; q < 4; ++q) {
        const int o = o0 + ty + q * 8;
        const int r = iz * C_ + o;
        const float v = y[(size_t)r * N_ + n0 + tx] * scale[r] + shift[r];
        tile[ty + q * 8][tx] = fmaxf(v, 0.f);
    }
    __syncthreads();
    #pragma unroll
    for (int q = 0; q < 4; ++q) {
        const int n = n0 + ty + q * 8;
        fT[((size_t)iz * N_ + n) * C_ + o0 + tx] = tile[tx][ty + q * 8];
    }
}

// ---------------- per-point squared norm ----------------
__global__ __launch_bounds__(256) void k_xx(const float* __restrict__ fT, float* __restrict__ xx)
{
    const int r = blockIdx.x * 256 + threadIdx.x;   // [0, 3*B*N)
    const float4* row = (const float4*)(fT + (size_t)r * C_);
    float s = 0.f;
    #pragma unroll
    for (int q = 0; q < C_ / 4; ++q) {
        const float4 v = row[q];
        s += v.x * v.x + v.y * v.y + v.z * v.z + v.w * v.w;
    }
    xx[r] = s;
}

// ---------------- pairwise -dist^2 GEMM (one i,b) ----------------
__global__ __launch_bounds__(256) void k_pd(
    const float* __restrict__ fTb, const float* __restrict__ xxb, float* __restrict__ pd)
{
    __shared__ float As[64][68], Bs[64][68];   // [k][m], pad keeps 16B align
    const int n0 = blockIdx.x * 64, m0 = blockIdx.y * 64;
    const int tm = threadIdx.x & 15, tn = threadIdx.x >> 4;
    float acc[4][4] = {};
    for (int kc = 0; kc < C_; kc += 64) {
        __syncthreads();
        #pragma unroll
        for (int q = 0; q < 4; ++q) {
            const int id = threadIdx.x + 256 * q;
            const int m = id >> 4, c4 = id & 15;
            const float4 va = *(const float4*)(fTb + ((size_t)(n0 + m)) * C_ + kc + c4 * 4);
            As[c4*4+0][m] = va.x; As[c4*4+1][m] = va.y; As[c4*4+2][m] = va.z; As[c4*4+3][m] = va.w;
            const float4 vb = *(const float4*)(fTb + ((size_t)(m0 + m)) * C_ + kc + c4 * 4);
            Bs[c4*4+0][m] = vb.x; Bs[c4*4+1][m] = vb.y; Bs[c4*4+2][m] = vb.z; Bs[c4*4+3][m] = vb.w;
        }
        __syncthreads();
        #pragma unroll
        for (int k = 0; k < 64; ++k) {
            const float4 a  = *(const float4*)&As[k][tm * 4];
            const float4 bb = *(const float4*)&Bs[k][tn * 4];
            acc[0][0] += a.x*bb.x; acc[0][1] += a.x*bb.y; acc[0][2] += a.x*bb.z; acc[0][3] += a.x*bb.w;
            acc[1][0] += a.y*bb.x; acc[1][1] += a.y*bb.y; acc[1][2] += a.y*bb.z; acc[1][3] += a.y*bb.w;
            acc[2][0] += a.z*bb.x; acc[2][1] += a.z*bb.y; acc[2][2] += a.z*bb.z; acc[2][3] += a.z*bb.w;
            acc[3][0] += a.w*bb.x; acc[3][1] += a.w*bb.y; acc[3][2] += a.w*bb.z; acc[3][3] += a.w*bb.w;
        }
    }
    const float xm0 = xxb[m0 + tn*4 + 0], xm1 = xxb[m0 + tn*4 + 1];
    const float xm2 = xxb[m0 + tn*4 + 2], xm3 = xxb[m0 + tn*4 + 3];
    #pragma unroll
    for (int rr = 0; rr < 4; ++rr) {
        const int n = n0 + tm * 4 + rr;
        const float xn = xxb[n];
        float4 st;
        st.x = 2.f * acc[rr][0] - xn - xm0;
        st.y = 2.f * acc[rr][1] - xn - xm1;
        st.z = 2.f * acc[rr][2] - xn - xm2;
        st.w = 2.f * acc[rr][3] - xn - xm3;
        *(float4*)(pd + (size_t)n * N_ + m0 + tn * 4) = st;
    }
}

// ---------------- top-K=20 per row (one wave per row) ----------------
__global__ __launch_bounds__(256) void k_topk(const float* __restrict__ pd, int* __restrict__ idxb)
{
    const int lane = threadIdx.x & 63;
    const int n = blockIdx.x * 4 + (threadIdx.x >> 6);
    const float* row = pd + (size_t)n * N_;
    float v[32];
    #pragma unroll
    for (int j = 0; j < 32; ++j) v[j] = row[j * 64 + lane];
    for (int it = 0; it < K_; ++it) {
        float best = -3e38f; int bj = 0;
        #pragma unroll
        for (int j = 0; j < 32; ++j) if (v[j] > best) { best = v[j]; bj = j; }
        int bm = bj * 64 + lane;
        #pragma unroll
        for (int off = 1; off < 64; off <<= 1) {
            const float ov = __shfl_xor(best, off);
            const int   om = __shfl_xor(bm, off);
            if (ov > best || (ov == best && om < bm)) { best = ov; bm = om; }
        }
        if (lane == 0) idxb[n * K_ + it] = bm;
        if ((bm & 63) == lane) {
            const int jj = bm >> 6;          // static unroll avoids scratch (rule #20)
            #pragma unroll
            for (int j = 0; j < 32; ++j) if (j == jj) v[j] = -3e38f;
        }
    }
}

// ---------------- P/Q GEMMs: P=(W1a+W1b)·f, Q=(-W1b)·f ----------------
__global__ __launch_bounds__(256) void k_pq(
    const float* __restrict__ fT, const float* __restrict__ gW1,
    float* __restrict__ P, float* __restrict__ Q)
{
    __shared__ float As[64][68], Bs[64][68];
    const int iz = blockIdx.z;
    const int i = iz >> 2;
    const int n0 = blockIdx.x * 64;
    const int yt = blockIdx.y;           // 0,1 -> P cols; 2,3 -> Q cols
    const bool isQ = (yt >= 2);
    const int oc0 = (yt & 1) * 64;
    const float* fTb = fT + (size_t)iz * N_ * C_;
    const int tm = threadIdx.x & 15, tn = threadIdx.x >> 4;
    float acc[4][4] = {};
    for (int kc = 0; kc < C_; kc += 64) {
        __syncthreads();
        #pragma unroll
        for (int q = 0; q < 4; ++q) {
            const int id = threadIdx.x + 256 * q;
            const int m = id >> 4, c4 = id & 15;
            const float4 va = *(const float4*)(fTb + ((size_t)(n0 + m)) * C_ + kc + c4 * 4);
            As[c4*4+0][m] = va.x; As[c4*4+1][m] = va.y; As[c4*4+2][m] = va.z; As[c4*4+3][m] = va.w;
            const float* wrow = gW1 + ((size_t)i * C_ + oc0 + m) * (2 * C_);
            const float4 wa = *(const float4*)(wrow + kc + c4 * 4);
            const float4 wb = *(const float4*)(wrow + C_ + kc + c4 * 4);
            float4 bv;
            if (isQ) { bv.x = -wb.x; bv.y = -wb.y; bv.z = -wb.z; bv.w = -wb.w; }
            else     { bv.x = wa.x + wb.x; bv.y = wa.y + wb.y; bv.z = wa.z + wb.z; bv.w = wa.w + wb.w; }
            Bs[c4*4+0][m] = bv.x; Bs[c4*4+1][m] = bv.y; Bs[c4*4+2][m] = bv.z; Bs[c4*4+3][m] = bv.w;
        }
        __syncthreads();
        #pragma unroll
        for (int k = 0; k < 64; ++k) {
            const float4 a  = *(const float4*)&As[k][tm * 4];
            const float4 bb = *(const float4*)&Bs[k][tn * 4];
            acc[0][0] += a.x*bb.x; acc[0][1] += a.x*bb.y; acc[0][2] += a.x*bb.z; acc[0][3] += a.x*bb.w;
            acc[1][0] += a.y*bb.x; acc[1][1] += a.y*bb.y; acc[1][2] += a.y*bb.z; acc[1][3] += a.y*bb.w;
            acc[2][0] += a.z*bb.x; acc[2][1] += a.z*bb.y; acc[2][2] += a.z*bb.z; acc[2][3] += a.z*bb.w;
            acc[3][0] += a.w*bb.x; acc[3][1] += a.w*bb.y; acc[3][2] += a.w*bb.z; acc[3][3] += a.w*bb.w;
        }
    }
    float* out = (isQ ? Q : P) + (size_t)iz * N_ * C_;
    #pragma unroll
    for (int rr = 0; rr < 4; ++rr) {
        const float4 st = make_float4(acc[rr][0], acc[rr][1], acc[rr][2], acc[rr][3]);
        *(float4*)(out + ((size_t)(n0 + tm * 4 + rr)) * C_ + oc0 + tn * 4) = st;
    }
}

// ---------------- edge conv2 + max over k (2 points per block) ----------------
__global__ __launch_bounds__(256) void k_conv2max(
    const float* __restrict__ P, const float* __restrict__ Q, const int* __restrict__ idxb,
    const float* __restrict__ gb1, const float* __restrict__ gg1, const float* __restrict__ gbe1,
    const float* __restrict__ gW2, const float* __restrict__ gb2, const float* __restrict__ gg2,
    const float* __restrict__ gbe2, float* __restrict__ gT)
{
    __shared__ float h1s[40][C_];     // h1 rows for 2 points x 20 nbrs
    __shared__ float Ws[64][C_];      // W2 K-chunk, [c][o] so o is bank-fast
    __shared__ float s1s[C_], t1s[C_], s2s[C_], t2s[C_];
    __shared__ float red[2][C_][2];
    const int i = blockIdx.z, b = blockIdx.y;
    const int p0 = blockIdx.x * 2;
    const int t = threadIdx.x;
    if (t < C_) {
        const float bn = sqrtf(1.00001f);
        const float g1 = gg1[i * C_ + t];
        s1s[t] = g1 / bn;
        t1s[t] = gb1[i * C_ + t] * (g1 / bn) + gbe1[i * C_ + t];
        const float g2 = gg2[i * C_ + t];
        s2s[t] = g2 / bn;
        t2s[t] = gb2[i * C_ + t] * (g2 / bn) + gbe2[i * C_ + t];
    }
    __syncthreads();
    {   // build h1 = relu((P[n]+Q[idx])*s1 + t1)
        const int o = t & 127, half = t >> 7;
        const size_t base = (size_t)(i * B_ + b) * N_;
        const float* Pb = P + base * C_;
        const float* Qb = Q + base * C_;
        const int* idp = idxb + base * K_;
        const float s1o = s1s[o], t1o = t1s[o];
        for (int rr = half; rr < 40; rr += 2) {
            const int pt = rr / 20, j = rr % 20;
            const int n = p0 + pt;
            const int m = idp[n * K_ + j];
            const float val = Pb[(size_t)n * C_ + o] + Qb[(size_t)m * C_ + o];
            h1s[rr][o] = fmaxf(val * s1o + t1o, 0.f);
        }
    }
    const int op = t & 63;            // thread owns outputs op and op+64
    const int pt = (t >> 6) & 1;
    const int jh = t >> 7;
    const int ro = pt * 20 + jh * 10;
    float acc[10][2] = {};
    for (int kc = 0; kc < C_; kc += 64) {
        __syncthreads();
        #pragma unroll
        for (int q = 0; q < 8; ++q) {
            const int id = t + 256 * q;
            const int oo = id & 127, cq = id >> 7;
            const float4 wv = *(const float4*)(gW2 + ((size_t)i * C_ + oo) * C_ + kc + cq * 4);
            Ws[cq*4+0][oo] = wv.x; Ws[cq*4+1][oo] = wv.y; Ws[cq*4+2][oo] = wv.z; Ws[cq*4+3][oo] = wv.w;
        }
        __syncthreads();
        #pragma unroll 4
        for (int c4 = 0; c4 < 16; ++c4) {
            const float w00 = Ws[c4*4+0][op],    w01 = Ws[c4*4+1][op],    w02 = Ws[c4*4+2][op],    w03 = Ws[c4*4+3][op];
            const float w10 = Ws[c4*4+0][op+64], w11 = Ws[c4*4+1][op+64], w12 = Ws[c4*4+2][op+64], w13 = Ws[c4*4+3][op+64];
            #pragma unroll
            for (int j = 0; j < 10; ++j) {
                const float4 a = *(const float4*)&h1s[ro + j][kc + c4 * 4];
                acc[j][0] += a.x*w00 + a.y*w01 + a.z*w02 + a.w*w03;
                acc[j][1] += a.x*w10 + a.y*w11 + a.z*w12 + a.w*w13;
            }
        }
    }
    const float s2a = s2s[op], t2a = t2s[op], s2b = s2s[op+64], t2b = t2s[op+64];
    float mx0 = 0.f, mx1 = 0.f;       // relu floor
    #pragma unroll
    for (int j = 0; j < 10; ++j) {
        mx0 = fmaxf(mx0, acc[j][0] * s2a + t2a);
        mx1 = fmaxf(mx1, acc[j][1] * s2b + t2b);
    }
    red[pt][op][jh] = mx0;
    red[pt][op + 64][jh] = mx1;
    __syncthreads();
    if (jh == 0) {
        const float v0 = fmaxf(red[pt][op][0], red[pt][op][1]);
        const float v1 = fmaxf(red[pt][op + 64][0], red[pt][op + 64][1]);
        float* gp = gT + ((size_t)(i * B_ + b) * N_ + p0 + pt) * C_;
        gp[op] = v0;
        gp[op + 64] = v1;
    }
}

// ---------------- transpose gT [n][c] -> g [c][n] ----------------
__global__ __launch_bounds__(256) void k_transpose2(
    const float* __restrict__ gT, float* __restrict__ g)
{
    __shared__ float tile[32][33];
    const int n0 = blockIdx.x * 32, o0 = blockIdx.y * 32;
    const int iz = blockIdx.z;
    const int tx = threadIdx.x, ty = threadIdx.y;
    #pragma unroll
    for (int q = 0; q < 4; ++q) {
        const int n = n0 + ty + q * 8;
        tile[ty + q * 8][tx] = gT[((size_t)iz * N_ + n) * C_ + o0 + tx];
    }
    __syncthreads();
    #pragma unroll
    for (int q = 0; q < 4; ++q) {
        const int o = o0 + ty + q * 8;
        g[((size_t)iz * C_ + o) * N_ + n0 + tx] = tile[tx][ty + q * 8];
    }
}

// ---------------- l2 norms over N for q,k branches ----------------
__global__ __launch_bounds__(256) void k_l2norm(const float* __restrict__ g, float* __restrict__ norms)
{
    const int r = blockIdx.x;       // [0, 2*B*C)
    const float* row = g + (size_t)r * N_;
    float s = 0.f;
    for (int n = threadIdx.x; n < N_; n += 256) { const float v = row[n]; s += v * v; }
    #pragma unroll
    for (int off = 32; off > 0; off >>= 1) s += __shfl_down(s, off);
    __shared__ float red[4];
    if ((threadIdx.x & 63) == 0) red[threadIdx.x >> 6] = s;
    __syncthreads();
    if (threadIdx.x == 0)
        norms[r] = fmaxf(sqrtf(red[0] + red[1] + red[2] + red[3]), 1e-12f);
}

// ---------------- attention scores + softmax (one q-row per block) ----------------
__global__ __launch_bounds__(256) void k_attn(
    const float* __restrict__ g, const float* __restrict__ norms,
    const float* __restrict__ temp, float* __restrict__ attn)
{
    __shared__ float qs[N_];
    __shared__ float rowv[32];
    const int r = blockIdx.x;                 // b*128 + h*32 + c
    const int c = r & 31, h = (r >> 5) & 3, b = r >> 7;
    const float* qrow  = g + ((size_t)(0 * B_ + b) * C_ + h * 32 + c) * N_;
    const float* krows = g + ((size_t)(1 * B_ + b) * C_ + h * 32) * N_;
    for (int n = threadIdx.x; n < N_; n += 256) qs[n] = qrow[n];
    __syncthreads();
    const int d = threadIdx.x >> 3, s = threadIdx.x & 7;
    const float* kr = krows + (size_t)d * N_;
    float acc = 0.f;
    for (int m = 0; m < N_ / 32; ++m) {
        const int n = (m * 8 + s) * 4;
        const float4 kv = *(const float4*)(kr + n);
        acc += qs[n] * kv.x + qs[n+1] * kv.y + qs[n+2] * kv.z + qs[n+3] * kv.w;
    }
    #pragma unroll
    for (int off = 1; off < 8; off <<= 1) acc += __shfl_xor(acc, off);
    if (s == 0) rowv[d] = acc;
    __syncthreads();
    if (threadIdx.x < 32) {
        const int dd = threadIdx.x;
        const float nq = norms[(size_t)(0 * B_ + b) * C_ + h * 32 + c];
        const float nk = norms[(size_t)(1 * B_ + b) * C_ + h * 32 + dd];
        const float v = rowv[dd] / (nq * nk) * temp[h];
        float mx = v;
        #pragma unroll
        for (int off = 1; off < 32; off <<= 1) mx = fmaxf(mx, __shfl_xor(mx, off));
        const float e = expf(v - mx);
        float sm = e;
        #pragma unroll
        for (int off = 1; off < 32; off <<= 1) sm += __shfl_xor(sm, off);
        attn[(size_t)r * 32 + dd] = e / sm;
    }
}

// ---------------- attn @ v ----------------
__global__ __launch_bounds__(256) void k_av(
    const float* __restrict__ attn, const float* __restrict__ g, float* __restrict__ av)
{
    __shared__ float at[32][32];
    const int n = blockIdx.x * 256 + threadIdx.x;
    const int h = blockIdx.y, b = blockIdx.z;
    for (int t2 = threadIdx.x; t2 < 1024; t2 += 256)
        at[t2 >> 5][t2 & 31] = attn[((size_t)(b * H_ + h)) * 1024 + t2];
    __syncthreads();
    const float* vrows = g + ((size_t)(2 * B_ + b) * C_ + h * 32) * N_;
    float acc[32] = {};
    for (int dd = 0; dd < 32; ++dd) {
        const float vv = vrows[(size_t)dd * N_ + n];
        #pragma unroll
        for (int cc = 0; cc < 32; ++cc) acc[cc] += at[cc][dd] * vv;
    }
    float* avb = av + ((size_t)b * C_ + h * 32) * N_ + n;
    #pragma unroll
    for (int cc = 0; cc < 32; ++cc) avb[(size_t)cc * N_] = acc[cc];
}

// ---------------- projection + bias + residual ----------------
__global__ __launch_bounds__(256) void k_proj(
    const float* __restrict__ av, const float* __restrict__ pW, const float* __restrict__ pb,
    const float* __restrict__ x, float* __restrict__ out)
{
    __shared__ float Ws[8][C_];
    const int n = blockIdx.x * 256 + threadIdx.x;
    const int o0 = blockIdx.y * 8;
    const int b = blockIdx.z;
    for (int t = threadIdx.x; t < 8 * C_; t += 256) {
        const int j = t >> 7, c = t & 127;
        Ws[j][c] = pW[(size_t)(o0 + j) * C_ + c];
    }
    __syncthreads();
    float acc[8] = {};
    const float* ab = av + ((size_t)b * C_) * N_ + n;
    #pragma unroll 4
    for (int c = 0; c < C_; ++c) {
        const float vv = ab[(size_t)c * N_];
        #pragma unroll
        for (int j = 0; j < 8; ++j) acc[j] += Ws[j][c] * vv;
    }
    #pragma unroll
    for (int j = 0; j < 8; ++j) {
        const int o = o0 + j;
        const size_t off = ((size_t)b * C_ + o) * N_ + n;
        out[off] = acc[j] + pb[o] + x[off];
    }
}

extern "C" void kernel_launch(void* const* d_in, const int* in_sizes, int n_in,
                              void* d_out, int out_size, void* d_ws, size_t ws_size,
                              hipStream_t stream)
{
    const float* x    = (const float*)d_in[0];
    const float* fW   = (const float*)d_in[1];
    const float* fb   = (const float*)d_in[2];
    const float* fg   = (const float*)d_in[3];
    const float* fbe  = (const float*)d_in[4];
    const float* gW1  = (const float*)d_in[5];
    const float* gb1  = (const float*)d_in[6];
    const float* gg1  = (const float*)d_in[7];
    const float* gbe1 = (const float*)d_in[8];
    const float* gW2  = (const float*)d_in[9];
    const float* gb2  = (const float*)d_in[10];
    const float* gg2  = (const float*)d_in[11];
    const float* gbe2 = (const float*)d_in[12];
    const float* pW   = (const float*)d_in[13];
    const float* pb   = (const float*)d_in[14];
    const float* temp = (const float*)d_in[15];
    float* ws = (float*)d_ws;

    float* y    = ws + OFF_Y;
    float* fT   = ws + OFF_FT;
    float* sc   = ws + OFF_SC;
    float* sh   = ws + OFF_SH;
    float* xx   = ws + OFF_XX;
    int*   idxb = (int*)(ws + OFF_IDX);
    float* P    = ws + OFF_P;
    float* Q    = ws + OFF_Q;
    float* gT   = ws + OFF_GT;
    float* g    = ws + OFF_G;
    float* nrm  = ws + OFF_NRM;
    float* attn = ws + OFF_ATT;
    float* av   = ws + OFF_AV;
    float* pd   = ws + OFF_PD;

    k_filter_conv<<<dim3(N_/256, C_/8, 12), 256, 0, stream>>>(x, fW, fb, y);
    k_rowstats<<<12 * C_, 256, 0, stream>>>(y, fg, fbe, sc, sh);
    k_norm_transpose<<<dim3(N_/32, C_/32, 12), dim3(32, 8), 0, stream>>>(y, sc, sh, fT);
    k_xx<<<(12 * N_) / 256, 256, 0, stream>>>(fT, xx);
    for (int ib = 0; ib < 12; ++ib) {
        k_pd<<<dim3(N_/64, N_/64), 256, 0, stream>>>(fT + (size_t)ib * N_ * C_, xx + ib * N_, pd);
        k_topk<<<N_/4, 256, 0, stream>>>(pd, idxb + (size_t)ib * N_ * K_);
    }
    k_pq<<<dim3(N_/64, 4, 12), 256, 0, stream>>>(fT, gW1, P, Q);
    k_conv2max<<<dim3(N_/2, B_, 3), 256, 0, stream>>>(P, Q, idxb, gb1, gg1, gbe1,
                                                      gW2, gb2, gg2, gbe2, gT);
    k_transpose2<<<dim3(N_/32, C_/32, 12), dim3(32, 8), 0, stream>>>(gT, g);
    k_l2norm<<<2 * B_ * C_, 256, 0, stream>>>(g, nrm);
    k_attn<<<B_ * H_ * 32, 256, 0, stream>>>(g, nrm, temp, attn);
    k_av<<<dim3(N_/256, H_, B_), 256, 0, stream>>>(attn, g, av);
    k_proj<<<dim3(N_/256, C_/8, B_), 256, 0, stream>>>(av, pW, pb, x, (float*)d_out);
    (void)in_sizes; (void)n_in; (void)out_size; (void)ws_size;
}

// Round 3
// 867.109 us; speedup vs baseline: 1.4791x; 1.4791x over previous
//
#include <hip/hip_runtime.h>
#include <math.h>

// Round 2 resubmit: round-1 source unchanged — bench was an infra failure
// (container died twice, no kernel signal). Audit found no OOB/race/LDS issue.

#define B_ 4
#define C_ 128
#define N_ 2048
#define H_ 4
#define K_ 20

typedef __bf16 bf16x8 __attribute__((ext_vector_type(8)));
typedef float f32x4 __attribute__((ext_vector_type(4)));
typedef unsigned int u32x4 __attribute__((ext_vector_type(4)));

__device__ __forceinline__ unsigned short f2bf(float f) {
    unsigned int u = __builtin_bit_cast(unsigned int, f);
    u += 0x7fffu + ((u >> 16) & 1u);       // RNE
    return (unsigned short)(u >> 16);
}
__device__ __forceinline__ float bf2f(unsigned short s) {
    return __builtin_bit_cast(float, (unsigned int)s << 16);
}

// ---- workspace layout (float offsets) ----
#define OFF_Y    0           // [3][B][C][N]  conv output
#define OFF_FT   3145728     // [3][B][N][C]  filtered features, row-major per point
#define OFF_SC   6291456     // [3*B*C] IN scale
#define OFF_SH   6292992     // [3*B*C] IN shift
#define OFF_XX   6294528     // [3*B*N] squared norms
#define OFF_IDX  6319104     // [3*B*N*K] int neighbor indices
#define OFF_P    6810624     // [3][B][N][C]  P = (W1a+W1b)·f
#define OFF_Q    9956352     // [3][B][N][C]  Q = -W1b·f
#define OFF_GT   13102080    // [3][B][N][C]  gcn out (point-major)
#define OFF_G    16247808    // [3][B][C][N]  gcn out (channel-major)
#define OFF_NRM  19393536    // [2*B*C] l2 norms for q,k
#define OFF_ATT  19394560    // [B][H][32][32] softmaxed attention
#define OFF_AV   19410944    // [B][C][N] attention output
#define OFF_PD   20459520    // [N][N] pairwise dist scratch (reused per i,b)
// total = 24,653,824 floats = 98.6 MB

// ---------------- filter: 1x1 conv ----------------
__global__ __launch_bounds__(256) void k_filter_conv(
    const float* __restrict__ x, const float* __restrict__ fW,
    const float* __restrict__ fb, float* __restrict__ y)
{
    __shared__ float Ws[8][C_];
    const int n = blockIdx.x * 256 + threadIdx.x;
    const int o0 = blockIdx.y * 8;
    const int iz = blockIdx.z;                 // i*B + b
    const int i = iz >> 2, b = iz & 3;
    for (int t = threadIdx.x; t < 8 * C_; t += 256) {
        const int j = t >> 7, c = t & 127;
        Ws[j][c] = fW[((size_t)i * C_ + o0 + j) * C_ + c];
    }
    __syncthreads();
    float acc[8] = {};
    const float* xb = x + ((size_t)b * C_) * N_ + n;
    #pragma unroll 4
    for (int c = 0; c < C_; ++c) {
        const float xv = xb[(size_t)c * N_];
        #pragma unroll
        for (int j = 0; j < 8; ++j) acc[j] += Ws[j][c] * xv;
    }
    float* yb = y + ((size_t)iz * C_ + o0) * N_ + n;
    #pragma unroll
    for (int j = 0; j < 8; ++j) yb[(size_t)j * N_] = acc[j] + fb[i * C_ + o0 + j];
}

// ---------------- instance-norm row stats ----------------
__global__ __launch_bounds__(256) void k_rowstats(
    const float* __restrict__ y, const float* __restrict__ fg,
    const float* __restrict__ fbe, float* __restrict__ scale, float* __restrict__ shift)
{
    const int r = blockIdx.x;                  // (i*B+b)*C + o
    const int i = r >> 9, o = r & 127;
    const float* row = y + (size_t)r * N_;
    float s = 0.f, ss = 0.f;
    for (int n = threadIdx.x; n < N_; n += 256) {
        const float v = row[n];
        s += v; ss += v * v;
    }
    #pragma unroll
    for (int off = 32; off > 0; off >>= 1) {
        s += __shfl_down(s, off);
        ss += __shfl_down(ss, off);
    }
    __shared__ float red[2][4];
    const int wid = threadIdx.x >> 6;
    if ((threadIdx.x & 63) == 0) { red[0][wid] = s; red[1][wid] = ss; }
    __syncthreads();
    if (threadIdx.x == 0) {
        s = red[0][0] + red[0][1] + red[0][2] + red[0][3];
        ss = red[1][0] + red[1][1] + red[1][2] + red[1][3];
        const float mean = s * (1.f / N_);
        const float var = ss * (1.f / N_) - mean * mean;
        const float bn = sqrtf(1.00001f);
        const float sc = fg[i * C_ + o] / (bn * sqrtf(var + 1e-3f));
        scale[r] = sc;
        shift[r] = fbe[i * C_ + o] - mean * sc;
    }
}

// ---------------- normalize + relu + transpose to [n][c] ----------------
__global__ __launch_bounds__(256) void k_norm_transpose(
    const float* __restrict__ y, const float* __restrict__ scale,
    const float* __restrict__ shift, float* __restrict__ fT)
{
    __shared__ float tile[32][33];
    const int n0 = blockIdx.x * 32, o0 = blockIdx.y * 32;
    const int iz = blockIdx.z;
    const int tx = threadIdx.x, ty = threadIdx.y;
    #pragma unroll
    for (int q = 0; q < 4; ++q) {
        const int o = o0 + ty + q * 8;
        const int r = iz * C_ + o;
        const float v = y[(size_t)r * N_ + n0 + tx] * scale[r] + shift[r];
        tile[ty + q * 8][tx] = fmaxf(v, 0.f);
    }
    __syncthreads();
    #pragma unroll
    for (int q = 0; q < 4; ++q) {
        const int n = n0 + ty + q * 8;
        fT[((size_t)iz * N_ + n) * C_ + o0 + tx] = tile[tx][ty + q * 8];
    }
}

// ---------------- per-point squared norm ----------------
__global__ __launch_bounds__(256) void k_xx(const float* __restrict__ fT, float* __restrict__ xx)
{
    const int r = blockIdx.x * 256 + threadIdx.x;   // [0, 3*B*N)
    const float4* row = (const float4*)(fT + (size_t)r * C_);
    float s = 0.f;
    #pragma unroll
    for (int q = 0; q < C_ / 4; ++q) {
        const float4 v = row[q];
        s += v.x * v.x + v.y * v.y + v.z * v.z + v.w * v.w;
    }
    xx[r] = s;
}

// ---------------- pairwise -dist^2 GEMM (one i,b) ----------------
__global__ __launch_bounds__(256) void k_pd(
    const float* __restrict__ fTb, const float* __restrict__ xxb, float* __restrict__ pd)
{
    __shared__ float As[64][68], Bs[64][68];   // [k][m], pad keeps 16B align
    const int n0 = blockIdx.x * 64, m0 = blockIdx.y * 64;
    const int tm = threadIdx.x & 15, tn = threadIdx.x >> 4;
    float acc[4][4] = {};
    for (int kc = 0; kc < C_; kc += 64) {
        __syncthreads();
        #pragma unroll
        for (int q = 0; q < 4; ++q) {
            const int id = threadIdx.x + 256 * q;
            const int m = id >> 4, c4 = id & 15;
            const float4 va = *(const float4*)(fTb + ((size_t)(n0 + m)) * C_ + kc + c4 * 4);
            As[c4*4+0][m] = va.x; As[c4*4+1][m] = va.y; As[c4*4+2][m] = va.z; As[c4*4+3][m] = va.w;
            const float4 vb = *(const float4*)(fTb + ((size_t)(m0 + m)) * C_ + kc + c4 * 4);
            Bs[c4*4+0][m] = vb.x; Bs[c4*4+1][m] = vb.y; Bs[c4*4+2][m] = vb.z; Bs[c4*4+3][m] = vb.w;
        }
        __syncthreads();
        #pragma unroll
        for (int k = 0; k < 64; ++k) {
            const float4 a  = *(const float4*)&As[k][tm * 4];
            const float4 bb = *(const float4*)&Bs[k][tn * 4];
            acc[0][0] += a.x*bb.x; acc[0][1] += a.x*bb.y; acc[0][2] += a.x*bb.z; acc[0][3] += a.x*bb.w;
            acc[1][0] += a.y*bb.x; acc[1][1] += a.y*bb.y; acc[1][2] += a.y*bb.z; acc[1][3] += a.y*bb.w;
            acc[2][0] += a.z*bb.x; acc[2][1] += a.z*bb.y; acc[2][2] += a.z*bb.z; acc[2][3] += a.z*bb.w;
            acc[3][0] += a.w*bb.x; acc[3][1] += a.w*bb.y; acc[3][2] += a.w*bb.z; acc[3][3] += a.w*bb.w;
        }
    }
    const float xm0 = xxb[m0 + tn*4 + 0], xm1 = xxb[m0 + tn*4 + 1];
    const float xm2 = xxb[m0 + tn*4 + 2], xm3 = xxb[m0 + tn*4 + 3];
    #pragma unroll
    for (int rr = 0; rr < 4; ++rr) {
        const int n = n0 + tm * 4 + rr;
        const float xn = xxb[n];
        float4 st;
        st.x = 2.f * acc[rr][0] - xn - xm0;
        st.y = 2.f * acc[rr][1] - xn - xm1;
        st.z = 2.f * acc[rr][2] - xn - xm2;
        st.w = 2.f * acc[rr][3] - xn - xm3;
        *(float4*)(pd + (size_t)n * N_ + m0 + tn * 4) = st;
    }
}

// ---------------- top-K=20 per row (one wave per row) ----------------
__global__ __launch_bounds__(256) void k_topk(const float* __restrict__ pd, int* __restrict__ idxb)
{
    const int lane = threadIdx.x & 63;
    const int n = blockIdx.x * 4 + (threadIdx.x >> 6);
    const float* row = pd + (size_t)n * N_;
    float v[32];
    #pragma unroll
    for (int j = 0; j < 32; ++j) v[j] = row[j * 64 + lane];
    for (int it = 0; it < K_; ++it) {
        float best = -3e38f; int bj = 0;
        #pragma unroll
        for (int j = 0; j < 32; ++j) if (v[j] > best) { best = v[j]; bj = j; }
        int bm = bj * 64 + lane;
        #pragma unroll
        for (int off = 1; off < 64; off <<= 1) {
            const float ov = __shfl_xor(best, off);
            const int   om = __shfl_xor(bm, off);
            if (ov > best || (ov == best && om < bm)) { best = ov; bm = om; }
        }
        if (lane == 0) idxb[n * K_ + it] = bm;
        if ((bm & 63) == lane) {
            const int jj = bm >> 6;          // static unroll avoids scratch (rule #20)
            #pragma unroll
            for (int j = 0; j < 32; ++j) if (j == jj) v[j] = -3e38f;
        }
    }
}

// ---------------- P/Q GEMMs: P=(W1a+W1b)·f, Q=(-W1b)·f ----------------
__global__ __launch_bounds__(256) void k_pq(
    const float* __restrict__ fT, const float* __restrict__ gW1,
    float* __restrict__ P, float* __restrict__ Q)
{
    __shared__ float As[64][68], Bs[64][68];
    const int iz = blockIdx.z;
    const int i = iz >> 2;
    const int n0 = blockIdx.x * 64;
    const int yt = blockIdx.y;           // 0,1 -> P cols; 2,3 -> Q cols
    const bool isQ = (yt >= 2);
    const int oc0 = (yt & 1) * 64;
    const float* fTb = fT + (size_t)iz * N_ * C_;
    const int tm = threadIdx.x & 15, tn = threadIdx.x >> 4;
    float acc[4][4] = {};
    for (int kc = 0; kc < C_; kc += 64) {
        __syncthreads();
        #pragma unroll
        for (int q = 0; q < 4; ++q) {
            const int id = threadIdx.x + 256 * q;
            const int m = id >> 4, c4 = id & 15;
            const float4 va = *(const float4*)(fTb + ((size_t)(n0 + m)) * C_ + kc + c4 * 4);
            As[c4*4+0][m] = va.x; As[c4*4+1][m] = va.y; As[c4*4+2][m] = va.z; As[c4*4+3][m] = va.w;
            const float* wrow = gW1 + ((size_t)i * C_ + oc0 + m) * (2 * C_);
            const float4 wa = *(const float4*)(wrow + kc + c4 * 4);
            const float4 wb = *(const float4*)(wrow + C_ + kc + c4 * 4);
            float4 bv;
            if (isQ) { bv.x = -wb.x; bv.y = -wb.y; bv.z = -wb.z; bv.w = -wb.w; }
            else     { bv.x = wa.x + wb.x; bv.y = wa.y + wb.y; bv.z = wa.z + wb.z; bv.w = wa.w + wb.w; }
            Bs[c4*4+0][m] = bv.x; Bs[c4*4+1][m] = bv.y; Bs[c4*4+2][m] = bv.z; Bs[c4*4+3][m] = bv.w;
        }
        __syncthreads();
        #pragma unroll
        for (int k = 0; k < 64; ++k) {
            const float4 a  = *(const float4*)&As[k][tm * 4];
            const float4 bb = *(const float4*)&Bs[k][tn * 4];
            acc[0][0] += a.x*bb.x; acc[0][1] += a.x*bb.y; acc[0][2] += a.x*bb.z; acc[0][3] += a.x*bb.w;
            acc[1][0] += a.y*bb.x; acc[1][1] += a.y*bb.y; acc[1][2] += a.y*bb.z; acc[1][3] += a.y*bb.w;
            acc[2][0] += a.z*bb.x; acc[2][1] += a.z*bb.y; acc[2][2] += a.z*bb.z; acc[2][3] += a.z*bb.w;
            acc[3][0] += a.w*bb.x; acc[3][1] += a.w*bb.y; acc[3][2] += a.w*bb.z; acc[3][3] += a.w*bb.w;
        }
    }
    float* out = (isQ ? Q : P) + (size_t)iz * N_ * C_;
    #pragma unroll
    for (int rr = 0; rr < 4; ++rr) {
        const float4 st = make_float4(acc[rr][0], acc[rr][1], acc[rr][2], acc[rr][3]);
        *(float4*)(out + ((size_t)(n0 + tm * 4 + rr)) * C_ + oc0 + tn * 4) = st;
    }
}

// ---------------- edge conv2 + max over k : bf16 MFMA version ----------------
// 8 points/block, 160 h1 rows, 4 waves; wave w owns output cols [w*32, w*32+32).
// h1s / W2s are bf16 in LDS with T2 XOR swizzle (byte ^= (row&7)<<4).
__global__ __launch_bounds__(256) void k_edge2(
    const float* __restrict__ P, const float* __restrict__ Q, const int* __restrict__ idxb,
    const float* __restrict__ gb1, const float* __restrict__ gg1, const float* __restrict__ gbe1,
    const float* __restrict__ gW2, const float* __restrict__ gb2, const float* __restrict__ gg2,
    const float* __restrict__ gbe2, float* __restrict__ gT)
{
    __shared__ __align__(16) unsigned short h1s[160 * C_];  // 40 KB
    __shared__ __align__(16) unsigned short W2s[C_ * C_];   // 32 KB
    __shared__ float s1s[C_], t1s[C_], s2s[C_], t2s[C_];
    __shared__ int idxs[160];
    const int i = blockIdx.z, b = blockIdx.y;
    const int p0 = blockIdx.x * 8;
    const int t = threadIdx.x;
    const size_t base = (size_t)(i * B_ + b) * N_;

    if (t < C_) {
        const float bn = sqrtf(1.00001f);
        const float g1 = gg1[i * C_ + t];
        s1s[t] = g1 / bn;
        t1s[t] = gb1[i * C_ + t] * (g1 / bn) + gbe1[i * C_ + t];
        const float g2 = gg2[i * C_ + t];
        s2s[t] = g2 / bn;
        t2s[t] = gb2[i * C_ + t] * (g2 / bn) + gbe2[i * C_ + t];
    }
    if (t < 160) idxs[t] = idxb[base * K_ + p0 * K_ + t];
    __syncthreads();

    const int seg = t & 7;            // fixed 16-element column segment per thread
    const int rb = t >> 3;            // base row / base o
    float4 s1v[4], t1v[4];
    #pragma unroll
    for (int q = 0; q < 4; ++q) {
        s1v[q] = *(const float4*)&s1s[seg * 16 + q * 4];
        t1v[q] = *(const float4*)&t1s[seg * 16 + q * 4];
    }
    // ---- build h1 (bf16, swizzled) ----
    const float* Pb = P + base * C_;
    const float* Qb = Q + base * C_;
    #pragma unroll
    for (int it = 0; it < 5; ++it) {
        const int row = rb + 32 * it;
        const int p = row / 20;
        const int m = idxs[row];
        const float* Pr = Pb + (size_t)(p0 + p) * C_ + seg * 16;
        const float* Qr = Qb + (size_t)m * C_ + seg * 16;
        unsigned int pk[8];
        #pragma unroll
        for (int q = 0; q < 4; ++q) {
            const float4 pv = *(const float4*)(Pr + q * 4);
            const float4 qv = *(const float4*)(Qr + q * 4);
            const float r0 = fmaxf((pv.x + qv.x) * s1v[q].x + t1v[q].x, 0.f);
            const float r1 = fmaxf((pv.y + qv.y) * s1v[q].y + t1v[q].y, 0.f);
            const float r2 = fmaxf((pv.z + qv.z) * s1v[q].z + t1v[q].z, 0.f);
            const float r3 = fmaxf((pv.w + qv.w) * s1v[q].w + t1v[q].w, 0.f);
            pk[q * 2 + 0] = (unsigned int)f2bf(r0) | ((unsigned int)f2bf(r1) << 16);
            pk[q * 2 + 1] = (unsigned int)f2bf(r2) | ((unsigned int)f2bf(r3) << 16);
        }
        const int sw = (row & 7) << 4;
        char* bp = (char*)h1s + row * 256;
        *(u32x4*)(bp + ((seg * 32) ^ sw))      = (u32x4){pk[0], pk[1], pk[2], pk[3]};
        *(u32x4*)(bp + ((seg * 32 + 16) ^ sw)) = (u32x4){pk[4], pk[5], pk[6], pk[7]};
    }
    // ---- stage W2 (bf16, swizzled) ----
    #pragma unroll
    for (int it = 0; it < 4; ++it) {
        const int o = rb + 32 * it;
        const float* wr = gW2 + ((size_t)i * C_ + o) * C_ + seg * 16;
        unsigned int pk[8];
        #pragma unroll
        for (int q = 0; q < 4; ++q) {
            const float4 wv = *(const float4*)(wr + q * 4);
            pk[q * 2 + 0] = (unsigned int)f2bf(wv.x) | ((unsigned int)f2bf(wv.y) << 16);
            pk[q * 2 + 1] = (unsigned int)f2bf(wv.z) | ((unsigned int)f2bf(wv.w) << 16);
        }
        const int sw = (o & 7) << 4;
        char* bp = (char*)W2s + o * 256;
        *(u32x4*)(bp + ((seg * 32) ^ sw))      = (u32x4){pk[0], pk[1], pk[2], pk[3]};
        *(u32x4*)(bp + ((seg * 32 + 16) ^ sw)) = (u32x4){pk[4], pk[5], pk[6], pk[7]};
    }
    __syncthreads();

    // ---- MFMA: D[row][o] = sum_c h1[row][c] * W2[o][c] ----
    const int lane = t & 63, w = t >> 6;
    const int lr = lane & 15, lg = lane >> 4;
    bf16x8 Bf[2][4];
    #pragma unroll
    for (int nb = 0; nb < 2; ++nb)
        #pragma unroll
        for (int ks = 0; ks < 4; ++ks) {
            const int o = w * 32 + nb * 16 + lr;
            const int cb = ks * 64 + lg * 16;          // byte col
            Bf[nb][ks] = __builtin_bit_cast(bf16x8,
                *(const u32x4*)((const char*)W2s + o * 256 + (cb ^ ((o & 7) << 4))));
        }
    f32x4 acc[10][2];
    #pragma unroll
    for (int mt = 0; mt < 10; ++mt)
        #pragma unroll
        for (int nb = 0; nb < 2; ++nb)
            acc[mt][nb] = (f32x4){0.f, 0.f, 0.f, 0.f};
    #pragma unroll
    for (int mt = 0; mt < 10; ++mt) {
        bf16x8 Af[4];
        #pragma unroll
        for (int ks = 0; ks < 4; ++ks) {
            const int row = mt * 16 + lr;
            const int cb = ks * 64 + lg * 16;
            Af[ks] = __builtin_bit_cast(bf16x8,
                *(const u32x4*)((const char*)h1s + row * 256 + (cb ^ ((row & 7) << 4))));
        }
        #pragma unroll
        for (int nb = 0; nb < 2; ++nb)
            #pragma unroll
            for (int ks = 0; ks < 4; ++ks)
                acc[mt][nb] = __builtin_amdgcn_mfma_f32_16x16x32_bf16(
                    Af[ks], Bf[nb][ks], acc[mt][nb], 0, 0, 0);
    }
    __syncthreads();   // all waves done reading h1s

    // ---- epilogue: scale+shift+relu, store h2 bf16 into h1s region ----
    #pragma unroll
    for (int mt = 0; mt < 10; ++mt)
        #pragma unroll
        for (int nb = 0; nb < 2; ++nb) {
            const int col = w * 32 + nb * 16 + lr;
            const float s2c = s2s[col], t2c = t2s[col];
            #pragma unroll
            for (int r = 0; r < 4; ++r) {
                const int row = mt * 16 + lg * 4 + r;
                const float v = fmaxf(acc[mt][nb][r] * s2c + t2c, 0.f);
                *(unsigned short*)((char*)h1s + row * 256 + ((col * 2) ^ ((row & 7) << 4))) = f2bf(v);
            }
        }
    __syncthreads();

    // ---- max over 20 neighbors per point ----
    const int oc = t & 127, ph = t >> 7;
    float* gp = gT + (base + p0) * C_;
    #pragma unroll
    for (int pp = 0; pp < 4; ++pp) {
        const int p = ph * 4 + pp;
        float mx = 0.f;
        #pragma unroll
        for (int j = 0; j < 20; ++j) {
            const int row = p * 20 + j;
            const unsigned short us =
                *(const unsigned short*)((const char*)h1s + row * 256 + ((oc * 2) ^ ((row & 7) << 4)));
            mx = fmaxf(mx, bf2f(us));
        }
        gp[(size_t)p * C_ + oc] = mx;
    }
}

// ---------------- transpose gT [n][c] -> g [c][n] ----------------
__global__ __launch_bounds__(256) void k_transpose2(
    const float* __restrict__ gT, float* __restrict__ g)
{
    __shared__ float tile[32][33];
    const int n0 = blockIdx.x * 32, o0 = blockIdx.y * 32;
    const int iz = blockIdx.z;
    const int tx = threadIdx.x, ty = threadIdx.y;
    #pragma unroll
    for (int q = 0; q < 4; ++q) {
        const int n = n0 + ty + q * 8;
        tile[ty + q * 8][tx] = gT[((size_t)iz * N_ + n) * C_ + o0 + tx];
    }
    __syncthreads();
    #pragma unroll
    for (int q = 0; q < 4; ++q) {
        const int o = o0 + ty + q * 8;
        g[((size_t)iz * C_ + o) * N_ + n0 + tx] = tile[tx][ty + q * 8];
    }
}

// ---------------- l2 norms over N for q,k branches ----------------
__global__ __launch_bounds__(256) void k_l2norm(const float* __restrict__ g, float* __restrict__ norms)
{
    const int r = blockIdx.x;       // [0, 2*B*C)
    const float* row = g + (size_t)r * N_;
    float s = 0.f;
    for (int n = threadIdx.x; n < N_; n += 256) { const float v = row[n]; s += v * v; }
    #pragma unroll
    for (int off = 32; off > 0; off >>= 1) s += __shfl_down(s, off);
    __shared__ float red[4];
    if ((threadIdx.x & 63) == 0) red[threadIdx.x >> 6] = s;
    __syncthreads();
    if (threadIdx.x == 0)
        norms[r] = fmaxf(sqrtf(red[0] + red[1] + red[2] + red[3]), 1e-12f);
}

// ---------------- attention scores + softmax (one q-row per block) ----------------
__global__ __launch_bounds__(256) void k_attn(
    const float* __restrict__ g, const float* __restrict__ norms,
    const float* __restrict__ temp, float* __restrict__ attn)
{
    __shared__ float qs[N_];
    __shared__ float rowv[32];
    const int r = blockIdx.x;                 // b*128 + h*32 + c
    const int c = r & 31, h = (r >> 5) & 3, b = r >> 7;
    const float* qrow  = g + ((size_t)(0 * B_ + b) * C_ + h * 32 + c) * N_;
    const float* krows = g + ((size_t)(1 * B_ + b) * C_ + h * 32) * N_;
    for (int n = threadIdx.x; n < N_; n += 256) qs[n] = qrow[n];
    __syncthreads();
    const int d = threadIdx.x >> 3, s = threadIdx.x & 7;
    const float* kr = krows + (size_t)d * N_;
    float acc = 0.f;
    for (int m = 0; m < N_ / 32; ++m) {
        const int n = (m * 8 + s) * 4;
        const float4 kv = *(const float4*)(kr + n);
        acc += qs[n] * kv.x + qs[n+1] * kv.y + qs[n+2] * kv.z + qs[n+3] * kv.w;
    }
    #pragma unroll
    for (int off = 1; off < 8; off <<= 1) acc += __shfl_xor(acc, off);
    if (s == 0) rowv[d] = acc;
    __syncthreads();
    if (threadIdx.x < 32) {
        const int dd = threadIdx.x;
        const float nq = norms[(size_t)(0 * B_ + b) * C_ + h * 32 + c];
        const float nk = norms[(size_t)(1 * B_ + b) * C_ + h * 32 + dd];
        const float v = rowv[dd] / (nq * nk) * temp[h];
        float mx = v;
        #pragma unroll
        for (int off = 1; off < 32; off <<= 1) mx = fmaxf(mx, __shfl_xor(mx, off));
        const float e = expf(v - mx);
        float sm = e;
        #pragma unroll
        for (int off = 1; off < 32; off <<= 1) sm += __shfl_xor(sm, off);
        attn[(size_t)r * 32 + dd] = e / sm;
    }
}

// ---------------- attn @ v ----------------
__global__ __launch_bounds__(256) void k_av(
    const float* __restrict__ attn, const float* __restrict__ g, float* __restrict__ av)
{
    __shared__ float at[32][32];
    const int n = blockIdx.x * 256 + threadIdx.x;
    const int h = blockIdx.y, b = blockIdx.z;
    for (int t2 = threadIdx.x; t2 < 1024; t2 += 256)
        at[t2 >> 5][t2 & 31] = attn[((size_t)(b * H_ + h)) * 1024 + t2];
    __syncthreads();
    const float* vrows = g + ((size_t)(2 * B_ + b) * C_ + h * 32) * N_;
    float acc[32] = {};
    for (int dd = 0; dd < 32; ++dd) {
        const float vv = vrows[(size_t)dd * N_ + n];
        #pragma unroll
        for (int cc = 0; cc < 32; ++cc) acc[cc] += at[cc][dd] * vv;
    }
    float* avb = av + ((size_t)b * C_ + h * 32) * N_ + n;
    #pragma unroll
    for (int cc = 0; cc < 32; ++cc) avb[(size_t)cc * N_] = acc[cc];
}

// ---------------- projection + bias + residual ----------------
__global__ __launch_bounds__(256) void k_proj(
    const float* __restrict__ av, const float* __restrict__ pW, const float* __restrict__ pb,
    const float* __restrict__ x, float* __restrict__ out)
{
    __shared__ float Ws[8][C_];
    const int n = blockIdx.x * 256 + threadIdx.x;
    const int o0 = blockIdx.y * 8;
    const int b = blockIdx.z;
    for (int t = threadIdx.x; t < 8 * C_; t += 256) {
        const int j = t >> 7, c = t & 127;
        Ws[j][c] = pW[(size_t)(o0 + j) * C_ + c];
    }
    __syncthreads();
    float acc[8] = {};
    const float* ab = av + ((size_t)b * C_) * N_ + n;
    #pragma unroll 4
    for (int c = 0; c < C_; ++c) {
        const float vv = ab[(size_t)c * N_];
        #pragma unroll
        for (int j = 0; j < 8; ++j) acc[j] += Ws[j][c] * vv;
    }
    #pragma unroll
    for (int j = 0; j < 8; ++j) {
        const int o = o0 + j;
        const size_t off = ((size_t)b * C_ + o) * N_ + n;
        out[off] = acc[j] + pb[o] + x[off];
    }
}

extern "C" void kernel_launch(void* const* d_in, const int* in_sizes, int n_in,
                              void* d_out, int out_size, void* d_ws, size_t ws_size,
                              hipStream_t stream)
{
    const float* x    = (const float*)d_in[0];
    const float* fW   = (const float*)d_in[1];
    const float* fb   = (const float*)d_in[2];
    const float* fg   = (const float*)d_in[3];
    const float* fbe  = (const float*)d_in[4];
    const float* gW1  = (const float*)d_in[5];
    const float* gb1  = (const float*)d_in[6];
    const float* gg1  = (const float*)d_in[7];
    const float* gbe1 = (const float*)d_in[8];
    const float* gW2  = (const float*)d_in[9];
    const float* gb2  = (const float*)d_in[10];
    const float* gg2  = (const float*)d_in[11];
    const float* gbe2 = (const float*)d_in[12];
    const float* pW   = (const float*)d_in[13];
    const float* pb   = (const float*)d_in[14];
    const float* temp = (const float*)d_in[15];
    float* ws = (float*)d_ws;

    float* y    = ws + OFF_Y;
    float* fT   = ws + OFF_FT;
    float* sc   = ws + OFF_SC;
    float* sh   = ws + OFF_SH;
    float* xx   = ws + OFF_XX;
    int*   idxb = (int*)(ws + OFF_IDX);
    float* P    = ws + OFF_P;
    float* Q    = ws + OFF_Q;
    float* gT   = ws + OFF_GT;
    float* g    = ws + OFF_G;
    float* nrm  = ws + OFF_NRM;
    float* attn = ws + OFF_ATT;
    float* av   = ws + OFF_AV;
    float* pd   = ws + OFF_PD;

    k_filter_conv<<<dim3(N_/256, C_/8, 12), 256, 0, stream>>>(x, fW, fb, y);
    k_rowstats<<<12 * C_, 256, 0, stream>>>(y, fg, fbe, sc, sh);
    k_norm_transpose<<<dim3(N_/32, C_/32, 12), dim3(32, 8), 0, stream>>>(y, sc, sh, fT);
    k_xx<<<(12 * N_) / 256, 256, 0, stream>>>(fT, xx);
    for (int ib = 0; ib < 12; ++ib) {
        k_pd<<<dim3(N_/64, N_/64), 256, 0, stream>>>(fT + (size_t)ib * N_ * C_, xx + ib * N_, pd);
        k_topk<<<N_/4, 256, 0, stream>>>(pd, idxb + (size_t)ib * N_ * K_);
    }
    k_pq<<<dim3(N_/64, 4, 12), 256, 0, stream>>>(fT, gW1, P, Q);
    k_edge2<<<dim3(N_/8, B_, 3), 256, 0, stream>>>(P, Q, idxb, gb1, gg1, gbe1,
                                                   gW2, gb2, gg2, gbe2, gT);
    k_transpose2<<<dim3(N_/32, C_/32, 12), dim3(32, 8), 0, stream>>>(gT, g);
    k_l2norm<<<2 * B_ * C_, 256, 0, stream>>>(g, nrm);
    k_attn<<<B_ * H_ * 32, 256, 0, stream>>>(g, nrm, temp, attn);
    k_av<<<dim3(N_/256, H_, B_), 256, 0, stream>>>(attn, g, av);
    k_proj<<<dim3(N_/256, C_/8, B_), 256, 0, stream>>>(av, pW, pb, x, (float*)d_out);
    (void)in_sizes; (void)n_in; (void)out_size; (void)ws_size;
}

// Round 4
// 711.661 us; speedup vs baseline: 1.8022x; 1.2184x over previous
//
#include <hip/hip_runtime.h>
#include <math.h>

// R3: k_pd fp32 vector-GEMM (12 x ~45us) -> k_pd_mfma split-bf16 MFMA
// (hi*hi + hi*lo + lo*hi, fp32 accum ~ fp32 quality). hi/lo planes written by
// k_norm_transpose into the OFF_G region (dead until k_transpose2). Everything
// else unchanged from the passing R1/R2 kernel (absmax 0.031).

#define B_ 4
#define C_ 128
#define N_ 2048
#define H_ 4
#define K_ 20

typedef __bf16 bf16x8 __attribute__((ext_vector_type(8)));
typedef float f32x4 __attribute__((ext_vector_type(4)));
typedef unsigned int u32x4 __attribute__((ext_vector_type(4)));

__device__ __forceinline__ unsigned short f2bf(float f) {
    unsigned int u = __builtin_bit_cast(unsigned int, f);
    u += 0x7fffu + ((u >> 16) & 1u);       // RNE
    return (unsigned short)(u >> 16);
}
__device__ __forceinline__ float bf2f(unsigned short s) {
    return __builtin_bit_cast(float, (unsigned int)s << 16);
}

// ---- workspace layout (float offsets) ----
#define OFF_Y    0           // [3][B][C][N]  conv output
#define OFF_FT   3145728     // [3][B][N][C]  filtered features, row-major per point
#define OFF_SC   6291456     // [3*B*C] IN scale
#define OFF_SH   6292992     // [3*B*C] IN shift
#define OFF_XX   6294528     // [3*B*N] squared norms
#define OFF_IDX  6319104     // [3*B*N*K] int neighbor indices
#define OFF_P    6810624     // [3][B][N][C]  P = (W1a+W1b)·f
#define OFF_Q    9956352     // [3][B][N][C]  Q = -W1b·f
#define OFF_GT   13102080    // [3][B][N][C]  gcn out (point-major)
#define OFF_G    16247808    // [3][B][C][N]  gcn out (channel-major); until
                             // k_transpose2 runs, doubles as fH/fL bf16 planes
#define OFF_NRM  19393536    // [2*B*C] l2 norms for q,k
#define OFF_ATT  19394560    // [B][H][32][32] softmaxed attention
#define OFF_AV   19410944    // [B][C][N] attention output
#define OFF_PD   20459520    // [N][N] pairwise dist scratch (reused per i,b)
// total = 24,653,824 floats = 98.6 MB

// ---------------- filter: 1x1 conv ----------------
__global__ __launch_bounds__(256) void k_filter_conv(
    const float* __restrict__ x, const float* __restrict__ fW,
    const float* __restrict__ fb, float* __restrict__ y)
{
    __shared__ float Ws[8][C_];
    const int n = blockIdx.x * 256 + threadIdx.x;
    const int o0 = blockIdx.y * 8;
    const int iz = blockIdx.z;                 // i*B + b
    const int i = iz >> 2, b = iz & 3;
    for (int t = threadIdx.x; t < 8 * C_; t += 256) {
        const int j = t >> 7, c = t & 127;
        Ws[j][c] = fW[((size_t)i * C_ + o0 + j) * C_ + c];
    }
    __syncthreads();
    float acc[8] = {};
    const float* xb = x + ((size_t)b * C_) * N_ + n;
    #pragma unroll 4
    for (int c = 0; c < C_; ++c) {
        const float xv = xb[(size_t)c * N_];
        #pragma unroll
        for (int j = 0; j < 8; ++j) acc[j] += Ws[j][c] * xv;
    }
    float* yb = y + ((size_t)iz * C_ + o0) * N_ + n;
    #pragma unroll
    for (int j = 0; j < 8; ++j) yb[(size_t)j * N_] = acc[j] + fb[i * C_ + o0 + j];
}

// ---------------- instance-norm row stats ----------------
__global__ __launch_bounds__(256) void k_rowstats(
    const float* __restrict__ y, const float* __restrict__ fg,
    const float* __restrict__ fbe, float* __restrict__ scale, float* __restrict__ shift)
{
    const int r = blockIdx.x;                  // (i*B+b)*C + o
    const int i = r >> 9, o = r & 127;
    const float* row = y + (size_t)r * N_;
    float s = 0.f, ss = 0.f;
    for (int n = threadIdx.x; n < N_; n += 256) {
        const float v = row[n];
        s += v; ss += v * v;
    }
    #pragma unroll
    for (int off = 32; off > 0; off >>= 1) {
        s += __shfl_down(s, off);
        ss += __shfl_down(ss, off);
    }
    __shared__ float red[2][4];
    const int wid = threadIdx.x >> 6;
    if ((threadIdx.x & 63) == 0) { red[0][wid] = s; red[1][wid] = ss; }
    __syncthreads();
    if (threadIdx.x == 0) {
        s = red[0][0] + red[0][1] + red[0][2] + red[0][3];
        ss = red[1][0] + red[1][1] + red[1][2] + red[1][3];
        const float mean = s * (1.f / N_);
        const float var = ss * (1.f / N_) - mean * mean;
        const float bn = sqrtf(1.00001f);
        const float sc = fg[i * C_ + o] / (bn * sqrtf(var + 1e-3f));
        scale[r] = sc;
        shift[r] = fbe[i * C_ + o] - mean * sc;
    }
}

// ------- normalize + relu + transpose to [n][c]; also emit bf16 hi/lo planes -------
__global__ __launch_bounds__(256) void k_norm_transpose(
    const float* __restrict__ y, const float* __restrict__ scale,
    const float* __restrict__ shift, float* __restrict__ fT,
    unsigned short* __restrict__ fH, unsigned short* __restrict__ fL)
{
    __shared__ float tile[32][33];
    const int n0 = blockIdx.x * 32, o0 = blockIdx.y * 32;
    const int iz = blockIdx.z;
    const int tx = threadIdx.x, ty = threadIdx.y;
    #pragma unroll
    for (int q = 0; q < 4; ++q) {
        const int o = o0 + ty + q * 8;
        const int r = iz * C_ + o;
        const float v = y[(size_t)r * N_ + n0 + tx] * scale[r] + shift[r];
        tile[ty + q * 8][tx] = fmaxf(v, 0.f);
    }
    __syncthreads();
    #pragma unroll
    for (int q = 0; q < 4; ++q) {
        const int n = n0 + ty + q * 8;
        const size_t idx = ((size_t)iz * N_ + n) * C_ + o0 + tx;
        const float v = tile[tx][ty + q * 8];
        fT[idx] = v;
        const unsigned short hi = f2bf(v);
        fH[idx] = hi;
        fL[idx] = f2bf(v - bf2f(hi));
    }
}

// ---------------- per-point squared norm ----------------
__global__ __launch_bounds__(256) void k_xx(const float* __restrict__ fT, float* __restrict__ xx)
{
    const int r = blockIdx.x * 256 + threadIdx.x;   // [0, 3*B*N)
    const float4* row = (const float4*)(fT + (size_t)r * C_);
    float s = 0.f;
    #pragma unroll
    for (int q = 0; q < C_ / 4; ++q) {
        const float4 v = row[q];
        s += v.x * v.x + v.y * v.y + v.z * v.z + v.w * v.w;
    }
    xx[r] = s;
}

// ------- pairwise -dist^2 via split-bf16 MFMA (one i,b): 64x64 tile/block -------
// inner ~= hi.hi' + hi.lo' + lo.hi' (fp32 accumulate); pd = 2*inner - xn - xm.
__global__ __launch_bounds__(256) void k_pd_mfma(
    const unsigned short* __restrict__ fHb, const unsigned short* __restrict__ fLb,
    const float* __restrict__ xxb, float* __restrict__ pd)
{
    __shared__ __align__(16) unsigned short Ah[64 * C_], Al[64 * C_];
    __shared__ __align__(16) unsigned short Bh[64 * C_], Bl[64 * C_];
    const int n0 = blockIdx.x * 64, m0 = blockIdx.y * 64;
    const int t = threadIdx.x;
    {   // stage 4 bf16 planes (T2 XOR swizzle, byte ^= (row&7)<<4)
        const int s = t & 15, rb = t >> 4;
        #pragma unroll
        for (int q = 0; q < 4; ++q) {
            const int r = rb + q * 16;
            const int ld = r * 256 + ((s * 16) ^ ((r & 7) << 4));
            *(u32x4*)((char*)Ah + ld) = *(const u32x4*)((const char*)fHb + (size_t)(n0 + r) * 256 + s * 16);
            *(u32x4*)((char*)Al + ld) = *(const u32x4*)((const char*)fLb + (size_t)(n0 + r) * 256 + s * 16);
            *(u32x4*)((char*)Bh + ld) = *(const u32x4*)((const char*)fHb + (size_t)(m0 + r) * 256 + s * 16);
            *(u32x4*)((char*)Bl + ld) = *(const u32x4*)((const char*)fLb + (size_t)(m0 + r) * 256 + s * 16);
        }
    }
    __syncthreads();
    const int lane = t & 63, w = t >> 6;       // wave w owns rows [w*16, w*16+16)
    const int lr = lane & 15, lg = lane >> 4;
    f32x4 acc[4];
    #pragma unroll
    for (int ct = 0; ct < 4; ++ct) acc[ct] = (f32x4){0.f, 0.f, 0.f, 0.f};
    #pragma unroll
    for (int ks = 0; ks < 4; ++ks) {           // K = 128, 32 per MFMA
        const int arow = w * 16 + lr;
        const int cb = ks * 64 + lg * 16;      // byte col within 256B row
        const bf16x8 ah = __builtin_bit_cast(bf16x8,
            *(const u32x4*)((const char*)Ah + arow * 256 + (cb ^ ((arow & 7) << 4))));
        const bf16x8 al = __builtin_bit_cast(bf16x8,
            *(const u32x4*)((const char*)Al + arow * 256 + (cb ^ ((arow & 7) << 4))));
        #pragma unroll
        for (int ct = 0; ct < 4; ++ct) {
            const int brow = ct * 16 + lr;
            const int boff = brow * 256 + (cb ^ ((brow & 7) << 4));
            const bf16x8 bh = __builtin_bit_cast(bf16x8, *(const u32x4*)((const char*)Bh + boff));
            const bf16x8 bl = __builtin_bit_cast(bf16x8, *(const u32x4*)((const char*)Bl + boff));
            acc[ct] = __builtin_amdgcn_mfma_f32_16x16x32_bf16(ah, bh, acc[ct], 0, 0, 0);
            acc[ct] = __builtin_amdgcn_mfma_f32_16x16x32_bf16(ah, bl, acc[ct], 0, 0, 0);
            acc[ct] = __builtin_amdgcn_mfma_f32_16x16x32_bf16(al, bh, acc[ct], 0, 0, 0);
        }
    }
    // epilogue: D col=lane&15, row=(lane>>4)*4+r  (m89/m91-verified mapping)
    #pragma unroll
    for (int ct = 0; ct < 4; ++ct) {
        const int m = m0 + ct * 16 + lr;
        const float xm = xxb[m];
        #pragma unroll
        for (int r = 0; r < 4; ++r) {
            const int n = n0 + w * 16 + lg * 4 + r;
            pd[(size_t)n * N_ + m] = 2.f * acc[ct][r] - xxb[n] - xm;
        }
    }
}

// ---------------- top-K=20 per row (one wave per row) ----------------
__global__ __launch_bounds__(256) void k_topk(const float* __restrict__ pd, int* __restrict__ idxb)
{
    const int lane = threadIdx.x & 63;
    const int n = blockIdx.x * 4 + (threadIdx.x >> 6);
    const float* row = pd + (size_t)n * N_;
    float v[32];
    #pragma unroll
    for (int j = 0; j < 32; ++j) v[j] = row[j * 64 + lane];
    for (int it = 0; it < K_; ++it) {
        float best = -3e38f; int bj = 0;
        #pragma unroll
        for (int j = 0; j < 32; ++j) if (v[j] > best) { best = v[j]; bj = j; }
        int bm = bj * 64 + lane;
        #pragma unroll
        for (int off = 1; off < 64; off <<= 1) {
            const float ov = __shfl_xor(best, off);
            const int   om = __shfl_xor(bm, off);
            if (ov > best || (ov == best && om < bm)) { best = ov; bm = om; }
        }
        if (lane == 0) idxb[n * K_ + it] = bm;
        if ((bm & 63) == lane) {
            const int jj = bm >> 6;          // static unroll avoids scratch (rule #20)
            #pragma unroll
            for (int j = 0; j < 32; ++j) if (j == jj) v[j] = -3e38f;
        }
    }
}

// ---------------- P/Q GEMMs: P=(W1a+W1b)·f, Q=(-W1b)·f ----------------
__global__ __launch_bounds__(256) void k_pq(
    const float* __restrict__ fT, const float* __restrict__ gW1,
    float* __restrict__ P, float* __restrict__ Q)
{
    __shared__ float As[64][68], Bs[64][68];
    const int iz = blockIdx.z;
    const int i = iz >> 2;
    const int n0 = blockIdx.x * 64;
    const int yt = blockIdx.y;           // 0,1 -> P cols; 2,3 -> Q cols
    const bool isQ = (yt >= 2);
    const int oc0 = (yt & 1) * 64;
    const float* fTb = fT + (size_t)iz * N_ * C_;
    const int tm = threadIdx.x & 15, tn = threadIdx.x >> 4;
    float acc[4][4] = {};
    for (int kc = 0; kc < C_; kc += 64) {
        __syncthreads();
        #pragma unroll
        for (int q = 0; q < 4; ++q) {
            const int id = threadIdx.x + 256 * q;
            const int m = id >> 4, c4 = id & 15;
            const float4 va = *(const float4*)(fTb + ((size_t)(n0 + m)) * C_ + kc + c4 * 4);
            As[c4*4+0][m] = va.x; As[c4*4+1][m] = va.y; As[c4*4+2][m] = va.z; As[c4*4+3][m] = va.w;
            const float* wrow = gW1 + ((size_t)i * C_ + oc0 + m) * (2 * C_);
            const float4 wa = *(const float4*)(wrow + kc + c4 * 4);
            const float4 wb = *(const float4*)(wrow + C_ + kc + c4 * 4);
            float4 bv;
            if (isQ) { bv.x = -wb.x; bv.y = -wb.y; bv.z = -wb.z; bv.w = -wb.w; }
            else     { bv.x = wa.x + wb.x; bv.y = wa.y + wb.y; bv.z = wa.z + wb.z; bv.w = wa.w + wb.w; }
            Bs[c4*4+0][m] = bv.x; Bs[c4*4+1][m] = bv.y; Bs[c4*4+2][m] = bv.z; Bs[c4*4+3][m] = bv.w;
        }
        __syncthreads();
        #pragma unroll
        for (int k = 0; k < 64; ++k) {
            const float4 a  = *(const float4*)&As[k][tm * 4];
            const float4 bb = *(const float4*)&Bs[k][tn * 4];
            acc[0][0] += a.x*bb.x; acc[0][1] += a.x*bb.y; acc[0][2] += a.x*bb.z; acc[0][3] += a.x*bb.w;
            acc[1][0] += a.y*bb.x; acc[1][1] += a.y*bb.y; acc[1][2] += a.y*bb.z; acc[1][3] += a.y*bb.w;
            acc[2][0] += a.z*bb.x; acc[2][1] += a.z*bb.y; acc[2][2] += a.z*bb.z; acc[2][3] += a.z*bb.w;
            acc[3][0] += a.w*bb.x; acc[3][1] += a.w*bb.y; acc[3][2] += a.w*bb.z; acc[3][3] += a.w*bb.w;
        }
    }
    float* out = (isQ ? Q : P) + (size_t)iz * N_ * C_;
    #pragma unroll
    for (int rr = 0; rr < 4; ++rr) {
        const float4 st = make_float4(acc[rr][0], acc[rr][1], acc[rr][2], acc[rr][3]);
        *(float4*)(out + ((size_t)(n0 + tm * 4 + rr)) * C_ + oc0 + tn * 4) = st;
    }
}

// ---------------- edge conv2 + max over k : bf16 MFMA version ----------------
__global__ __launch_bounds__(256) void k_edge2(
    const float* __restrict__ P, const float* __restrict__ Q, const int* __restrict__ idxb,
    const float* __restrict__ gb1, const float* __restrict__ gg1, const float* __restrict__ gbe1,
    const float* __restrict__ gW2, const float* __restrict__ gb2, const float* __restrict__ gg2,
    const float* __restrict__ gbe2, float* __restrict__ gT)
{
    __shared__ __align__(16) unsigned short h1s[160 * C_];  // 40 KB
    __shared__ __align__(16) unsigned short W2s[C_ * C_];   // 32 KB
    __shared__ float s1s[C_], t1s[C_], s2s[C_], t2s[C_];
    __shared__ int idxs[160];
    const int i = blockIdx.z, b = blockIdx.y;
    const int p0 = blockIdx.x * 8;
    const int t = threadIdx.x;
    const size_t base = (size_t)(i * B_ + b) * N_;

    if (t < C_) {
        const float bn = sqrtf(1.00001f);
        const float g1 = gg1[i * C_ + t];
        s1s[t] = g1 / bn;
        t1s[t] = gb1[i * C_ + t] * (g1 / bn) + gbe1[i * C_ + t];
        const float g2 = gg2[i * C_ + t];
        s2s[t] = g2 / bn;
        t2s[t] = gb2[i * C_ + t] * (g2 / bn) + gbe2[i * C_ + t];
    }
    if (t < 160) idxs[t] = idxb[base * K_ + p0 * K_ + t];
    __syncthreads();

    const int seg = t & 7;            // fixed 16-element column segment per thread
    const int rb = t >> 3;            // base row / base o
    float4 s1v[4], t1v[4];
    #pragma unroll
    for (int q = 0; q < 4; ++q) {
        s1v[q] = *(const float4*)&s1s[seg * 16 + q * 4];
        t1v[q] = *(const float4*)&t1s[seg * 16 + q * 4];
    }
    // ---- build h1 (bf16, swizzled) ----
    const float* Pb = P + base * C_;
    const float* Qb = Q + base * C_;
    #pragma unroll
    for (int it = 0; it < 5; ++it) {
        const int row = rb + 32 * it;
        const int p = row / 20;
        const int m = idxs[row];
        const float* Pr = Pb + (size_t)(p0 + p) * C_ + seg * 16;
        const float* Qr = Qb + (size_t)m * C_ + seg * 16;
        unsigned int pk[8];
        #pragma unroll
        for (int q = 0; q < 4; ++q) {
            const float4 pv = *(const float4*)(Pr + q * 4);
            const float4 qv = *(const float4*)(Qr + q * 4);
            const float r0 = fmaxf((pv.x + qv.x) * s1v[q].x + t1v[q].x, 0.f);
            const float r1 = fmaxf((pv.y + qv.y) * s1v[q].y + t1v[q].y, 0.f);
            const float r2 = fmaxf((pv.z + qv.z) * s1v[q].z + t1v[q].z, 0.f);
            const float r3 = fmaxf((pv.w + qv.w) * s1v[q].w + t1v[q].w, 0.f);
            pk[q * 2 + 0] = (unsigned int)f2bf(r0) | ((unsigned int)f2bf(r1) << 16);
            pk[q * 2 + 1] = (unsigned int)f2bf(r2) | ((unsigned int)f2bf(r3) << 16);
        }
        const int sw = (row & 7) << 4;
        char* bp = (char*)h1s + row * 256;
        *(u32x4*)(bp + ((seg * 32) ^ sw))      = (u32x4){pk[0], pk[1], pk[2], pk[3]};
        *(u32x4*)(bp + ((seg * 32 + 16) ^ sw)) = (u32x4){pk[4], pk[5], pk[6], pk[7]};
    }
    // ---- stage W2 (bf16, swizzled) ----
    #pragma unroll
    for (int it = 0; it < 4; ++it) {
        const int o = rb + 32 * it;
        const float* wr = gW2 + ((size_t)i * C_ + o) * C_ + seg * 16;
        unsigned int pk[8];
        #pragma unroll
        for (int q = 0; q < 4; ++q) {
            const float4 wv = *(const float4*)(wr + q * 4);
            pk[q * 2 + 0] = (unsigned int)f2bf(wv.x) | ((unsigned int)f2bf(wv.y) << 16);
            pk[q * 2 + 1] = (unsigned int)f2bf(wv.z) | ((unsigned int)f2bf(wv.w) << 16);
        }
        const int sw = (o & 7) << 4;
        char* bp = (char*)W2s + o * 256;
        *(u32x4*)(bp + ((seg * 32) ^ sw))      = (u32x4){pk[0], pk[1], pk[2], pk[3]};
        *(u32x4*)(bp + ((seg * 32 + 16) ^ sw)) = (u32x4){pk[4], pk[5], pk[6], pk[7]};
    }
    __syncthreads();

    // ---- MFMA: D[row][o] = sum_c h1[row][c] * W2[o][c] ----
    const int lane = t & 63, w = t >> 6;
    const int lr = lane & 15, lg = lane >> 4;
    bf16x8 Bf[2][4];
    #pragma unroll
    for (int nb = 0; nb < 2; ++nb)
        #pragma unroll
        for (int ks = 0; ks < 4; ++ks) {
            const int o = w * 32 + nb * 16 + lr;
            const int cb = ks * 64 + lg * 16;          // byte col
            Bf[nb][ks] = __builtin_bit_cast(bf16x8,
                *(const u32x4*)((const char*)W2s + o * 256 + (cb ^ ((o & 7) << 4))));
        }
    f32x4 acc[10][2];
    #pragma unroll
    for (int mt = 0; mt < 10; ++mt)
        #pragma unroll
        for (int nb = 0; nb < 2; ++nb)
            acc[mt][nb] = (f32x4){0.f, 0.f, 0.f, 0.f};
    #pragma unroll
    for (int mt = 0; mt < 10; ++mt) {
        bf16x8 Af[4];
        #pragma unroll
        for (int ks = 0; ks < 4; ++ks) {
            const int row = mt * 16 + lr;
            const int cb = ks * 64 + lg * 16;
            Af[ks] = __builtin_bit_cast(bf16x8,
                *(const u32x4*)((const char*)h1s + row * 256 + (cb ^ ((row & 7) << 4))));
        }
        #pragma unroll
        for (int nb = 0; nb < 2; ++nb)
            #pragma unroll
            for (int ks = 0; ks < 4; ++ks)
                acc[mt][nb] = __builtin_amdgcn_mfma_f32_16x16x32_bf16(
                    Af[ks], Bf[nb][ks], acc[mt][nb], 0, 0, 0);
    }
    __syncthreads();   // all waves done reading h1s

    // ---- epilogue: scale+shift+relu, store h2 bf16 into h1s region ----
    #pragma unroll
    for (int mt = 0; mt < 10; ++mt)
        #pragma unroll
        for (int nb = 0; nb < 2; ++nb) {
            const int col = w * 32 + nb * 16 + lr;
            const float s2c = s2s[col], t2c = t2s[col];
            #pragma unroll
            for (int r = 0; r < 4; ++r) {
                const int row = mt * 16 + lg * 4 + r;
                const float v = fmaxf(acc[mt][nb][r] * s2c + t2c, 0.f);
                *(unsigned short*)((char*)h1s + row * 256 + ((col * 2) ^ ((row & 7) << 4))) = f2bf(v);
            }
        }
    __syncthreads();

    // ---- max over 20 neighbors per point ----
    const int oc = t & 127, ph = t >> 7;
    float* gp = gT + (base + p0) * C_;
    #pragma unroll
    for (int pp = 0; pp < 4; ++pp) {
        const int p = ph * 4 + pp;
        float mx = 0.f;
        #pragma unroll
        for (int j = 0; j < 20; ++j) {
            const int row = p * 20 + j;
            const unsigned short us =
                *(const unsigned short*)((const char*)h1s + row * 256 + ((oc * 2) ^ ((row & 7) << 4)));
            mx = fmaxf(mx, bf2f(us));
        }
        gp[(size_t)p * C_ + oc] = mx;
    }
}

// ---------------- transpose gT [n][c] -> g [c][n] ----------------
__global__ __launch_bounds__(256) void k_transpose2(
    const float* __restrict__ gT, float* __restrict__ g)
{
    __shared__ float tile[32][33];
    const int n0 = blockIdx.x * 32, o0 = blockIdx.y * 32;
    const int iz = blockIdx.z;
    const int tx = threadIdx.x, ty = threadIdx.y;
    #pragma unroll
    for (int q = 0; q < 4; ++q) {
        const int n = n0 + ty + q * 8;
        tile[ty + q * 8][tx] = gT[((size_t)iz * N_ + n) * C_ + o0 + tx];
    }
    __syncthreads();
    #pragma unroll
    for (int q = 0; q < 4; ++q) {
        const int o = o0 + ty + q * 8;
        g[((size_t)iz * C_ + o) * N_ + n0 + tx] = tile[tx][ty + q * 8];
    }
}

// ---------------- l2 norms over N for q,k branches ----------------
__global__ __launch_bounds__(256) void k_l2norm(const float* __restrict__ g, float* __restrict__ norms)
{
    const int r = blockIdx.x;       // [0, 2*B*C)
    const float* row = g + (size_t)r * N_;
    float s = 0.f;
    for (int n = threadIdx.x; n < N_; n += 256) { const float v = row[n]; s += v * v; }
    #pragma unroll
    for (int off = 32; off > 0; off >>= 1) s += __shfl_down(s, off);
    __shared__ float red[4];
    if ((threadIdx.x & 63) == 0) red[threadIdx.x >> 6] = s;
    __syncthreads();
    if (threadIdx.x == 0)
        norms[r] = fmaxf(sqrtf(red[0] + red[1] + red[2] + red[3]), 1e-12f);
}

// ---------------- attention scores + softmax (one q-row per block) ----------------
__global__ __launch_bounds__(256) void k_attn(
    const float* __restrict__ g, const float* __restrict__ norms,
    const float* __restrict__ temp, float* __restrict__ attn)
{
    __shared__ float qs[N_];
    __shared__ float rowv[32];
    const int r = blockIdx.x;                 // b*128 + h*32 + c
    const int c = r & 31, h = (r >> 5) & 3, b = r >> 7;
    const float* qrow  = g + ((size_t)(0 * B_ + b) * C_ + h * 32 + c) * N_;
    const float* krows = g + ((size_t)(1 * B_ + b) * C_ + h * 32) * N_;
    for (int n = threadIdx.x; n < N_; n += 256) qs[n] = qrow[n];
    __syncthreads();
    const int d = threadIdx.x >> 3, s = threadIdx.x & 7;
    const float* kr = krows + (size_t)d * N_;
    float acc = 0.f;
    for (int m = 0; m < N_ / 32; ++m) {
        const int n = (m * 8 + s) * 4;
        const float4 kv = *(const float4*)(kr + n);
        acc += qs[n] * kv.x + qs[n+1] * kv.y + qs[n+2] * kv.z + qs[n+3] * kv.w;
    }
    #pragma unroll
    for (int off = 1; off < 8; off <<= 1) acc += __shfl_xor(acc, off);
    if (s == 0) rowv[d] = acc;
    __syncthreads();
    if (threadIdx.x < 32) {
        const int dd = threadIdx.x;
        const float nq = norms[(size_t)(0 * B_ + b) * C_ + h * 32 + c];
        const float nk = norms[(size_t)(1 * B_ + b) * C_ + h * 32 + dd];
        const float v = rowv[dd] / (nq * nk) * temp[h];
        float mx = v;
        #pragma unroll
        for (int off = 1; off < 32; off <<= 1) mx = fmaxf(mx, __shfl_xor(mx, off));
        const float e = expf(v - mx);
        float sm = e;
        #pragma unroll
        for (int off = 1; off < 32; off <<= 1) sm += __shfl_xor(sm, off);
        attn[(size_t)r * 32 + dd] = e / sm;
    }
}

// ---------------- attn @ v ----------------
__global__ __launch_bounds__(256) void k_av(
    const float* __restrict__ attn, const float* __restrict__ g, float* __restrict__ av)
{
    __shared__ float at[32][32];
    const int n = blockIdx.x * 256 + threadIdx.x;
    const int h = blockIdx.y, b = blockIdx.z;
    for (int t2 = threadIdx.x; t2 < 1024; t2 += 256)
        at[t2 >> 5][t2 & 31] = attn[((size_t)(b * H_ + h)) * 1024 + t2];
    __syncthreads();
    const float* vrows = g + ((size_t)(2 * B_ + b) * C_ + h * 32) * N_;
    float acc[32] = {};
    for (int dd = 0; dd < 32; ++dd) {
        const float vv = vrows[(size_t)dd * N_ + n];
        #pragma unroll
        for (int cc = 0; cc < 32; ++cc) acc[cc] += at[cc][dd] * vv;
    }
    float* avb = av + ((size_t)b * C_ + h * 32) * N_ + n;
    #pragma unroll
    for (int cc = 0; cc < 32; ++cc) avb[(size_t)cc * N_] = acc[cc];
}

// ---------------- projection + bias + residual ----------------
__global__ __launch_bounds__(256) void k_proj(
    const float* __restrict__ av, const float* __restrict__ pW, const float* __restrict__ pb,
    const float* __restrict__ x, float* __restrict__ out)
{
    __shared__ float Ws[8][C_];
    const int n = blockIdx.x * 256 + threadIdx.x;
    const int o0 = blockIdx.y * 8;
    const int b = blockIdx.z;
    for (int t = threadIdx.x; t < 8 * C_; t += 256) {
        const int j = t >> 7, c = t & 127;
        Ws[j][c] = pW[(size_t)(o0 + j) * C_ + c];
    }
    __syncthreads();
    float acc[8] = {};
    const float* ab = av + ((size_t)b * C_) * N_ + n;
    #pragma unroll 4
    for (int c = 0; c < C_; ++c) {
        const float vv = ab[(size_t)c * N_];
        #pragma unroll
        for (int j = 0; j < 8; ++j) acc[j] += Ws[j][c] * vv;
    }
    #pragma unroll
    for (int j = 0; j < 8; ++j) {
        const int o = o0 + j;
        const size_t off = ((size_t)b * C_ + o) * N_ + n;
        out[off] = acc[j] + pb[o] + x[off];
    }
}

extern "C" void kernel_launch(void* const* d_in, const int* in_sizes, int n_in,
                              void* d_out, int out_size, void* d_ws, size_t ws_size,
                              hipStream_t stream)
{
    const float* x    = (const float*)d_in[0];
    const float* fW   = (const float*)d_in[1];
    const float* fb   = (const float*)d_in[2];
    const float* fg   = (const float*)d_in[3];
    const float* fbe  = (const float*)d_in[4];
    const float* gW1  = (const float*)d_in[5];
    const float* gb1  = (const float*)d_in[6];
    const float* gg1  = (const float*)d_in[7];
    const float* gbe1 = (const float*)d_in[8];
    const float* gW2  = (const float*)d_in[9];
    const float* gb2  = (const float*)d_in[10];
    const float* gg2  = (const float*)d_in[11];
    const float* gbe2 = (const float*)d_in[12];
    const float* pW   = (const float*)d_in[13];
    const float* pb   = (const float*)d_in[14];
    const float* temp = (const float*)d_in[15];
    float* ws = (float*)d_ws;

    float* y    = ws + OFF_Y;
    float* fT   = ws + OFF_FT;
    float* sc   = ws + OFF_SC;
    float* sh   = ws + OFF_SH;
    float* xx   = ws + OFF_XX;
    int*   idxb = (int*)(ws + OFF_IDX);
    float* P    = ws + OFF_P;
    float* Q    = ws + OFF_Q;
    float* gT   = ws + OFF_GT;
    float* g    = ws + OFF_G;
    float* nrm  = ws + OFF_NRM;
    float* attn = ws + OFF_ATT;
    float* av   = ws + OFF_AV;
    float* pd   = ws + OFF_PD;
    // bf16 hi/lo feature planes live in the (not-yet-written) OFF_G region:
    // fH: 12*N*C u16, fL right after; together exactly 3145728 floats = |G|.
    unsigned short* fH = (unsigned short*)g;
    unsigned short* fL = fH + (size_t)12 * N_ * C_;

    k_filter_conv<<<dim3(N_/256, C_/8, 12), 256, 0, stream>>>(x, fW, fb, y);
    k_rowstats<<<12 * C_, 256, 0, stream>>>(y, fg, fbe, sc, sh);
    k_norm_transpose<<<dim3(N_/32, C_/32, 12), dim3(32, 8), 0, stream>>>(y, sc, sh, fT, fH, fL);
    k_xx<<<(12 * N_) / 256, 256, 0, stream>>>(fT, xx);
    for (int ib = 0; ib < 12; ++ib) {
        k_pd_mfma<<<dim3(N_/64, N_/64), 256, 0, stream>>>(
            fH + (size_t)ib * N_ * C_, fL + (size_t)ib * N_ * C_, xx + ib * N_, pd);
        k_topk<<<N_/4, 256, 0, stream>>>(pd, idxb + (size_t)ib * N_ * K_);
    }
    k_pq<<<dim3(N_/64, 4, 12), 256, 0, stream>>>(fT, gW1, P, Q);
    k_edge2<<<dim3(N_/8, B_, 3), 256, 0, stream>>>(P, Q, idxb, gb1, gg1, gbe1,
                                                   gW2, gb2, gg2, gbe2, gT);
    k_transpose2<<<dim3(N_/32, C_/32, 12), dim3(32, 8), 0, stream>>>(gT, g);
    k_l2norm<<<2 * B_ * C_, 256, 0, stream>>>(g, nrm);
    k_attn<<<B_ * H_ * 32, 256, 0, stream>>>(g, nrm, temp, attn);
    k_av<<<dim3(N_/256, H_, B_), 256, 0, stream>>>(attn, g, av);
    k_proj<<<dim3(N_/256, C_/8, B_), 256, 0, stream>>>(av, pW, pb, x, (float*)d_out);
    (void)in_sizes; (void)n_in; (void)out_size; (void)ws_size;
}

// Round 5
// 521.514 us; speedup vs baseline: 2.4593x; 1.3646x over previous
//
#include <hip/hip_runtime.h>
#include <math.h>

// R4: batch the kNN phase. Workspace rearranged into an arena that holds
// Y (pre-knn), 4 pd buffers (during knn), and P/Q/GT/AV (post-knn).
// 24 serialized pd/topk dispatches -> 3x(pd z=4 ; topk y=4). Kernel math
// unchanged from the passing R3 build (absmax 0.0625).

#define B_ 4
#define C_ 128
#define N_ 2048
#define H_ 4
#define K_ 20

typedef __bf16 bf16x8 __attribute__((ext_vector_type(8)));
typedef float f32x4 __attribute__((ext_vector_type(4)));
typedef unsigned int u32x4 __attribute__((ext_vector_type(4)));

__device__ __forceinline__ unsigned short f2bf(float f) {
    unsigned int u = __builtin_bit_cast(unsigned int, f);
    u += 0x7fffu + ((u >> 16) & 1u);       // RNE
    return (unsigned short)(u >> 16);
}
__device__ __forceinline__ float bf2f(unsigned short s) {
    return __builtin_bit_cast(float, (unsigned int)s << 16);
}

// ---- workspace layout (float offsets) ----
// ARENA [0, 16777216): time-shared.
//   pre-knn : Y [3][B][C][N] (3145728) at offset 0
//   knn     : 4 pd buffers, stride PD_STRIDE
//   post-knn: P, Q, GT, AV
#define PD_STRIDE 4194304
#define OFF_Y     0
#define OFF_P     0
#define OFF_Q     3145728
#define OFF_GT    6291456
#define OFF_AV    9437184
#define OFF_FT    16777216   // [3][B][N][C] fp32 features (3145728)
#define OFF_SC    19922944   // 1536
#define OFF_SH    19924480   // 1536
#define OFF_XX    19926016   // 24576
#define OFF_IDX   19950592   // 3*B*N*K ints (491520)
#define OFF_G     20442112   // 3145728: fH/fL bf16 planes during knn, g after
#define OFF_NRM   23587840   // 1024
#define OFF_ATT   23588864   // 16384
// total = 23,605,248 floats = 94.4 MB (< R3's 98.6 MB requirement)

// ---------------- filter: 1x1 conv ----------------
__global__ __launch_bounds__(256) void k_filter_conv(
    const float* __restrict__ x, const float* __restrict__ fW,
    const float* __restrict__ fb, float* __restrict__ y)
{
    __shared__ float Ws[8][C_];
    const int n = blockIdx.x * 256 + threadIdx.x;
    const int o0 = blockIdx.y * 8;
    const int iz = blockIdx.z;                 // i*B + b
    const int i = iz >> 2, b = iz & 3;
    for (int t = threadIdx.x; t < 8 * C_; t += 256) {
        const int j = t >> 7, c = t & 127;
        Ws[j][c] = fW[((size_t)i * C_ + o0 + j) * C_ + c];
    }
    __syncthreads();
    float acc[8] = {};
    const float* xb = x + ((size_t)b * C_) * N_ + n;
    #pragma unroll 4
    for (int c = 0; c < C_; ++c) {
        const float xv = xb[(size_t)c * N_];
        #pragma unroll
        for (int j = 0; j < 8; ++j) acc[j] += Ws[j][c] * xv;
    }
    float* yb = y + ((size_t)iz * C_ + o0) * N_ + n;
    #pragma unroll
    for (int j = 0; j < 8; ++j) yb[(size_t)j * N_] = acc[j] + fb[i * C_ + o0 + j];
}

// ---------------- instance-norm row stats ----------------
__global__ __launch_bounds__(256) void k_rowstats(
    const float* __restrict__ y, const float* __restrict__ fg,
    const float* __restrict__ fbe, float* __restrict__ scale, float* __restrict__ shift)
{
    const int r = blockIdx.x;                  // (i*B+b)*C + o
    const int i = r >> 9, o = r & 127;
    const float* row = y + (size_t)r * N_;
    float s = 0.f, ss = 0.f;
    for (int n = threadIdx.x; n < N_; n += 256) {
        const float v = row[n];
        s += v; ss += v * v;
    }
    #pragma unroll
    for (int off = 32; off > 0; off >>= 1) {
        s += __shfl_down(s, off);
        ss += __shfl_down(ss, off);
    }
    __shared__ float red[2][4];
    const int wid = threadIdx.x >> 6;
    if ((threadIdx.x & 63) == 0) { red[0][wid] = s; red[1][wid] = ss; }
    __syncthreads();
    if (threadIdx.x == 0) {
        s = red[0][0] + red[0][1] + red[0][2] + red[0][3];
        ss = red[1][0] + red[1][1] + red[1][2] + red[1][3];
        const float mean = s * (1.f / N_);
        const float var = ss * (1.f / N_) - mean * mean;
        const float bn = sqrtf(1.00001f);
        const float sc = fg[i * C_ + o] / (bn * sqrtf(var + 1e-3f));
        scale[r] = sc;
        shift[r] = fbe[i * C_ + o] - mean * sc;
    }
}

// ------- normalize + relu + transpose to [n][c]; also emit bf16 hi/lo planes -------
__global__ __launch_bounds__(256) void k_norm_transpose(
    const float* __restrict__ y, const float* __restrict__ scale,
    const float* __restrict__ shift, float* __restrict__ fT,
    unsigned short* __restrict__ fH, unsigned short* __restrict__ fL)
{
    __shared__ float tile[32][33];
    const int n0 = blockIdx.x * 32, o0 = blockIdx.y * 32;
    const int iz = blockIdx.z;
    const int tx = threadIdx.x, ty = threadIdx.y;
    #pragma unroll
    for (int q = 0; q < 4; ++q) {
        const int o = o0 + ty + q * 8;
        const int r = iz * C_ + o;
        const float v = y[(size_t)r * N_ + n0 + tx] * scale[r] + shift[r];
        tile[ty + q * 8][tx] = fmaxf(v, 0.f);
    }
    __syncthreads();
    #pragma unroll
    for (int q = 0; q < 4; ++q) {
        const int n = n0 + ty + q * 8;
        const size_t idx = ((size_t)iz * N_ + n) * C_ + o0 + tx;
        const float v = tile[tx][ty + q * 8];
        fT[idx] = v;
        const unsigned short hi = f2bf(v);
        fH[idx] = hi;
        fL[idx] = f2bf(v - bf2f(hi));
    }
}

// ---------------- per-point squared norm ----------------
__global__ __launch_bounds__(256) void k_xx(const float* __restrict__ fT, float* __restrict__ xx)
{
    const int r = blockIdx.x * 256 + threadIdx.x;   // [0, 3*B*N)
    const float4* row = (const float4*)(fT + (size_t)r * C_);
    float s = 0.f;
    #pragma unroll
    for (int q = 0; q < C_ / 4; ++q) {
        const float4 v = row[q];
        s += v.x * v.x + v.y * v.y + v.z * v.z + v.w * v.w;
    }
    xx[r] = s;
}

// ------- pairwise -dist^2 via split-bf16 MFMA; z = buffer slot (ib = ib0+z) -------
__global__ __launch_bounds__(256) void k_pd_mfma(
    const unsigned short* __restrict__ fH, const unsigned short* __restrict__ fL,
    const float* __restrict__ xx, float* __restrict__ pdarena, int ib0)
{
    __shared__ __align__(16) unsigned short Ah[64 * C_], Al[64 * C_];
    __shared__ __align__(16) unsigned short Bh[64 * C_], Bl[64 * C_];
    const int j = blockIdx.z, ib = ib0 + j;
    const unsigned short* fHb = fH + (size_t)ib * N_ * C_;
    const unsigned short* fLb = fL + (size_t)ib * N_ * C_;
    const float* xxb = xx + ib * N_;
    float* pd = pdarena + (size_t)j * PD_STRIDE;
    const int n0 = blockIdx.x * 64, m0 = blockIdx.y * 64;
    const int t = threadIdx.x;
    {   // stage 4 bf16 planes (T2 XOR swizzle, byte ^= (row&7)<<4)
        const int s = t & 15, rb = t >> 4;
        #pragma unroll
        for (int q = 0; q < 4; ++q) {
            const int r = rb + q * 16;
            const int ld = r * 256 + ((s * 16) ^ ((r & 7) << 4));
            *(u32x4*)((char*)Ah + ld) = *(const u32x4*)((const char*)fHb + (size_t)(n0 + r) * 256 + s * 16);
            *(u32x4*)((char*)Al + ld) = *(const u32x4*)((const char*)fLb + (size_t)(n0 + r) * 256 + s * 16);
            *(u32x4*)((char*)Bh + ld) = *(const u32x4*)((const char*)fHb + (size_t)(m0 + r) * 256 + s * 16);
            *(u32x4*)((char*)Bl + ld) = *(const u32x4*)((const char*)fLb + (size_t)(m0 + r) * 256 + s * 16);
        }
    }
    __syncthreads();
    const int lane = t & 63, w = t >> 6;       // wave w owns rows [w*16, w*16+16)
    const int lr = lane & 15, lg = lane >> 4;
    f32x4 acc[4];
    #pragma unroll
    for (int ct = 0; ct < 4; ++ct) acc[ct] = (f32x4){0.f, 0.f, 0.f, 0.f};
    #pragma unroll
    for (int ks = 0; ks < 4; ++ks) {           // K = 128, 32 per MFMA
        const int arow = w * 16 + lr;
        const int cb = ks * 64 + lg * 16;      // byte col within 256B row
        const bf16x8 ah = __builtin_bit_cast(bf16x8,
            *(const u32x4*)((const char*)Ah + arow * 256 + (cb ^ ((arow & 7) << 4))));
        const bf16x8 al = __builtin_bit_cast(bf16x8,
            *(const u32x4*)((const char*)Al + arow * 256 + (cb ^ ((arow & 7) << 4))));
        #pragma unroll
        for (int ct = 0; ct < 4; ++ct) {
            const int brow = ct * 16 + lr;
            const int boff = brow * 256 + (cb ^ ((brow & 7) << 4));
            const bf16x8 bh = __builtin_bit_cast(bf16x8, *(const u32x4*)((const char*)Bh + boff));
            const bf16x8 bl = __builtin_bit_cast(bf16x8, *(const u32x4*)((const char*)Bl + boff));
            acc[ct] = __builtin_amdgcn_mfma_f32_16x16x32_bf16(ah, bh, acc[ct], 0, 0, 0);
            acc[ct] = __builtin_amdgcn_mfma_f32_16x16x32_bf16(ah, bl, acc[ct], 0, 0, 0);
            acc[ct] = __builtin_amdgcn_mfma_f32_16x16x32_bf16(al, bh, acc[ct], 0, 0, 0);
        }
    }
    // epilogue: D col=lane&15, row=(lane>>4)*4+r  (m89/m91-verified mapping)
    #pragma unroll
    for (int ct = 0; ct < 4; ++ct) {
        const int m = m0 + ct * 16 + lr;
        const float xm = xxb[m];
        #pragma unroll
        for (int r = 0; r < 4; ++r) {
            const int n = n0 + w * 16 + lg * 4 + r;
            pd[(size_t)n * N_ + m] = 2.f * acc[ct][r] - xxb[n] - xm;
        }
    }
}

// ------- top-K=20 per row (one wave per row); y = buffer slot (ib = ib0+y) -------
__global__ __launch_bounds__(256) void k_topk(
    const float* __restrict__ pdarena, int* __restrict__ idxb, int ib0)
{
    const int j = blockIdx.y;
    const float* pd = pdarena + (size_t)j * PD_STRIDE;
    const int lane = threadIdx.x & 63;
    const int n = blockIdx.x * 4 + (threadIdx.x >> 6);
    int* out = idxb + ((size_t)(ib0 + j) * N_ + n) * K_;
    const float* row = pd + (size_t)n * N_;
    float v[32];
    #pragma unroll
    for (int jj = 0; jj < 32; ++jj) v[jj] = row[jj * 64 + lane];
    for (int it = 0; it < K_; ++it) {
        float best = -3e38f; int bj = 0;
        #pragma unroll
        for (int jj = 0; jj < 32; ++jj) if (v[jj] > best) { best = v[jj]; bj = jj; }
        int bm = bj * 64 + lane;
        #pragma unroll
        for (int off = 1; off < 64; off <<= 1) {
            const float ov = __shfl_xor(best, off);
            const int   om = __shfl_xor(bm, off);
            if (ov > best || (ov == best && om < bm)) { best = ov; bm = om; }
        }
        if (lane == 0) out[it] = bm;
        if ((bm & 63) == lane) {
            const int jc = bm >> 6;          // static unroll avoids scratch (rule #20)
            #pragma unroll
            for (int jj = 0; jj < 32; ++jj) if (jj == jc) v[jj] = -3e38f;
        }
    }
}

// ---------------- P/Q GEMMs: P=(W1a+W1b)·f, Q=(-W1b)·f ----------------
__global__ __launch_bounds__(256) void k_pq(
    const float* __restrict__ fT, const float* __restrict__ gW1,
    float* __restrict__ P, float* __restrict__ Q)
{
    __shared__ float As[64][68], Bs[64][68];
    const int iz = blockIdx.z;
    const int i = iz >> 2;
    const int n0 = blockIdx.x * 64;
    const int yt = blockIdx.y;           // 0,1 -> P cols; 2,3 -> Q cols
    const bool isQ = (yt >= 2);
    const int oc0 = (yt & 1) * 64;
    const float* fTb = fT + (size_t)iz * N_ * C_;
    const int tm = threadIdx.x & 15, tn = threadIdx.x >> 4;
    float acc[4][4] = {};
    for (int kc = 0; kc < C_; kc += 64) {
        __syncthreads();
        #pragma unroll
        for (int q = 0; q < 4; ++q) {
            const int id = threadIdx.x + 256 * q;
            const int m = id >> 4, c4 = id & 15;
            const float4 va = *(const float4*)(fTb + ((size_t)(n0 + m)) * C_ + kc + c4 * 4);
            As[c4*4+0][m] = va.x; As[c4*4+1][m] = va.y; As[c4*4+2][m] = va.z; As[c4*4+3][m] = va.w;
            const float* wrow = gW1 + ((size_t)i * C_ + oc0 + m) * (2 * C_);
            const float4 wa = *(const float4*)(wrow + kc + c4 * 4);
            const float4 wb = *(const float4*)(wrow + C_ + kc + c4 * 4);
            float4 bv;
            if (isQ) { bv.x = -wb.x; bv.y = -wb.y; bv.z = -wb.z; bv.w = -wb.w; }
            else     { bv.x = wa.x + wb.x; bv.y = wa.y + wb.y; bv.z = wa.z + wb.z; bv.w = wa.w + wb.w; }
            Bs[c4*4+0][m] = bv.x; Bs[c4*4+1][m] = bv.y; Bs[c4*4+2][m] = bv.z; Bs[c4*4+3][m] = bv.w;
        }
        __syncthreads();
        #pragma unroll
        for (int k = 0; k < 64; ++k) {
            const float4 a  = *(const float4*)&As[k][tm * 4];
            const float4 bb = *(const float4*)&Bs[k][tn * 4];
            acc[0][0] += a.x*bb.x; acc[0][1] += a.x*bb.y; acc[0][2] += a.x*bb.z; acc[0][3] += a.x*bb.w;
            acc[1][0] += a.y*bb.x; acc[1][1] += a.y*bb.y; acc[1][2] += a.y*bb.z; acc[1][3] += a.y*bb.w;
            acc[2][0] += a.z*bb.x; acc[2][1] += a.z*bb.y; acc[2][2] += a.z*bb.z; acc[2][3] += a.z*bb.w;
            acc[3][0] += a.w*bb.x; acc[3][1] += a.w*bb.y; acc[3][2] += a.w*bb.z; acc[3][3] += a.w*bb.w;
        }
    }
    float* out = (isQ ? Q : P) + (size_t)iz * N_ * C_;
    #pragma unroll
    for (int rr = 0; rr < 4; ++rr) {
        const float4 st = make_float4(acc[rr][0], acc[rr][1], acc[rr][2], acc[rr][3]);
        *(float4*)(out + ((size_t)(n0 + tm * 4 + rr)) * C_ + oc0 + tn * 4) = st;
    }
}

// ---------------- edge conv2 + max over k : bf16 MFMA version ----------------
__global__ __launch_bounds__(256) void k_edge2(
    const float* __restrict__ P, const float* __restrict__ Q, const int* __restrict__ idxb,
    const float* __restrict__ gb1, const float* __restrict__ gg1, const float* __restrict__ gbe1,
    const float* __restrict__ gW2, const float* __restrict__ gb2, const float* __restrict__ gg2,
    const float* __restrict__ gbe2, float* __restrict__ gT)
{
    __shared__ __align__(16) unsigned short h1s[160 * C_];  // 40 KB
    __shared__ __align__(16) unsigned short W2s[C_ * C_];   // 32 KB
    __shared__ float s1s[C_], t1s[C_], s2s[C_], t2s[C_];
    __shared__ int idxs[160];
    const int i = blockIdx.z, b = blockIdx.y;
    const int p0 = blockIdx.x * 8;
    const int t = threadIdx.x;
    const size_t base = (size_t)(i * B_ + b) * N_;

    if (t < C_) {
        const float bn = sqrtf(1.00001f);
        const float g1 = gg1[i * C_ + t];
        s1s[t] = g1 / bn;
        t1s[t] = gb1[i * C_ + t] * (g1 / bn) + gbe1[i * C_ + t];
        const float g2 = gg2[i * C_ + t];
        s2s[t] = g2 / bn;
        t2s[t] = gb2[i * C_ + t] * (g2 / bn) + gbe2[i * C_ + t];
    }
    if (t < 160) idxs[t] = idxb[base * K_ + p0 * K_ + t];
    __syncthreads();

    const int seg = t & 7;            // fixed 16-element column segment per thread
    const int rb = t >> 3;            // base row / base o
    float4 s1v[4], t1v[4];
    #pragma unroll
    for (int q = 0; q < 4; ++q) {
        s1v[q] = *(const float4*)&s1s[seg * 16 + q * 4];
        t1v[q] = *(const float4*)&t1s[seg * 16 + q * 4];
    }
    // ---- build h1 (bf16, swizzled) ----
    const float* Pb = P + base * C_;
    const float* Qb = Q + base * C_;
    #pragma unroll
    for (int it = 0; it < 5; ++it) {
        const int row = rb + 32 * it;
        const int p = row / 20;
        const int m = idxs[row];
        const float* Pr = Pb + (size_t)(p0 + p) * C_ + seg * 16;
        const float* Qr = Qb + (size_t)m * C_ + seg * 16;
        unsigned int pk[8];
        #pragma unroll
        for (int q = 0; q < 4; ++q) {
            const float4 pv = *(const float4*)(Pr + q * 4);
            const float4 qv = *(const float4*)(Qr + q * 4);
            const float r0 = fmaxf((pv.x + qv.x) * s1v[q].x + t1v[q].x, 0.f);
            const float r1 = fmaxf((pv.y + qv.y) * s1v[q].y + t1v[q].y, 0.f);
            const float r2 = fmaxf((pv.z + qv.z) * s1v[q].z + t1v[q].z, 0.f);
            const float r3 = fmaxf((pv.w + qv.w) * s1v[q].w + t1v[q].w, 0.f);
            pk[q * 2 + 0] = (unsigned int)f2bf(r0) | ((unsigned int)f2bf(r1) << 16);
            pk[q * 2 + 1] = (unsigned int)f2bf(r2) | ((unsigned int)f2bf(r3) << 16);
        }
        const int sw = (row & 7) << 4;
        char* bp = (char*)h1s + row * 256;
        *(u32x4*)(bp + ((seg * 32) ^ sw))      = (u32x4){pk[0], pk[1], pk[2], pk[3]};
        *(u32x4*)(bp + ((seg * 32 + 16) ^ sw)) = (u32x4){pk[4], pk[5], pk[6], pk[7]};
    }
    // ---- stage W2 (bf16, swizzled) ----
    #pragma unroll
    for (int it = 0; it < 4; ++it) {
        const int o = rb + 32 * it;
        const float* wr = gW2 + ((size_t)i * C_ + o) * C_ + seg * 16;
        unsigned int pk[8];
        #pragma unroll
        for (int q = 0; q < 4; ++q) {
            const float4 wv = *(const float4*)(wr + q * 4);
            pk[q * 2 + 0] = (unsigned int)f2bf(wv.x) | ((unsigned int)f2bf(wv.y) << 16);
            pk[q * 2 + 1] = (unsigned int)f2bf(wv.z) | ((unsigned int)f2bf(wv.w) << 16);
        }
        const int sw = (o & 7) << 4;
        char* bp = (char*)W2s + o * 256;
        *(u32x4*)(bp + ((seg * 32) ^ sw))      = (u32x4){pk[0], pk[1], pk[2], pk[3]};
        *(u32x4*)(bp + ((seg * 32 + 16) ^ sw)) = (u32x4){pk[4], pk[5], pk[6], pk[7]};
    }
    __syncthreads();

    // ---- MFMA: D[row][o] = sum_c h1[row][c] * W2[o][c] ----
    const int lane = t & 63, w = t >> 6;
    const int lr = lane & 15, lg = lane >> 4;
    bf16x8 Bf[2][4];
    #pragma unroll
    for (int nb = 0; nb < 2; ++nb)
        #pragma unroll
        for (int ks = 0; ks < 4; ++ks) {
            const int o = w * 32 + nb * 16 + lr;
            const int cb = ks * 64 + lg * 16;          // byte col
            Bf[nb][ks] = __builtin_bit_cast(bf16x8,
                *(const u32x4*)((const char*)W2s + o * 256 + (cb ^ ((o & 7) << 4))));
        }
    f32x4 acc[10][2];
    #pragma unroll
    for (int mt = 0; mt < 10; ++mt)
        #pragma unroll
        for (int nb = 0; nb < 2; ++nb)
            acc[mt][nb] = (f32x4){0.f, 0.f, 0.f, 0.f};
    #pragma unroll
    for (int mt = 0; mt < 10; ++mt) {
        bf16x8 Af[4];
        #pragma unroll
        for (int ks = 0; ks < 4; ++ks) {
            const int row = mt * 16 + lr;
            const int cb = ks * 64 + lg * 16;
            Af[ks] = __builtin_bit_cast(bf16x8,
                *(const u32x4*)((const char*)h1s + row * 256 + (cb ^ ((row & 7) << 4))));
        }
        #pragma unroll
        for (int nb = 0; nb < 2; ++nb)
            #pragma unroll
            for (int ks = 0; ks < 4; ++ks)
                acc[mt][nb] = __builtin_amdgcn_mfma_f32_16x16x32_bf16(
                    Af[ks], Bf[nb][ks], acc[mt][nb], 0, 0, 0);
    }
    __syncthreads();   // all waves done reading h1s

    // ---- epilogue: scale+shift+relu, store h2 bf16 into h1s region ----
    #pragma unroll
    for (int mt = 0; mt < 10; ++mt)
        #pragma unroll
        for (int nb = 0; nb < 2; ++nb) {
            const int col = w * 32 + nb * 16 + lr;
            const float s2c = s2s[col], t2c = t2s[col];
            #pragma unroll
            for (int r = 0; r < 4; ++r) {
                const int row = mt * 16 + lg * 4 + r;
                const float v = fmaxf(acc[mt][nb][r] * s2c + t2c, 0.f);
                *(unsigned short*)((char*)h1s + row * 256 + ((col * 2) ^ ((row & 7) << 4))) = f2bf(v);
            }
        }
    __syncthreads();

    // ---- max over 20 neighbors per point ----
    const int oc = t & 127, ph = t >> 7;
    float* gp = gT + (base + p0) * C_;
    #pragma unroll
    for (int pp = 0; pp < 4; ++pp) {
        const int p = ph * 4 + pp;
        float mx = 0.f;
        #pragma unroll
        for (int j = 0; j < 20; ++j) {
            const int row = p * 20 + j;
            const unsigned short us =
                *(const unsigned short*)((const char*)h1s + row * 256 + ((oc * 2) ^ ((row & 7) << 4)));
            mx = fmaxf(mx, bf2f(us));
        }
        gp[(size_t)p * C_ + oc] = mx;
    }
}

// ---------------- transpose gT [n][c] -> g [c][n] ----------------
__global__ __launch_bounds__(256) void k_transpose2(
    const float* __restrict__ gT, float* __restrict__ g)
{
    __shared__ float tile[32][33];
    const int n0 = blockIdx.x * 32, o0 = blockIdx.y * 32;
    const int iz = blockIdx.z;
    const int tx = threadIdx.x, ty = threadIdx.y;
    #pragma unroll
    for (int q = 0; q < 4; ++q) {
        const int n = n0 + ty + q * 8;
        tile[ty + q * 8][tx] = gT[((size_t)iz * N_ + n) * C_ + o0 + tx];
    }
    __syncthreads();
    #pragma unroll
    for (int q = 0; q < 4; ++q) {
        const int o = o0 + ty + q * 8;
        g[((size_t)iz * C_ + o) * N_ + n0 + tx] = tile[tx][ty + q * 8];
    }
}

// ---------------- l2 norms over N for q,k branches ----------------
__global__ __launch_bounds__(256) void k_l2norm(const float* __restrict__ g, float* __restrict__ norms)
{
    const int r = blockIdx.x;       // [0, 2*B*C)
    const float* row = g + (size_t)r * N_;
    float s = 0.f;
    for (int n = threadIdx.x; n < N_; n += 256) { const float v = row[n]; s += v * v; }
    #pragma unroll
    for (int off = 32; off > 0; off >>= 1) s += __shfl_down(s, off);
    __shared__ float red[4];
    if ((threadIdx.x & 63) == 0) red[threadIdx.x >> 6] = s;
    __syncthreads();
    if (threadIdx.x == 0)
        norms[r] = fmaxf(sqrtf(red[0] + red[1] + red[2] + red[3]), 1e-12f);
}

// ---------------- attention scores + softmax (one q-row per block) ----------------
__global__ __launch_bounds__(256) void k_attn(
    const float* __restrict__ g, const float* __restrict__ norms,
    const float* __restrict__ temp, float* __restrict__ attn)
{
    __shared__ float qs[N_];
    __shared__ float rowv[32];
    const int r = blockIdx.x;                 // b*128 + h*32 + c
    const int c = r & 31, h = (r >> 5) & 3, b = r >> 7;
    const float* qrow  = g + ((size_t)(0 * B_ + b) * C_ + h * 32 + c) * N_;
    const float* krows = g + ((size_t)(1 * B_ + b) * C_ + h * 32) * N_;
    for (int n = threadIdx.x; n < N_; n += 256) qs[n] = qrow[n];
    __syncthreads();
    const int d = threadIdx.x >> 3, s = threadIdx.x & 7;
    const float* kr = krows + (size_t)d * N_;
    float acc = 0.f;
    for (int m = 0; m < N_ / 32; ++m) {
        const int n = (m * 8 + s) * 4;
        const float4 kv = *(const float4*)(kr + n);
        acc += qs[n] * kv.x + qs[n+1] * kv.y + qs[n+2] * kv.z + qs[n+3] * kv.w;
    }
    #pragma unroll
    for (int off = 1; off < 8; off <<= 1) acc += __shfl_xor(acc, off);
    if (s == 0) rowv[d] = acc;
    __syncthreads();
    if (threadIdx.x < 32) {
        const int dd = threadIdx.x;
        const float nq = norms[(size_t)(0 * B_ + b) * C_ + h * 32 + c];
        const float nk = norms[(size_t)(1 * B_ + b) * C_ + h * 32 + dd];
        const float v = rowv[dd] / (nq * nk) * temp[h];
        float mx = v;
        #pragma unroll
        for (int off = 1; off < 32; off <<= 1) mx = fmaxf(mx, __shfl_xor(mx, off));
        const float e = expf(v - mx);
        float sm = e;
        #pragma unroll
        for (int off = 1; off < 32; off <<= 1) sm += __shfl_xor(sm, off);
        attn[(size_t)r * 32 + dd] = e / sm;
    }
}

// ---------------- attn @ v ----------------
__global__ __launch_bounds__(256) void k_av(
    const float* __restrict__ attn, const float* __restrict__ g, float* __restrict__ av)
{
    __shared__ float at[32][32];
    const int n = blockIdx.x * 256 + threadIdx.x;
    const int h = blockIdx.y, b = blockIdx.z;
    for (int t2 = threadIdx.x; t2 < 1024; t2 += 256)
        at[t2 >> 5][t2 & 31] = attn[((size_t)(b * H_ + h)) * 1024 + t2];
    __syncthreads();
    const float* vrows = g + ((size_t)(2 * B_ + b) * C_ + h * 32) * N_;
    float acc[32] = {};
    for (int dd = 0; dd < 32; ++dd) {
        const float vv = vrows[(size_t)dd * N_ + n];
        #pragma unroll
        for (int cc = 0; cc < 32; ++cc) acc[cc] += at[cc][dd] * vv;
    }
    float* avb = av + ((size_t)b * C_ + h * 32) * N_ + n;
    #pragma unroll
    for (int cc = 0; cc < 32; ++cc) avb[(size_t)cc * N_] = acc[cc];
}

// ---------------- projection + bias + residual ----------------
__global__ __launch_bounds__(256) void k_proj(
    const float* __restrict__ av, const float* __restrict__ pW, const float* __restrict__ pb,
    const float* __restrict__ x, float* __restrict__ out)
{
    __shared__ float Ws[8][C_];
    const int n = blockIdx.x * 256 + threadIdx.x;
    const int o0 = blockIdx.y * 8;
    const int b = blockIdx.z;
    for (int t = threadIdx.x; t < 8 * C_; t += 256) {
        const int j = t >> 7, c = t & 127;
        Ws[j][c] = pW[(size_t)(o0 + j) * C_ + c];
    }
    __syncthreads();
    float acc[8] = {};
    const float* ab = av + ((size_t)b * C_) * N_ + n;
    #pragma unroll 4
    for (int c = 0; c < C_; ++c) {
        const float vv = ab[(size_t)c * N_];
        #pragma unroll
        for (int j = 0; j < 8; ++j) acc[j] += Ws[j][c] * vv;
    }
    #pragma unroll
    for (int j = 0; j < 8; ++j) {
        const int o = o0 + j;
        const size_t off = ((size_t)b * C_ + o) * N_ + n;
        out[off] = acc[j] + pb[o] + x[off];
    }
}

extern "C" void kernel_launch(void* const* d_in, const int* in_sizes, int n_in,
                              void* d_out, int out_size, void* d_ws, size_t ws_size,
                              hipStream_t stream)
{
    const float* x    = (const float*)d_in[0];
    const float* fW   = (const float*)d_in[1];
    const float* fb   = (const float*)d_in[2];
    const float* fg   = (const float*)d_in[3];
    const float* fbe  = (const float*)d_in[4];
    const float* gW1  = (const float*)d_in[5];
    const float* gb1  = (const float*)d_in[6];
    const float* gg1  = (const float*)d_in[7];
    const float* gbe1 = (const float*)d_in[8];
    const float* gW2  = (const float*)d_in[9];
    const float* gb2  = (const float*)d_in[10];
    const float* gg2  = (const float*)d_in[11];
    const float* gbe2 = (const float*)d_in[12];
    const float* pW   = (const float*)d_in[13];
    const float* pb   = (const float*)d_in[14];
    const float* temp = (const float*)d_in[15];
    float* ws = (float*)d_ws;

    float* arena = ws;                 // Y pre-knn / 4 pd buffers / P,Q,GT,AV
    float* y    = ws + OFF_Y;
    float* P    = ws + OFF_P;
    float* Q    = ws + OFF_Q;
    float* gT   = ws + OFF_GT;
    float* av   = ws + OFF_AV;
    float* fT   = ws + OFF_FT;
    float* sc   = ws + OFF_SC;
    float* sh   = ws + OFF_SH;
    float* xx   = ws + OFF_XX;
    int*   idxb = (int*)(ws + OFF_IDX);
    float* g    = ws + OFF_G;
    float* nrm  = ws + OFF_NRM;
    float* attn = ws + OFF_ATT;
    // bf16 hi/lo feature planes live in the (not-yet-written) OFF_G region
    unsigned short* fH = (unsigned short*)g;
    unsigned short* fL = fH + (size_t)12 * N_ * C_;

    k_filter_conv<<<dim3(N_/256, C_/8, 12), 256, 0, stream>>>(x, fW, fb, y);
    k_rowstats<<<12 * C_, 256, 0, stream>>>(y, fg, fbe, sc, sh);
    k_norm_transpose<<<dim3(N_/32, C_/32, 12), dim3(32, 8), 0, stream>>>(y, sc, sh, fT, fH, fL);
    k_xx<<<(12 * N_) / 256, 256, 0, stream>>>(fT, xx);
    for (int g4 = 0; g4 < 3; ++g4) {   // 4-wide batched knn (Y is dead now)
        k_pd_mfma<<<dim3(N_/64, N_/64, 4), 256, 0, stream>>>(fH, fL, xx, arena, g4 * 4);
        k_topk<<<dim3(N_/4, 4), 256, 0, stream>>>(arena, idxb, g4 * 4);
    }
    k_pq<<<dim3(N_/64, 4, 12), 256, 0, stream>>>(fT, gW1, P, Q);
    k_edge2<<<dim3(N_/8, B_, 3), 256, 0, stream>>>(P, Q, idxb, gb1, gg1, gbe1,
                                                   gW2, gb2, gg2, gbe2, gT);
    k_transpose2<<<dim3(N_/32, C_/32, 12), dim3(32, 8), 0, stream>>>(gT, g);
    k_l2norm<<<2 * B_ * C_, 256, 0, stream>>>(g, nrm);
    k_attn<<<B_ * H_ * 32, 256, 0, stream>>>(g, nrm, temp, attn);
    k_av<<<dim3(N_/256, H_, B_), 256, 0, stream>>>(attn, g, av);
    k_proj<<<dim3(N_/256, C_/8, B_), 256, 0, stream>>>(av, pW, pb, x, (float*)d_out);
    (void)in_sizes; (void)n_in; (void)out_size; (void)ws_size;
}

// Round 6
// 499.756 us; speedup vs baseline: 2.5663x; 1.0435x over previous
//
#include <hip/hip_runtime.h>
#include <math.h>

// R5: (1) LDS swizzle (row&7)<<4 -> (row&15)<<4 in pd/edge2 (fragment reads
// group 16 rows; 3-bit XOR left an ~8-way conflict: SQ_LDS_BANK_CONFLICT 4.5M
// on edge2). (2) k_pq fp32 -> k_pq_mfma split-bf16 (A = existing fH/fL planes,
// B = weight combos split at stage). (3) fT dropped (pq was last consumer);
// k_xx reads the planes. Everything else unchanged from R4 (absmax 0.0625).

#define B_ 4
#define C_ 128
#define N_ 2048
#define H_ 4
#define K_ 20

typedef __bf16 bf16x8 __attribute__((ext_vector_type(8)));
typedef float f32x4 __attribute__((ext_vector_type(4)));
typedef unsigned int u32x4 __attribute__((ext_vector_type(4)));

__device__ __forceinline__ unsigned short f2bf(float f) {
    unsigned int u = __builtin_bit_cast(unsigned int, f);
    u += 0x7fffu + ((u >> 16) & 1u);       // RNE
    return (unsigned short)(u >> 16);
}
__device__ __forceinline__ float bf2f(unsigned short s) {
    return __builtin_bit_cast(float, (unsigned int)s << 16);
}

// ---- workspace layout (float offsets) ----
// ARENA [0, 16777216): Y pre-knn | 4 pd buffers during knn | P,Q,GT,AV after.
#define PD_STRIDE 4194304
#define OFF_Y     0
#define OFF_P     0
#define OFF_Q     3145728
#define OFF_GT    6291456
#define OFF_AV    9437184
#define OFF_SC    19922944   // 1536
#define OFF_SH    19924480   // 1536
#define OFF_XX    19926016   // 24576
#define OFF_IDX   19950592   // 3*B*N*K ints (491520)
#define OFF_G     20442112   // 3145728: fH/fL bf16 planes during knn, g after
#define OFF_NRM   23587840   // 1024
#define OFF_ATT   23588864   // 16384
// total = 23,605,248 floats = 94.4 MB

// ---------------- filter: 1x1 conv ----------------
__global__ __launch_bounds__(256) void k_filter_conv(
    const float* __restrict__ x, const float* __restrict__ fW,
    const float* __restrict__ fb, float* __restrict__ y)
{
    __shared__ float Ws[8][C_];
    const int n = blockIdx.x * 256 + threadIdx.x;
    const int o0 = blockIdx.y * 8;
    const int iz = blockIdx.z;                 // i*B + b
    const int i = iz >> 2, b = iz & 3;
    for (int t = threadIdx.x; t < 8 * C_; t += 256) {
        const int j = t >> 7, c = t & 127;
        Ws[j][c] = fW[((size_t)i * C_ + o0 + j) * C_ + c];
    }
    __syncthreads();
    float acc[8] = {};
    const float* xb = x + ((size_t)b * C_) * N_ + n;
    #pragma unroll 4
    for (int c = 0; c < C_; ++c) {
        const float xv = xb[(size_t)c * N_];
        #pragma unroll
        for (int j = 0; j < 8; ++j) acc[j] += Ws[j][c] * xv;
    }
    float* yb = y + ((size_t)iz * C_ + o0) * N_ + n;
    #pragma unroll
    for (int j = 0; j < 8; ++j) yb[(size_t)j * N_] = acc[j] + fb[i * C_ + o0 + j];
}

// ---------------- instance-norm row stats ----------------
__global__ __launch_bounds__(256) void k_rowstats(
    const float* __restrict__ y, const float* __restrict__ fg,
    const float* __restrict__ fbe, float* __restrict__ scale, float* __restrict__ shift)
{
    const int r = blockIdx.x;                  // (i*B+b)*C + o
    const int i = r >> 9, o = r & 127;
    const float* row = y + (size_t)r * N_;
    float s = 0.f, ss = 0.f;
    for (int n = threadIdx.x; n < N_; n += 256) {
        const float v = row[n];
        s += v; ss += v * v;
    }
    #pragma unroll
    for (int off = 32; off > 0; off >>= 1) {
        s += __shfl_down(s, off);
        ss += __shfl_down(ss, off);
    }
    __shared__ float red[2][4];
    const int wid = threadIdx.x >> 6;
    if ((threadIdx.x & 63) == 0) { red[0][wid] = s; red[1][wid] = ss; }
    __syncthreads();
    if (threadIdx.x == 0) {
        s = red[0][0] + red[0][1] + red[0][2] + red[0][3];
        ss = red[1][0] + red[1][1] + red[1][2] + red[1][3];
        const float mean = s * (1.f / N_);
        const float var = ss * (1.f / N_) - mean * mean;
        const float bn = sqrtf(1.00001f);
        const float sc = fg[i * C_ + o] / (bn * sqrtf(var + 1e-3f));
        scale[r] = sc;
        shift[r] = fbe[i * C_ + o] - mean * sc;
    }
}

// ------- normalize + relu + transpose to [n][c]; emit bf16 hi/lo planes -------
__global__ __launch_bounds__(256) void k_norm_transpose(
    const float* __restrict__ y, const float* __restrict__ scale,
    const float* __restrict__ shift,
    unsigned short* __restrict__ fH, unsigned short* __restrict__ fL)
{
    __shared__ float tile[32][33];
    const int n0 = blockIdx.x * 32, o0 = blockIdx.y * 32;
    const int iz = blockIdx.z;
    const int tx = threadIdx.x, ty = threadIdx.y;
    #pragma unroll
    for (int q = 0; q < 4; ++q) {
        const int o = o0 + ty + q * 8;
        const int r = iz * C_ + o;
        const float v = y[(size_t)r * N_ + n0 + tx] * scale[r] + shift[r];
        tile[ty + q * 8][tx] = fmaxf(v, 0.f);
    }
    __syncthreads();
    #pragma unroll
    for (int q = 0; q < 4; ++q) {
        const int n = n0 + ty + q * 8;
        const size_t idx = ((size_t)iz * N_ + n) * C_ + o0 + tx;
        const float v = tile[tx][ty + q * 8];
        const unsigned short hi = f2bf(v);
        fH[idx] = hi;
        fL[idx] = f2bf(v - bf2f(hi));
    }
}

// ---------------- per-point squared norm (from hi/lo planes) ----------------
__global__ __launch_bounds__(256) void k_xx(
    const unsigned short* __restrict__ fH, const unsigned short* __restrict__ fL,
    float* __restrict__ xx)
{
    const int r = blockIdx.x * 256 + threadIdx.x;   // [0, 3*B*N)
    const u32x4* rh = (const u32x4*)(fH + (size_t)r * C_);
    const u32x4* rl = (const u32x4*)(fL + (size_t)r * C_);
    float s = 0.f;
    #pragma unroll
    for (int q = 0; q < 16; ++q) {
        const u32x4 hv = rh[q], lv = rl[q];
        #pragma unroll
        for (int e = 0; e < 4; ++e) {
            const unsigned int h = hv[e], l = lv[e];
            const float v0 = bf2f((unsigned short)(h & 0xFFFFu)) + bf2f((unsigned short)(l & 0xFFFFu));
            const float v1 = bf2f((unsigned short)(h >> 16)) + bf2f((unsigned short)(l >> 16));
            s += v0 * v0 + v1 * v1;
        }
    }
    xx[r] = s;
}

// ------- pairwise -dist^2 via split-bf16 MFMA; z = buffer slot (ib = ib0+z) -------
__global__ __launch_bounds__(256) void k_pd_mfma(
    const unsigned short* __restrict__ fH, const unsigned short* __restrict__ fL,
    const float* __restrict__ xx, float* __restrict__ pdarena, int ib0)
{
    __shared__ __align__(16) unsigned short Ah[64 * C_], Al[64 * C_];
    __shared__ __align__(16) unsigned short Bh[64 * C_], Bl[64 * C_];
    const int j = blockIdx.z, ib = ib0 + j;
    const unsigned short* fHb = fH + (size_t)ib * N_ * C_;
    const unsigned short* fLb = fL + (size_t)ib * N_ * C_;
    const float* xxb = xx + ib * N_;
    float* pd = pdarena + (size_t)j * PD_STRIDE;
    const int n0 = blockIdx.x * 64, m0 = blockIdx.y * 64;
    const int t = threadIdx.x;
    {   // stage 4 bf16 planes (swizzle: byte ^= (row&15)<<4, bijective in 256B row)
        const int s = t & 15, rb = t >> 4;
        #pragma unroll
        for (int q = 0; q < 4; ++q) {
            const int r = rb + q * 16;
            const int ld = r * 256 + ((s * 16) ^ ((r & 15) << 4));
            *(u32x4*)((char*)Ah + ld) = *(const u32x4*)((const char*)fHb + (size_t)(n0 + r) * 256 + s * 16);
            *(u32x4*)((char*)Al + ld) = *(const u32x4*)((const char*)fLb + (size_t)(n0 + r) * 256 + s * 16);
            *(u32x4*)((char*)Bh + ld) = *(const u32x4*)((const char*)fHb + (size_t)(m0 + r) * 256 + s * 16);
            *(u32x4*)((char*)Bl + ld) = *(const u32x4*)((const char*)fLb + (size_t)(m0 + r) * 256 + s * 16);
        }
    }
    __syncthreads();
    const int lane = t & 63, w = t >> 6;       // wave w owns rows [w*16, w*16+16)
    const int lr = lane & 15, lg = lane >> 4;
    f32x4 acc[4];
    #pragma unroll
    for (int ct = 0; ct < 4; ++ct) acc[ct] = (f32x4){0.f, 0.f, 0.f, 0.f};
    #pragma unroll
    for (int ks = 0; ks < 4; ++ks) {           // K = 128, 32 per MFMA
        const int arow = w * 16 + lr;
        const int cb = ks * 64 + lg * 16;      // byte col within 256B row
        const bf16x8 ah = __builtin_bit_cast(bf16x8,
            *(const u32x4*)((const char*)Ah + arow * 256 + (cb ^ ((arow & 15) << 4))));
        const bf16x8 al = __builtin_bit_cast(bf16x8,
            *(const u32x4*)((const char*)Al + arow * 256 + (cb ^ ((arow & 15) << 4))));
        #pragma unroll
        for (int ct = 0; ct < 4; ++ct) {
            const int brow = ct * 16 + lr;
            const int boff = brow * 256 + (cb ^ ((brow & 15) << 4));
            const bf16x8 bh = __builtin_bit_cast(bf16x8, *(const u32x4*)((const char*)Bh + boff));
            const bf16x8 bl = __builtin_bit_cast(bf16x8, *(const u32x4*)((const char*)Bl + boff));
            acc[ct] = __builtin_amdgcn_mfma_f32_16x16x32_bf16(ah, bh, acc[ct], 0, 0, 0);
            acc[ct] = __builtin_amdgcn_mfma_f32_16x16x32_bf16(ah, bl, acc[ct], 0, 0, 0);
            acc[ct] = __builtin_amdgcn_mfma_f32_16x16x32_bf16(al, bh, acc[ct], 0, 0, 0);
        }
    }
    // epilogue: D col=lane&15, row=(lane>>4)*4+r  (m89/m91-verified mapping)
    #pragma unroll
    for (int ct = 0; ct < 4; ++ct) {
        const int m = m0 + ct * 16 + lr;
        const float xm = xxb[m];
        #pragma unroll
        for (int r = 0; r < 4; ++r) {
            const int n = n0 + w * 16 + lg * 4 + r;
            pd[(size_t)n * N_ + m] = 2.f * acc[ct][r] - xxb[n] - xm;
        }
    }
}

// ------- top-K=20 per row (one wave per row); y = buffer slot (ib = ib0+y) -------
__global__ __launch_bounds__(256) void k_topk(
    const float* __restrict__ pdarena, int* __restrict__ idxb, int ib0)
{
    const int j = blockIdx.y;
    const float* pd = pdarena + (size_t)j * PD_STRIDE;
    const int lane = threadIdx.x & 63;
    const int n = blockIdx.x * 4 + (threadIdx.x >> 6);
    int* out = idxb + ((size_t)(ib0 + j) * N_ + n) * K_;
    const float* row = pd + (size_t)n * N_;
    float v[32];
    #pragma unroll
    for (int jj = 0; jj < 32; ++jj) v[jj] = row[jj * 64 + lane];
    for (int it = 0; it < K_; ++it) {
        float best = -3e38f; int bj = 0;
        #pragma unroll
        for (int jj = 0; jj < 32; ++jj) if (v[jj] > best) { best = v[jj]; bj = jj; }
        int bm = bj * 64 + lane;
        #pragma unroll
        for (int off = 1; off < 64; off <<= 1) {
            const float ov = __shfl_xor(best, off);
            const int   om = __shfl_xor(bm, off);
            if (ov > best || (ov == best && om < bm)) { best = ov; bm = om; }
        }
        if (lane == 0) out[it] = bm;
        if ((bm & 63) == lane) {
            const int jc = bm >> 6;          // static unroll avoids scratch (rule #20)
            #pragma unroll
            for (int jj = 0; jj < 32; ++jj) if (jj == jc) v[jj] = -3e38f;
        }
    }
}

// ------- P/Q GEMMs via split-bf16 MFMA: P=(W1a+W1b)·f, Q=(-W1b)·f -------
__global__ __launch_bounds__(256) void k_pq_mfma(
    const unsigned short* __restrict__ fH, const unsigned short* __restrict__ fL,
    const float* __restrict__ gW1, float* __restrict__ P, float* __restrict__ Q)
{
    __shared__ __align__(16) unsigned short Ah[64 * C_], Al[64 * C_];
    __shared__ __align__(16) unsigned short Bh[64 * C_], Bl[64 * C_];
    const int iz = blockIdx.z, i = iz >> 2;
    const int n0 = blockIdx.x * 64;
    const int yt = blockIdx.y;           // 0,1 -> P col-halves; 2,3 -> Q col-halves
    const bool isQ = (yt >= 2);
    const int oc0 = (yt & 1) * 64;
    const int t = threadIdx.x;
    const unsigned short* fHb = fH + (size_t)iz * N_ * C_;
    const unsigned short* fLb = fL + (size_t)iz * N_ * C_;
    {   // A: straight copy of hi/lo planes
        const int s = t & 15, rb = t >> 4;
        #pragma unroll
        for (int q = 0; q < 4; ++q) {
            const int r = rb + q * 16;
            const int ld = r * 256 + ((s * 16) ^ ((r & 15) << 4));
            *(u32x4*)((char*)Ah + ld) = *(const u32x4*)((const char*)fHb + (size_t)(n0 + r) * 256 + s * 16);
            *(u32x4*)((char*)Al + ld) = *(const u32x4*)((const char*)fLb + (size_t)(n0 + r) * 256 + s * 16);
        }
    }
    {   // B: weight combos (fp32 combine -> split hi/lo)
        const int cs = t & 15, ro = t >> 4;  // cs: 8-elem col segment
        #pragma unroll
        for (int q = 0; q < 4; ++q) {
            const int o = ro + q * 16;
            const float* wrow = gW1 + ((size_t)i * C_ + oc0 + o) * (2 * C_) + cs * 8;
            const float4 a0 = *(const float4*)(wrow);
            const float4 a1 = *(const float4*)(wrow + 4);
            const float4 b0 = *(const float4*)(wrow + C_);
            const float4 b1 = *(const float4*)(wrow + C_ + 4);
            float cmb[8];
            if (isQ) {
                cmb[0] = -b0.x; cmb[1] = -b0.y; cmb[2] = -b0.z; cmb[3] = -b0.w;
                cmb[4] = -b1.x; cmb[5] = -b1.y; cmb[6] = -b1.z; cmb[7] = -b1.w;
            } else {
                cmb[0] = a0.x + b0.x; cmb[1] = a0.y + b0.y; cmb[2] = a0.z + b0.z; cmb[3] = a0.w + b0.w;
                cmb[4] = a1.x + b1.x; cmb[5] = a1.y + b1.y; cmb[6] = a1.z + b1.z; cmb[7] = a1.w + b1.w;
            }
            unsigned int ph[4], pl[4];
            #pragma unroll
            for (int e = 0; e < 4; ++e) {
                const unsigned short h0 = f2bf(cmb[e * 2 + 0]);
                const unsigned short h1 = f2bf(cmb[e * 2 + 1]);
                const unsigned short l0 = f2bf(cmb[e * 2 + 0] - bf2f(h0));
                const unsigned short l1 = f2bf(cmb[e * 2 + 1] - bf2f(h1));
                ph[e] = (unsigned int)h0 | ((unsigned int)h1 << 16);
                pl[e] = (unsigned int)l0 | ((unsigned int)l1 << 16);
            }
            const int ld = o * 256 + ((cs * 16) ^ ((o & 15) << 4));
            *(u32x4*)((char*)Bh + ld) = (u32x4){ph[0], ph[1], ph[2], ph[3]};
            *(u32x4*)((char*)Bl + ld) = (u32x4){pl[0], pl[1], pl[2], pl[3]};
        }
    }
    __syncthreads();
    const int lane = t & 63, w = t >> 6;
    const int lr = lane & 15, lg = lane >> 4;
    f32x4 acc[4];
    #pragma unroll
    for (int ct = 0; ct < 4; ++ct) acc[ct] = (f32x4){0.f, 0.f, 0.f, 0.f};
    #pragma unroll
    for (int ks = 0; ks < 4; ++ks) {
        const int arow = w * 16 + lr;
        const int cb = ks * 64 + lg * 16;
        const bf16x8 ah = __builtin_bit_cast(bf16x8,
            *(const u32x4*)((const char*)Ah + arow * 256 + (cb ^ ((arow & 15) << 4))));
        const bf16x8 al = __builtin_bit_cast(bf16x8,
            *(const u32x4*)((const char*)Al + arow * 256 + (cb ^ ((arow & 15) << 4))));
        #pragma unroll
        for (int ct = 0; ct < 4; ++ct) {
            const int brow = ct * 16 + lr;
            const int boff = brow * 256 + (cb ^ ((brow & 15) << 4));
            const bf16x8 bh = __builtin_bit_cast(bf16x8, *(const u32x4*)((const char*)Bh + boff));
            const bf16x8 bl = __builtin_bit_cast(bf16x8, *(const u32x4*)((const char*)Bl + boff));
            acc[ct] = __builtin_amdgcn_mfma_f32_16x16x32_bf16(ah, bh, acc[ct], 0, 0, 0);
            acc[ct] = __builtin_amdgcn_mfma_f32_16x16x32_bf16(ah, bl, acc[ct], 0, 0, 0);
            acc[ct] = __builtin_amdgcn_mfma_f32_16x16x32_bf16(al, bh, acc[ct], 0, 0, 0);
        }
    }
    float* outp = (isQ ? Q : P) + (size_t)iz * N_ * C_;
    #pragma unroll
    for (int ct = 0; ct < 4; ++ct) {
        #pragma unroll
        for (int r = 0; r < 4; ++r) {
            const int n = n0 + w * 16 + lg * 4 + r;
            outp[(size_t)n * C_ + oc0 + ct * 16 + lr] = acc[ct][r];
        }
    }
}

// ---------------- edge conv2 + max over k : bf16 MFMA version ----------------
__global__ __launch_bounds__(256) void k_edge2(
    const float* __restrict__ P, const float* __restrict__ Q, const int* __restrict__ idxb,
    const float* __restrict__ gb1, const float* __restrict__ gg1, const float* __restrict__ gbe1,
    const float* __restrict__ gW2, const float* __restrict__ gb2, const float* __restrict__ gg2,
    const float* __restrict__ gbe2, float* __restrict__ gT)
{
    __shared__ __align__(16) unsigned short h1s[160 * C_];  // 40 KB
    __shared__ __align__(16) unsigned short W2s[C_ * C_];   // 32 KB
    __shared__ float s1s[C_], t1s[C_], s2s[C_], t2s[C_];
    __shared__ int idxs[160];
    const int i = blockIdx.z, b = blockIdx.y;
    const int p0 = blockIdx.x * 8;
    const int t = threadIdx.x;
    const size_t base = (size_t)(i * B_ + b) * N_;

    if (t < C_) {
        const float bn = sqrtf(1.00001f);
        const float g1 = gg1[i * C_ + t];
        s1s[t] = g1 / bn;
        t1s[t] = gb1[i * C_ + t] * (g1 / bn) + gbe1[i * C_ + t];
        const float g2 = gg2[i * C_ + t];
        s2s[t] = g2 / bn;
        t2s[t] = gb2[i * C_ + t] * (g2 / bn) + gbe2[i * C_ + t];
    }
    if (t < 160) idxs[t] = idxb[base * K_ + p0 * K_ + t];
    __syncthreads();

    const int seg = t & 7;            // fixed 16-element column segment per thread
    const int rb = t >> 3;            // base row / base o
    float4 s1v[4], t1v[4];
    #pragma unroll
    for (int q = 0; q < 4; ++q) {
        s1v[q] = *(const float4*)&s1s[seg * 16 + q * 4];
        t1v[q] = *(const float4*)&t1s[seg * 16 + q * 4];
    }
    // ---- build h1 (bf16, swizzled: byte ^= (row&15)<<4) ----
    const float* Pb = P + base * C_;
    const float* Qb = Q + base * C_;
    #pragma unroll
    for (int it = 0; it < 5; ++it) {
        const int row = rb + 32 * it;
        const int p = row / 20;
        const int m = idxs[row];
        const float* Pr = Pb + (size_t)(p0 + p) * C_ + seg * 16;
        const float* Qr = Qb + (size_t)m * C_ + seg * 16;
        unsigned int pk[8];
        #pragma unroll
        for (int q = 0; q < 4; ++q) {
            const float4 pv = *(const float4*)(Pr + q * 4);
            const float4 qv = *(const float4*)(Qr + q * 4);
            const float r0 = fmaxf((pv.x + qv.x) * s1v[q].x + t1v[q].x, 0.f);
            const float r1 = fmaxf((pv.y + qv.y) * s1v[q].y + t1v[q].y, 0.f);
            const float r2 = fmaxf((pv.z + qv.z) * s1v[q].z + t1v[q].z, 0.f);
            const float r3 = fmaxf((pv.w + qv.w) * s1v[q].w + t1v[q].w, 0.f);
            pk[q * 2 + 0] = (unsigned int)f2bf(r0) | ((unsigned int)f2bf(r1) << 16);
            pk[q * 2 + 1] = (unsigned int)f2bf(r2) | ((unsigned int)f2bf(r3) << 16);
        }
        const int sw = (row & 15) << 4;
        char* bp = (char*)h1s + row * 256;
        *(u32x4*)(bp + ((seg * 32) ^ sw))      = (u32x4){pk[0], pk[1], pk[2], pk[3]};
        *(u32x4*)(bp + ((seg * 32 + 16) ^ sw)) = (u32x4){pk[4], pk[5], pk[6], pk[7]};
    }
    // ---- stage W2 (bf16, swizzled) ----
    #pragma unroll
    for (int it = 0; it < 4; ++it) {
        const int o = rb + 32 * it;
        const float* wr = gW2 + ((size_t)i * C_ + o) * C_ + seg * 16;
        unsigned int pk[8];
        #pragma unroll
        for (int q = 0; q < 4; ++q) {
            const float4 wv = *(const float4*)(wr + q * 4);
            pk[q * 2 + 0] = (unsigned int)f2bf(wv.x) | ((unsigned int)f2bf(wv.y) << 16);
            pk[q * 2 + 1] = (unsigned int)f2bf(wv.z) | ((unsigned int)f2bf(wv.w) << 16);
        }
        const int sw = (o & 15) << 4;
        char* bp = (char*)W2s + o * 256;
        *(u32x4*)(bp + ((seg * 32) ^ sw))      = (u32x4){pk[0], pk[1], pk[2], pk[3]};
        *(u32x4*)(bp + ((seg * 32 + 16) ^ sw)) = (u32x4){pk[4], pk[5], pk[6], pk[7]};
    }
    __syncthreads();

    // ---- MFMA: D[row][o] = sum_c h1[row][c] * W2[o][c] ----
    const int lane = t & 63, w = t >> 6;
    const int lr = lane & 15, lg = lane >> 4;
    bf16x8 Bf[2][4];
    #pragma unroll
    for (int nb = 0; nb < 2; ++nb)
        #pragma unroll
        for (int ks = 0; ks < 4; ++ks) {
            const int o = w * 32 + nb * 16 + lr;
            const int cb = ks * 64 + lg * 16;          // byte col
            Bf[nb][ks] = __builtin_bit_cast(bf16x8,
                *(const u32x4*)((const char*)W2s + o * 256 + (cb ^ ((o & 15) << 4))));
        }
    f32x4 acc[10][2];
    #pragma unroll
    for (int mt = 0; mt < 10; ++mt)
        #pragma unroll
        for (int nb = 0; nb < 2; ++nb)
            acc[mt][nb] = (f32x4){0.f, 0.f, 0.f, 0.f};
    #pragma unroll
    for (int mt = 0; mt < 10; ++mt) {
        bf16x8 Af[4];
        #pragma unroll
        for (int ks = 0; ks < 4; ++ks) {
            const int row = mt * 16 + lr;
            const int cb = ks * 64 + lg * 16;
            Af[ks] = __builtin_bit_cast(bf16x8,
                *(const u32x4*)((const char*)h1s + row * 256 + (cb ^ ((row & 15) << 4))));
        }
        #pragma unroll
        for (int nb = 0; nb < 2; ++nb)
            #pragma unroll
            for (int ks = 0; ks < 4; ++ks)
                acc[mt][nb] = __builtin_amdgcn_mfma_f32_16x16x32_bf16(
                    Af[ks], Bf[nb][ks], acc[mt][nb], 0, 0, 0);
    }
    __syncthreads();   // all waves done reading h1s

    // ---- epilogue: scale+shift+relu, store h2 bf16 into h1s region ----
    #pragma unroll
    for (int mt = 0; mt < 10; ++mt)
        #pragma unroll
        for (int nb = 0; nb < 2; ++nb) {
            const int col = w * 32 + nb * 16 + lr;
            const float s2c = s2s[col], t2c = t2s[col];
            #pragma unroll
            for (int r = 0; r < 4; ++r) {
                const int row = mt * 16 + lg * 4 + r;
                const float v = fmaxf(acc[mt][nb][r] * s2c + t2c, 0.f);
                *(unsigned short*)((char*)h1s + row * 256 + ((col * 2) ^ ((row & 15) << 4))) = f2bf(v);
            }
        }
    __syncthreads();

    // ---- max over 20 neighbors per point ----
    const int oc = t & 127, ph = t >> 7;
    float* gp = gT + (base + p0) * C_;
    #pragma unroll
    for (int pp = 0; pp < 4; ++pp) {
        const int p = ph * 4 + pp;
        float mx = 0.f;
        #pragma unroll
        for (int j = 0; j < 20; ++j) {
            const int row = p * 20 + j;
            const unsigned short us =
                *(const unsigned short*)((const char*)h1s + row * 256 + ((oc * 2) ^ ((row & 15) << 4)));
            mx = fmaxf(mx, bf2f(us));
        }
        gp[(size_t)p * C_ + oc] = mx;
    }
}

// ---------------- transpose gT [n][c] -> g [c][n] ----------------
__global__ __launch_bounds__(256) void k_transpose2(
    const float* __restrict__ gT, float* __restrict__ g)
{
    __shared__ float tile[32][33];
    const int n0 = blockIdx.x * 32, o0 = blockIdx.y * 32;
    const int iz = blockIdx.z;
    const int tx = threadIdx.x, ty = threadIdx.y;
    #pragma unroll
    for (int q = 0; q < 4; ++q) {
        const int n = n0 + ty + q * 8;
        tile[ty + q * 8][tx] = gT[((size_t)iz * N_ + n) * C_ + o0 + tx];
    }
    __syncthreads();
    #pragma unroll
    for (int q = 0; q < 4; ++q) {
        const int o = o0 + ty + q * 8;
        g[((size_t)iz * C_ + o) * N_ + n0 + tx] = tile[tx][ty + q * 8];
    }
}

// ---------------- l2 norms over N for q,k branches ----------------
__global__ __launch_bounds__(256) void k_l2norm(const float* __restrict__ g, float* __restrict__ norms)
{
    const int r = blockIdx.x;       // [0, 2*B*C)
    const float* row = g + (size_t)r * N_;
    float s = 0.f;
    for (int n = threadIdx.x; n < N_; n += 256) { const float v = row[n]; s += v * v; }
    #pragma unroll
    for (int off = 32; off > 0; off >>= 1) s += __shfl_down(s, off);
    __shared__ float red[4];
    if ((threadIdx.x & 63) == 0) red[threadIdx.x >> 6] = s;
    __syncthreads();
    if (threadIdx.x == 0)
        norms[r] = fmaxf(sqrtf(red[0] + red[1] + red[2] + red[3]), 1e-12f);
}

// ---------------- attention scores + softmax (one q-row per block) ----------------
__global__ __launch_bounds__(256) void k_attn(
    const float* __restrict__ g, const float* __restrict__ norms,
    const float* __restrict__ temp, float* __restrict__ attn)
{
    __shared__ float qs[N_];
    __shared__ float rowv[32];
    const int r = blockIdx.x;                 // b*128 + h*32 + c
    const int c = r & 31, h = (r >> 5) & 3, b = r >> 7;
    const float* qrow  = g + ((size_t)(0 * B_ + b) * C_ + h * 32 + c) * N_;
    const float* krows = g + ((size_t)(1 * B_ + b) * C_ + h * 32) * N_;
    for (int n = threadIdx.x; n < N_; n += 256) qs[n] = qrow[n];
    __syncthreads();
    const int d = threadIdx.x >> 3, s = threadIdx.x & 7;
    const float* kr = krows + (size_t)d * N_;
    float acc = 0.f;
    for (int m = 0; m < N_ / 32; ++m) {
        const int n = (m * 8 + s) * 4;
        const float4 kv = *(const float4*)(kr + n);
        acc += qs[n] * kv.x + qs[n+1] * kv.y + qs[n+2] * kv.z + qs[n+3] * kv.w;
    }
    #pragma unroll
    for (int off = 1; off < 8; off <<= 1) acc += __shfl_xor(acc, off);
    if (s == 0) rowv[d] = acc;
    __syncthreads();
    if (threadIdx.x < 32) {
        const int dd = threadIdx.x;
        const float nq = norms[(size_t)(0 * B_ + b) * C_ + h * 32 + c];
        const float nk = norms[(size_t)(1 * B_ + b) * C_ + h * 32 + dd];
        const float v = rowv[dd] / (nq * nk) * temp[h];
        float mx = v;
        #pragma unroll
        for (int off = 1; off < 32; off <<= 1) mx = fmaxf(mx, __shfl_xor(mx, off));
        const float e = expf(v - mx);
        float sm = e;
        #pragma unroll
        for (int off = 1; off < 32; off <<= 1) sm += __shfl_xor(sm, off);
        attn[(size_t)r * 32 + dd] = e / sm;
    }
}

// ---------------- attn @ v ----------------
__global__ __launch_bounds__(256) void k_av(
    const float* __restrict__ attn, const float* __restrict__ g, float* __restrict__ av)
{
    __shared__ float at[32][32];
    const int n = blockIdx.x * 256 + threadIdx.x;
    const int h = blockIdx.y, b = blockIdx.z;
    for (int t2 = threadIdx.x; t2 < 1024; t2 += 256)
        at[t2 >> 5][t2 & 31] = attn[((size_t)(b * H_ + h)) * 1024 + t2];
    __syncthreads();
    const float* vrows = g + ((size_t)(2 * B_ + b) * C_ + h * 32) * N_;
    float acc[32] = {};
    for (int dd = 0; dd < 32; ++dd) {
        const float vv = vrows[(size_t)dd * N_ + n];
        #pragma unroll
        for (int cc = 0; cc < 32; ++cc) acc[cc] += at[cc][dd] * vv;
    }
    float* avb = av + ((size_t)b * C_ + h * 32) * N_ + n;
    #pragma unroll
    for (int cc = 0; cc < 32; ++cc) avb[(size_t)cc * N_] = acc[cc];
}

// ---------------- projection + bias + residual ----------------
__global__ __launch_bounds__(256) void k_proj(
    const float* __restrict__ av, const float* __restrict__ pW, const float* __restrict__ pb,
    const float* __restrict__ x, float* __restrict__ out)
{
    __shared__ float Ws[8][C_];
    const int n = blockIdx.x * 256 + threadIdx.x;
    const int o0 = blockIdx.y * 8;
    const int b = blockIdx.z;
    for (int t = threadIdx.x; t < 8 * C_; t += 256) {
        const int j = t >> 7, c = t & 127;
        Ws[j][c] = pW[(size_t)(o0 + j) * C_ + c];
    }
    __syncthreads();
    float acc[8] = {};
    const float* ab = av + ((size_t)b * C_) * N_ + n;
    #pragma unroll 4
    for (int c = 0; c < C_; ++c) {
        const float vv = ab[(size_t)c * N_];
        #pragma unroll
        for (int j = 0; j < 8; ++j) acc[j] += Ws[j][c] * vv;
    }
    #pragma unroll
    for (int j = 0; j < 8; ++j) {
        const int o = o0 + j;
        const size_t off = ((size_t)b * C_ + o) * N_ + n;
        out[off] = acc[j] + pb[o] + x[off];
    }
}

extern "C" void kernel_launch(void* const* d_in, const int* in_sizes, int n_in,
                              void* d_out, int out_size, void* d_ws, size_t ws_size,
                              hipStream_t stream)
{
    const float* x    = (const float*)d_in[0];
    const float* fW   = (const float*)d_in[1];
    const float* fb   = (const float*)d_in[2];
    const float* fg   = (const float*)d_in[3];
    const float* fbe  = (const float*)d_in[4];
    const float* gW1  = (const float*)d_in[5];
    const float* gb1  = (const float*)d_in[6];
    const float* gg1  = (const float*)d_in[7];
    const float* gbe1 = (const float*)d_in[8];
    const float* gW2  = (const float*)d_in[9];
    const float* gb2  = (const float*)d_in[10];
    const float* gg2  = (const float*)d_in[11];
    const float* gbe2 = (const float*)d_in[12];
    const float* pW   = (const float*)d_in[13];
    const float* pb   = (const float*)d_in[14];
    const float* temp = (const float*)d_in[15];
    float* ws = (float*)d_ws;

    float* arena = ws;                 // Y pre-knn / 4 pd buffers / P,Q,GT,AV
    float* y    = ws + OFF_Y;
    float* P    = ws + OFF_P;
    float* Q    = ws + OFF_Q;
    float* gT   = ws + OFF_GT;
    float* av   = ws + OFF_AV;
    float* sc   = ws + OFF_SC;
    float* sh   = ws + OFF_SH;
    float* xx   = ws + OFF_XX;
    int*   idxb = (int*)(ws + OFF_IDX);
    float* g    = ws + OFF_G;
    float* nrm  = ws + OFF_NRM;
    float* attn = ws + OFF_ATT;
    // bf16 hi/lo feature planes live in the (not-yet-written) OFF_G region
    unsigned short* fH = (unsigned short*)g;
    unsigned short* fL = fH + (size_t)12 * N_ * C_;

    k_filter_conv<<<dim3(N_/256, C_/8, 12), 256, 0, stream>>>(x, fW, fb, y);
    k_rowstats<<<12 * C_, 256, 0, stream>>>(y, fg, fbe, sc, sh);
    k_norm_transpose<<<dim3(N_/32, C_/32, 12), dim3(32, 8), 0, stream>>>(y, sc, sh, fH, fL);
    k_xx<<<(12 * N_) / 256, 256, 0, stream>>>(fH, fL, xx);
    for (int g4 = 0; g4 < 3; ++g4) {   // 4-wide batched knn (Y is dead now)
        k_pd_mfma<<<dim3(N_/64, N_/64, 4), 256, 0, stream>>>(fH, fL, xx, arena, g4 * 4);
        k_topk<<<dim3(N_/4, 4), 256, 0, stream>>>(arena, idxb, g4 * 4);
    }
    k_pq_mfma<<<dim3(N_/64, 4, 12), 256, 0, stream>>>(fH, fL, gW1, P, Q);
    k_edge2<<<dim3(N_/8, B_, 3), 256, 0, stream>>>(P, Q, idxb, gb1, gg1, gbe1,
                                                   gW2, gb2, gg2, gbe2, gT);
    k_transpose2<<<dim3(N_/32, C_/32, 12), dim3(32, 8), 0, stream>>>(gT, g);
    k_l2norm<<<2 * B_ * C_, 256, 0, stream>>>(g, nrm);
    k_attn<<<B_ * H_ * 32, 256, 0, stream>>>(g, nrm, temp, attn);
    k_av<<<dim3(N_/256, H_, B_), 256, 0, stream>>>(attn, g, av);
    k_proj<<<dim3(N_/256, C_/8, B_), 256, 0, stream>>>(av, pW, pb, x, (float*)d_out);
    (void)in_sizes; (void)n_in; (void)out_size; (void)ws_size;
}

// Round 7
// 489.394 us; speedup vs baseline: 2.6207x; 1.0212x over previous
//
#include <hip/hip_runtime.h>
#include <math.h>

// R6: (1) k_prep pre-converts W2*s2 -> bf16 and W1 combos -> split hi/lo bf16
// planes (once, off hot path). (2) k_edge2: W2 B-frags load global->register
// from W2bf (no 32KB LDS, no per-block f2bf) -> LDS 42KB -> 3 blocks/CU.
// (3) k_pq_mfma: B staged by bf16 copy; epilogue emits P'=bf16(P*s1+t1),
// Q'=bf16(Q*s1) so edge2 gathers half the bytes. R5 lesson: bank conflicts
// were NOT edge2's critical path (halved, time flat) -> attack VALU+occupancy.

#define B_ 4
#define C_ 128
#define N_ 2048
#define H_ 4
#define K_ 20

typedef __bf16 bf16x8 __attribute__((ext_vector_type(8)));
typedef float f32x4 __attribute__((ext_vector_type(4)));
typedef unsigned int u32x4 __attribute__((ext_vector_type(4)));

__device__ __forceinline__ unsigned short f2bf(float f) {
    unsigned int u = __builtin_bit_cast(unsigned int, f);
    u += 0x7fffu + ((u >> 16) & 1u);       // RNE
    return (unsigned short)(u >> 16);
}
__device__ __forceinline__ float bf2f(unsigned short s) {
    return __builtin_bit_cast(float, (unsigned int)s << 16);
}
__device__ __forceinline__ float bflo(unsigned int u) {   // low bf16 of pair
    return __builtin_bit_cast(float, u << 16);
}
__device__ __forceinline__ float bfhi(unsigned int u) {   // high bf16 of pair
    return __builtin_bit_cast(float, u & 0xFFFF0000u);
}

// ---- workspace layout (float offsets) ----
// ARENA [0, 16777216): Y pre-knn | 4 pd buffers during knn | P',Q',GT,AV after.
#define PD_STRIDE 4194304
#define OFF_Y     0
#define OFF_P     0          // u16 [3B][N][C] = 1572864 floats
#define OFF_Q     1572864    // u16 [3B][N][C]
#define OFF_GT    6291456
#define OFF_AV    9437184
#define OFF_SC    19922944   // 1536
#define OFF_SH    19924480   // 1536
#define OFF_XX    19926016   // 24576
#define OFF_IDX   19950592   // 3*B*N*K ints (491520)
#define OFF_G     20442112   // 3145728: fH/fL bf16 planes during knn, g after
#define OFF_NRM   23587840   // 1024
#define OFF_ATT   23588864   // 16384
#define OFF_W2B   23605248   // u16 [3][128][128] W2*s2 bf16 (24576 floats)
#define OFF_PWH   23629824   // u16 [3][128][128] (W1a+W1b) hi
#define OFF_PWL   23654400   // lo
#define OFF_QWH   23678976   // (-W1b) hi
#define OFF_QWL   23703552   // lo
// total = 23,728,128 floats = 94.9 MB

// ---------------- filter: 1x1 conv ----------------
__global__ __launch_bounds__(256) void k_filter_conv(
    const float* __restrict__ x, const float* __restrict__ fW,
    const float* __restrict__ fb, float* __restrict__ y)
{
    __shared__ float Ws[8][C_];
    const int n = blockIdx.x * 256 + threadIdx.x;
    const int o0 = blockIdx.y * 8;
    const int iz = blockIdx.z;                 // i*B + b
    const int i = iz >> 2, b = iz & 3;
    for (int t = threadIdx.x; t < 8 * C_; t += 256) {
        const int j = t >> 7, c = t & 127;
        Ws[j][c] = fW[((size_t)i * C_ + o0 + j) * C_ + c];
    }
    __syncthreads();
    float acc[8] = {};
    const float* xb = x + ((size_t)b * C_) * N_ + n;
    #pragma unroll 4
    for (int c = 0; c < C_; ++c) {
        const float xv = xb[(size_t)c * N_];
        #pragma unroll
        for (int j = 0; j < 8; ++j) acc[j] += Ws[j][c] * xv;
    }
    float* yb = y + ((size_t)iz * C_ + o0) * N_ + n;
    #pragma unroll
    for (int j = 0; j < 8; ++j) yb[(size_t)j * N_] = acc[j] + fb[i * C_ + o0 + j];
}

// ---------------- weight prep: W2*s2 -> bf16; W1 combos -> hi/lo bf16 ----------------
__global__ __launch_bounds__(256) void k_prep(
    const float* __restrict__ gW2, const float* __restrict__ gg2,
    const float* __restrict__ gW1,
    unsigned short* __restrict__ W2b,
    unsigned short* __restrict__ PWh, unsigned short* __restrict__ PWl,
    unsigned short* __restrict__ QWh, unsigned short* __restrict__ QWl)
{
    const int i = blockIdx.x;
    const float bn = sqrtf(1.00001f);
    for (int id = threadIdx.x; id < 4096; id += 256) {
        const int o = id >> 5, c4 = (id & 31) * 4;
        const size_t eo = (size_t)i * C_ * C_ + o * C_ + c4;
        {   // W2 * s2
            const float s2 = gg2[i * C_ + o] / bn;
            const float4 wv = *(const float4*)(gW2 + ((size_t)i * C_ + o) * C_ + c4);
            uint2 pk;
            pk.x = (unsigned int)f2bf(wv.x * s2) | ((unsigned int)f2bf(wv.y * s2) << 16);
            pk.y = (unsigned int)f2bf(wv.z * s2) | ((unsigned int)f2bf(wv.w * s2) << 16);
            *(uint2*)(W2b + eo) = pk;
        }
        {   // W1 combos split hi/lo
            const float* wrow = gW1 + ((size_t)i * C_ + o) * (2 * C_);
            const float4 wa = *(const float4*)(wrow + c4);
            const float4 wb = *(const float4*)(wrow + C_ + c4);
            const float pv[4] = {wa.x + wb.x, wa.y + wb.y, wa.z + wb.z, wa.w + wb.w};
            const float qv[4] = {-wb.x, -wb.y, -wb.z, -wb.w};
            unsigned short ph[4], pl[4], qh[4], ql[4];
            #pragma unroll
            for (int e = 0; e < 4; ++e) {
                ph[e] = f2bf(pv[e]); pl[e] = f2bf(pv[e] - bf2f(ph[e]));
                qh[e] = f2bf(qv[e]); ql[e] = f2bf(qv[e] - bf2f(qh[e]));
            }
            *(uint2*)(PWh + eo) = (uint2){(unsigned int)ph[0] | ((unsigned int)ph[1] << 16),
                                          (unsigned int)ph[2] | ((unsigned int)ph[3] << 16)};
            *(uint2*)(PWl + eo) = (uint2){(unsigned int)pl[0] | ((unsigned int)pl[1] << 16),
                                          (unsigned int)pl[2] | ((unsigned int)pl[3] << 16)};
            *(uint2*)(QWh + eo) = (uint2){(unsigned int)qh[0] | ((unsigned int)qh[1] << 16),
                                          (unsigned int)qh[2] | ((unsigned int)qh[3] << 16)};
            *(uint2*)(QWl + eo) = (uint2){(unsigned int)ql[0] | ((unsigned int)ql[1] << 16),
                                          (unsigned int)ql[2] | ((unsigned int)ql[3] << 16)};
        }
    }
}

// ---------------- instance-norm row stats ----------------
__global__ __launch_bounds__(256) void k_rowstats(
    const float* __restrict__ y, const float* __restrict__ fg,
    const float* __restrict__ fbe, float* __restrict__ scale, float* __restrict__ shift)
{
    const int r = blockIdx.x;                  // (i*B+b)*C + o
    const int i = r >> 9, o = r & 127;
    const float* row = y + (size_t)r * N_;
    float s = 0.f, ss = 0.f;
    for (int n = threadIdx.x; n < N_; n += 256) {
        const float v = row[n];
        s += v; ss += v * v;
    }
    #pragma unroll
    for (int off = 32; off > 0; off >>= 1) {
        s += __shfl_down(s, off);
        ss += __shfl_down(ss, off);
    }
    __shared__ float red[2][4];
    const int wid = threadIdx.x >> 6;
    if ((threadIdx.x & 63) == 0) { red[0][wid] = s; red[1][wid] = ss; }
    __syncthreads();
    if (threadIdx.x == 0) {
        s = red[0][0] + red[0][1] + red[0][2] + red[0][3];
        ss = red[1][0] + red[1][1] + red[1][2] + red[1][3];
        const float mean = s * (1.f / N_);
        const float var = ss * (1.f / N_) - mean * mean;
        const float bn = sqrtf(1.00001f);
        const float sc = fg[i * C_ + o] / (bn * sqrtf(var + 1e-3f));
        scale[r] = sc;
        shift[r] = fbe[i * C_ + o] - mean * sc;
    }
}

// ------- normalize + relu + transpose to [n][c]; emit bf16 hi/lo planes -------
__global__ __launch_bounds__(256) void k_norm_transpose(
    const float* __restrict__ y, const float* __restrict__ scale,
    const float* __restrict__ shift,
    unsigned short* __restrict__ fH, unsigned short* __restrict__ fL)
{
    __shared__ float tile[32][33];
    const int n0 = blockIdx.x * 32, o0 = blockIdx.y * 32;
    const int iz = blockIdx.z;
    const int tx = threadIdx.x, ty = threadIdx.y;
    #pragma unroll
    for (int q = 0; q < 4; ++q) {
        const int o = o0 + ty + q * 8;
        const int r = iz * C_ + o;
        const float v = y[(size_t)r * N_ + n0 + tx] * scale[r] + shift[r];
        tile[ty + q * 8][tx] = fmaxf(v, 0.f);
    }
    __syncthreads();
    #pragma unroll
    for (int q = 0; q < 4; ++q) {
        const int n = n0 + ty + q * 8;
        const size_t idx = ((size_t)iz * N_ + n) * C_ + o0 + tx;
        const float v = tile[tx][ty + q * 8];
        const unsigned short hi = f2bf(v);
        fH[idx] = hi;
        fL[idx] = f2bf(v - bf2f(hi));
    }
}

// ---------------- per-point squared norm (from hi/lo planes) ----------------
__global__ __launch_bounds__(256) void k_xx(
    const unsigned short* __restrict__ fH, const unsigned short* __restrict__ fL,
    float* __restrict__ xx)
{
    const int r = blockIdx.x * 256 + threadIdx.x;   // [0, 3*B*N)
    const u32x4* rh = (const u32x4*)(fH + (size_t)r * C_);
    const u32x4* rl = (const u32x4*)(fL + (size_t)r * C_);
    float s = 0.f;
    #pragma unroll
    for (int q = 0; q < 16; ++q) {
        const u32x4 hv = rh[q], lv = rl[q];
        #pragma unroll
        for (int e = 0; e < 4; ++e) {
            const float v0 = bflo(hv[e]) + bflo(lv[e]);
            const float v1 = bfhi(hv[e]) + bfhi(lv[e]);
            s += v0 * v0 + v1 * v1;
        }
    }
    xx[r] = s;
}

// ------- pairwise -dist^2 via split-bf16 MFMA; z = buffer slot (ib = ib0+z) -------
__global__ __launch_bounds__(256) void k_pd_mfma(
    const unsigned short* __restrict__ fH, const unsigned short* __restrict__ fL,
    const float* __restrict__ xx, float* __restrict__ pdarena, int ib0)
{
    __shared__ __align__(16) unsigned short Ah[64 * C_], Al[64 * C_];
    __shared__ __align__(16) unsigned short Bh[64 * C_], Bl[64 * C_];
    const int j = blockIdx.z, ib = ib0 + j;
    const unsigned short* fHb = fH + (size_t)ib * N_ * C_;
    const unsigned short* fLb = fL + (size_t)ib * N_ * C_;
    const float* xxb = xx + ib * N_;
    float* pd = pdarena + (size_t)j * PD_STRIDE;
    const int n0 = blockIdx.x * 64, m0 = blockIdx.y * 64;
    const int t = threadIdx.x;
    {   // stage 4 bf16 planes (swizzle: byte ^= (row&15)<<4, bijective in 256B row)
        const int s = t & 15, rb = t >> 4;
        #pragma unroll
        for (int q = 0; q < 4; ++q) {
            const int r = rb + q * 16;
            const int ld = r * 256 + ((s * 16) ^ ((r & 15) << 4));
            *(u32x4*)((char*)Ah + ld) = *(const u32x4*)((const char*)fHb + (size_t)(n0 + r) * 256 + s * 16);
            *(u32x4*)((char*)Al + ld) = *(const u32x4*)((const char*)fLb + (size_t)(n0 + r) * 256 + s * 16);
            *(u32x4*)((char*)Bh + ld) = *(const u32x4*)((const char*)fHb + (size_t)(m0 + r) * 256 + s * 16);
            *(u32x4*)((char*)Bl + ld) = *(const u32x4*)((const char*)fLb + (size_t)(m0 + r) * 256 + s * 16);
        }
    }
    __syncthreads();
    const int lane = t & 63, w = t >> 6;       // wave w owns rows [w*16, w*16+16)
    const int lr = lane & 15, lg = lane >> 4;
    f32x4 acc[4];
    #pragma unroll
    for (int ct = 0; ct < 4; ++ct) acc[ct] = (f32x4){0.f, 0.f, 0.f, 0.f};
    #pragma unroll
    for (int ks = 0; ks < 4; ++ks) {           // K = 128, 32 per MFMA
        const int arow = w * 16 + lr;
        const int cb = ks * 64 + lg * 16;      // byte col within 256B row
        const bf16x8 ah = __builtin_bit_cast(bf16x8,
            *(const u32x4*)((const char*)Ah + arow * 256 + (cb ^ ((arow & 15) << 4))));
        const bf16x8 al = __builtin_bit_cast(bf16x8,
            *(const u32x4*)((const char*)Al + arow * 256 + (cb ^ ((arow & 15) << 4))));
        #pragma unroll
        for (int ct = 0; ct < 4; ++ct) {
            const int brow = ct * 16 + lr;
            const int boff = brow * 256 + (cb ^ ((brow & 15) << 4));
            const bf16x8 bh = __builtin_bit_cast(bf16x8, *(const u32x4*)((const char*)Bh + boff));
            const bf16x8 bl = __builtin_bit_cast(bf16x8, *(const u32x4*)((const char*)Bl + boff));
            acc[ct] = __builtin_amdgcn_mfma_f32_16x16x32_bf16(ah, bh, acc[ct], 0, 0, 0);
            acc[ct] = __builtin_amdgcn_mfma_f32_16x16x32_bf16(ah, bl, acc[ct], 0, 0, 0);
            acc[ct] = __builtin_amdgcn_mfma_f32_16x16x32_bf16(al, bh, acc[ct], 0, 0, 0);
        }
    }
    // epilogue: D col=lane&15, row=(lane>>4)*4+r  (m89/m91-verified mapping)
    #pragma unroll
    for (int ct = 0; ct < 4; ++ct) {
        const int m = m0 + ct * 16 + lr;
        const float xm = xxb[m];
        #pragma unroll
        for (int r = 0; r < 4; ++r) {
            const int n = n0 + w * 16 + lg * 4 + r;
            pd[(size_t)n * N_ + m] = 2.f * acc[ct][r] - xxb[n] - xm;
        }
    }
}

// ------- top-K=20 per row (one wave per row); y = buffer slot (ib = ib0+y) -------
__global__ __launch_bounds__(256) void k_topk(
    const float* __restrict__ pdarena, int* __restrict__ idxb, int ib0)
{
    const int j = blockIdx.y;
    const float* pd = pdarena + (size_t)j * PD_STRIDE;
    const int lane = threadIdx.x & 63;
    const int n = blockIdx.x * 4 + (threadIdx.x >> 6);
    int* out = idxb + ((size_t)(ib0 + j) * N_ + n) * K_;
    const float* row = pd + (size_t)n * N_;
    float v[32];
    #pragma unroll
    for (int jj = 0; jj < 32; ++jj) v[jj] = row[jj * 64 + lane];
    for (int it = 0; it < K_; ++it) {
        float best = -3e38f; int bj = 0;
        #pragma unroll
        for (int jj = 0; jj < 32; ++jj) if (v[jj] > best) { best = v[jj]; bj = jj; }
        int bm = bj * 64 + lane;
        #pragma unroll
        for (int off = 1; off < 64; off <<= 1) {
            const float ov = __shfl_xor(best, off);
            const int   om = __shfl_xor(bm, off);
            if (ov > best || (ov == best && om < bm)) { best = ov; bm = om; }
        }
        if (lane == 0) out[it] = bm;
        if ((bm & 63) == lane) {
            const int jc = bm >> 6;          // static unroll avoids scratch (rule #20)
            #pragma unroll
            for (int jj = 0; jj < 32; ++jj) if (jj == jc) v[jj] = -3e38f;
        }
    }
}

// ------- P/Q GEMMs via split-bf16 MFMA; emits bf16 P'=P*s1+t1, Q'=Q*s1 -------
__global__ __launch_bounds__(256) void k_pq_mfma(
    const unsigned short* __restrict__ fH, const unsigned short* __restrict__ fL,
    const unsigned short* __restrict__ PWh, const unsigned short* __restrict__ PWl,
    const unsigned short* __restrict__ QWh, const unsigned short* __restrict__ QWl,
    const float* __restrict__ gg1, const float* __restrict__ gb1,
    const float* __restrict__ gbe1,
    unsigned short* __restrict__ Pb, unsigned short* __restrict__ Qb)
{
    __shared__ __align__(16) unsigned short Ah[64 * C_], Al[64 * C_];
    __shared__ __align__(16) unsigned short Bh[64 * C_], Bl[64 * C_];
    const int iz = blockIdx.z, i = iz >> 2;
    const int n0 = blockIdx.x * 64;
    const int yt = blockIdx.y;           // 0,1 -> P col-halves; 2,3 -> Q col-halves
    const bool isQ = (yt >= 2);
    const int oc0 = (yt & 1) * 64;
    const int t = threadIdx.x;
    const unsigned short* fHb = fH + (size_t)iz * N_ * C_;
    const unsigned short* fLb = fL + (size_t)iz * N_ * C_;
    const unsigned short* Wh = (isQ ? QWh : PWh) + (size_t)i * C_ * C_;
    const unsigned short* Wl = (isQ ? QWl : PWl) + (size_t)i * C_ * C_;
    {   // A: copy hi/lo feature planes; B: copy pre-split weight planes
        const int s = t & 15, rb = t >> 4;
        #pragma unroll
        for (int q = 0; q < 4; ++q) {
            const int r = rb + q * 16;
            const int ld = r * 256 + ((s * 16) ^ ((r & 15) << 4));
            *(u32x4*)((char*)Ah + ld) = *(const u32x4*)((const char*)fHb + (size_t)(n0 + r) * 256 + s * 16);
            *(u32x4*)((char*)Al + ld) = *(const u32x4*)((const char*)fLb + (size_t)(n0 + r) * 256 + s * 16);
            *(u32x4*)((char*)Bh + ld) = *(const u32x4*)((const char*)(Wh + (size_t)(oc0 + r) * C_) + s * 16);
            *(u32x4*)((char*)Bl + ld) = *(const u32x4*)((const char*)(Wl + (size_t)(oc0 + r) * C_) + s * 16);
        }
    }
    __syncthreads();
    const int lane = t & 63, w = t >> 6;
    const int lr = lane & 15, lg = lane >> 4;
    f32x4 acc[4];
    #pragma unroll
    for (int ct = 0; ct < 4; ++ct) acc[ct] = (f32x4){0.f, 0.f, 0.f, 0.f};
    #pragma unroll
    for (int ks = 0; ks < 4; ++ks) {
        const int arow = w * 16 + lr;
        const int cb = ks * 64 + lg * 16;
        const bf16x8 ah = __builtin_bit_cast(bf16x8,
            *(const u32x4*)((const char*)Ah + arow * 256 + (cb ^ ((arow & 15) << 4))));
        const bf16x8 al = __builtin_bit_cast(bf16x8,
            *(const u32x4*)((const char*)Al + arow * 256 + (cb ^ ((arow & 15) << 4))));
        #pragma unroll
        for (int ct = 0; ct < 4; ++ct) {
            const int brow = ct * 16 + lr;
            const int boff = brow * 256 + (cb ^ ((brow & 15) << 4));
            const bf16x8 bh = __builtin_bit_cast(bf16x8, *(const u32x4*)((const char*)Bh + boff));
            const bf16x8 bl = __builtin_bit_cast(bf16x8, *(const u32x4*)((const char*)Bl + boff));
            acc[ct] = __builtin_amdgcn_mfma_f32_16x16x32_bf16(ah, bh, acc[ct], 0, 0, 0);
            acc[ct] = __builtin_amdgcn_mfma_f32_16x16x32_bf16(ah, bl, acc[ct], 0, 0, 0);
            acc[ct] = __builtin_amdgcn_mfma_f32_16x16x32_bf16(al, bh, acc[ct], 0, 0, 0);
        }
    }
    const float bn = sqrtf(1.00001f);
    unsigned short* outp = (isQ ? Qb : Pb) + (size_t)iz * N_ * C_;
    #pragma unroll
    for (int ct = 0; ct < 4; ++ct) {
        const int col = oc0 + ct * 16 + lr;
        const float s1 = gg1[i * C_ + col] / bn;
        const float t1 = isQ ? 0.f : (gb1[i * C_ + col] * s1 + gbe1[i * C_ + col]);
        #pragma unroll
        for (int r = 0; r < 4; ++r) {
            const int n = n0 + w * 16 + lg * 4 + r;
            outp[(size_t)n * C_ + col] = f2bf(acc[ct][r] * s1 + t1);
        }
    }
}

// ------- edge conv2 + max over k : W2 B-frags direct global->reg, 3 blk/CU -------
__global__ __launch_bounds__(256, 3) void k_edge2(
    const unsigned short* __restrict__ Pb, const unsigned short* __restrict__ Qb,
    const int* __restrict__ idxb, const unsigned short* __restrict__ W2b,
    const float* __restrict__ gg2, const float* __restrict__ gb2,
    const float* __restrict__ gbe2, float* __restrict__ gT)
{
    __shared__ __align__(16) unsigned short h1s[160 * C_];  // 40 KB
    __shared__ float t2s[C_];
    __shared__ int idxs[160];
    const int i = blockIdx.z, b = blockIdx.y;
    const int p0 = blockIdx.x * 8;
    const int t = threadIdx.x;
    const size_t base = (size_t)(i * B_ + b) * N_;

    if (t < C_) {
        const float bn = sqrtf(1.00001f);
        const float s2 = gg2[i * C_ + t] / bn;        // s2 already folded into W2b
        t2s[t] = gb2[i * C_ + t] * s2 + gbe2[i * C_ + t];
    }
    if (t < 160) idxs[t] = idxb[base * K_ + p0 * K_ + t];
    __syncthreads();

    // ---- B-fragments: direct global->register from pre-converted W2b ----
    const int lane = t & 63, w = t >> 6;
    const int lr = lane & 15, lg = lane >> 4;
    const unsigned short* W2bi = W2b + (size_t)i * C_ * C_;
    bf16x8 Bf[2][4];
    #pragma unroll
    for (int nb = 0; nb < 2; ++nb)
        #pragma unroll
        for (int ks = 0; ks < 4; ++ks) {
            const int o = w * 32 + nb * 16 + lr;
            Bf[nb][ks] = __builtin_bit_cast(bf16x8,
                *(const u32x4*)(W2bi + (size_t)o * C_ + ks * 32 + lg * 8));
        }

    // ---- build h1 = relu(P'[n] + Q'[m]) (bf16 inputs, swizzled bf16 out) ----
    const int seg = t & 7;            // 16-element column segment
    const int rb = t >> 3;
    const unsigned short* Pr0 = Pb + base * C_;
    const unsigned short* Qr0 = Qb + base * C_;
    #pragma unroll
    for (int it = 0; it < 5; ++it) {
        const int row = rb + 32 * it;
        const int p = row / 20;
        const int m = idxs[row];
        const u32x4* Pr = (const u32x4*)(Pr0 + (size_t)(p0 + p) * C_ + seg * 16);
        const u32x4* Qr = (const u32x4*)(Qr0 + (size_t)m * C_ + seg * 16);
        const u32x4 pv0 = Pr[0], pv1 = Pr[1];
        const u32x4 qv0 = Qr[0], qv1 = Qr[1];
        unsigned int pk[8];
        #pragma unroll
        for (int e = 0; e < 4; ++e) {
            const float lo0 = fmaxf(bflo(pv0[e]) + bflo(qv0[e]), 0.f);
            const float hi0 = fmaxf(bfhi(pv0[e]) + bfhi(qv0[e]), 0.f);
            pk[e] = (unsigned int)f2bf(lo0) | ((unsigned int)f2bf(hi0) << 16);
            const float lo1 = fmaxf(bflo(pv1[e]) + bflo(qv1[e]), 0.f);
            const float hi1 = fmaxf(bfhi(pv1[e]) + bfhi(qv1[e]), 0.f);
            pk[e + 4] = (unsigned int)f2bf(lo1) | ((unsigned int)f2bf(hi1) << 16);
        }
        const int sw = (row & 15) << 4;
        char* bp = (char*)h1s + row * 256;
        *(u32x4*)(bp + ((seg * 32) ^ sw))      = (u32x4){pk[0], pk[1], pk[2], pk[3]};
        *(u32x4*)(bp + ((seg * 32 + 16) ^ sw)) = (u32x4){pk[4], pk[5], pk[6], pk[7]};
    }
    __syncthreads();

    // ---- MFMA: D[row][o] = sum_c h1[row][c] * W2'[o][c] ----
    f32x4 acc[10][2];
    #pragma unroll
    for (int mt = 0; mt < 10; ++mt)
        #pragma unroll
        for (int nb = 0; nb < 2; ++nb)
            acc[mt][nb] = (f32x4){0.f, 0.f, 0.f, 0.f};
    #pragma unroll
    for (int mt = 0; mt < 10; ++mt) {
        bf16x8 Af[4];
        #pragma unroll
        for (int ks = 0; ks < 4; ++ks) {
            const int row = mt * 16 + lr;
            const int cb = ks * 64 + lg * 16;
            Af[ks] = __builtin_bit_cast(bf16x8,
                *(const u32x4*)((const char*)h1s + row * 256 + (cb ^ ((row & 15) << 4))));
        }
        #pragma unroll
        for (int nb = 0; nb < 2; ++nb)
            #pragma unroll
            for (int ks = 0; ks < 4; ++ks)
                acc[mt][nb] = __builtin_amdgcn_mfma_f32_16x16x32_bf16(
                    Af[ks], Bf[nb][ks], acc[mt][nb], 0, 0, 0);
    }
    __syncthreads();   // all waves done reading h1s

    // ---- epilogue: +t2, relu, store h2 bf16 into h1s region ----
    #pragma unroll
    for (int mt = 0; mt < 10; ++mt)
        #pragma unroll
        for (int nb = 0; nb < 2; ++nb) {
            const int col = w * 32 + nb * 16 + lr;
            const float t2c = t2s[col];
            #pragma unroll
            for (int r = 0; r < 4; ++r) {
                const int row = mt * 16 + lg * 4 + r;
                const float v = fmaxf(acc[mt][nb][r] + t2c, 0.f);
                *(unsigned short*)((char*)h1s + row * 256 + ((col * 2) ^ ((row & 15) << 4))) = f2bf(v);
            }
        }
    __syncthreads();

    // ---- max over 20 neighbors per point ----
    const int oc = t & 127, ph = t >> 7;
    float* gp = gT + (base + p0) * C_;
    #pragma unroll
    for (int pp = 0; pp < 4; ++pp) {
        const int p = ph * 4 + pp;
        float mx = 0.f;
        #pragma unroll
        for (int j = 0; j < 20; ++j) {
            const int row = p * 20 + j;
            const unsigned short us =
                *(const unsigned short*)((const char*)h1s + row * 256 + ((oc * 2) ^ ((row & 15) << 4)));
            mx = fmaxf(mx, bf2f(us));
        }
        gp[(size_t)p * C_ + oc] = mx;
    }
}

// ---------------- transpose gT [n][c] -> g [c][n] ----------------
__global__ __launch_bounds__(256) void k_transpose2(
    const float* __restrict__ gT, float* __restrict__ g)
{
    __shared__ float tile[32][33];
    const int n0 = blockIdx.x * 32, o0 = blockIdx.y * 32;
    const int iz = blockIdx.z;
    const int tx = threadIdx.x, ty = threadIdx.y;
    #pragma unroll
    for (int q = 0; q < 4; ++q) {
        const int n = n0 + ty + q * 8;
        tile[ty + q * 8][tx] = gT[((size_t)iz * N_ + n) * C_ + o0 + tx];
    }
    __syncthreads();
    #pragma unroll
    for (int q = 0; q < 4; ++q) {
        const int o = o0 + ty + q * 8;
        g[((size_t)iz * C_ + o) * N_ + n0 + tx] = tile[tx][ty + q * 8];
    }
}

// ---------------- l2 norms over N for q,k branches ----------------
__global__ __launch_bounds__(256) void k_l2norm(const float* __restrict__ g, float* __restrict__ norms)
{
    const int r = blockIdx.x;       // [0, 2*B*C)
    const float* row = g + (size_t)r * N_;
    float s = 0.f;
    for (int n = threadIdx.x; n < N_; n += 256) { const float v = row[n]; s += v * v; }
    #pragma unroll
    for (int off = 32; off > 0; off >>= 1) s += __shfl_down(s, off);
    __shared__ float red[4];
    if ((threadIdx.x & 63) == 0) red[threadIdx.x >> 6] = s;
    __syncthreads();
    if (threadIdx.x == 0)
        norms[r] = fmaxf(sqrtf(red[0] + red[1] + red[2] + red[3]), 1e-12f);
}

// ---------------- attention scores + softmax (one q-row per block) ----------------
__global__ __launch_bounds__(256) void k_attn(
    const float* __restrict__ g, const float* __restrict__ norms,
    const float* __restrict__ temp, float* __restrict__ attn)
{
    __shared__ float qs[N_];
    __shared__ float rowv[32];
    const int r = blockIdx.x;                 // b*128 + h*32 + c
    const int c = r & 31, h = (r >> 5) & 3, b = r >> 7;
    const float* qrow  = g + ((size_t)(0 * B_ + b) * C_ + h * 32 + c) * N_;
    const float* krows = g + ((size_t)(1 * B_ + b) * C_ + h * 32) * N_;
    for (int n = threadIdx.x; n < N_; n += 256) qs[n] = qrow[n];
    __syncthreads();
    const int d = threadIdx.x >> 3, s = threadIdx.x & 7;
    const float* kr = krows + (size_t)d * N_;
    float acc = 0.f;
    for (int m = 0; m < N_ / 32; ++m) {
        const int n = (m * 8 + s) * 4;
        const float4 kv = *(const float4*)(kr + n);
        acc += qs[n] * kv.x + qs[n+1] * kv.y + qs[n+2] * kv.z + qs[n+3] * kv.w;
    }
    #pragma unroll
    for (int off = 1; off < 8; off <<= 1) acc += __shfl_xor(acc, off);
    if (s == 0) rowv[d] = acc;
    __syncthreads();
    if (threadIdx.x < 32) {
        const int dd = threadIdx.x;
        const float nq = norms[(size_t)(0 * B_ + b) * C_ + h * 32 + c];
        const float nk = norms[(size_t)(1 * B_ + b) * C_ + h * 32 + dd];
        const float v = rowv[dd] / (nq * nk) * temp[h];
        float mx = v;
        #pragma unroll
        for (int off = 1; off < 32; off <<= 1) mx = fmaxf(mx, __shfl_xor(mx, off));
        const float e = expf(v - mx);
        float sm = e;
        #pragma unroll
        for (int off = 1; off < 32; off <<= 1) sm += __shfl_xor(sm, off);
        attn[(size_t)r * 32 + dd] = e / sm;
    }
}

// ---------------- attn @ v ----------------
__global__ __launch_bounds__(256) void k_av(
    const float* __restrict__ attn, const float* __restrict__ g, float* __restrict__ av)
{
    __shared__ float at[32][32];
    const int n = blockIdx.x * 256 + threadIdx.x;
    const int h = blockIdx.y, b = blockIdx.z;
    for (int t2 = threadIdx.x; t2 < 1024; t2 += 256)
        at[t2 >> 5][t2 & 31] = attn[((size_t)(b * H_ + h)) * 1024 + t2];
    __syncthreads();
    const float* vrows = g + ((size_t)(2 * B_ + b) * C_ + h * 32) * N_;
    float acc[32] = {};
    for (int dd = 0; dd < 32; ++dd) {
        const float vv = vrows[(size_t)dd * N_ + n];
        #pragma unroll
        for (int cc = 0; cc < 32; ++cc) acc[cc] += at[cc][dd] * vv;
    }
    float* avb = av + ((size_t)b * C_ + h * 32) * N_ + n;
    #pragma unroll
    for (int cc = 0; cc < 32; ++cc) avb[(size_t)cc * N_] = acc[cc];
}

// ---------------- projection + bias + residual ----------------
__global__ __launch_bounds__(256) void k_proj(
    const float* __restrict__ av, const float* __restrict__ pW, const float* __restrict__ pb,
    const float* __restrict__ x, float* __restrict__ out)
{
    __shared__ float Ws[8][C_];
    const int n = blockIdx.x * 256 + threadIdx.x;
    const int o0 = blockIdx.y * 8;
    const int b = blockIdx.z;
    for (int t = threadIdx.x; t < 8 * C_; t += 256) {
        const int j = t >> 7, c = t & 127;
        Ws[j][c] = pW[(size_t)(o0 + j) * C_ + c];
    }
    __syncthreads();
    float acc[8] = {};
    const float* ab = av + ((size_t)b * C_) * N_ + n;
    #pragma unroll 4
    for (int c = 0; c < C_; ++c) {
        const float vv = ab[(size_t)c * N_];
        #pragma unroll
        for (int j = 0; j < 8; ++j) acc[j] += Ws[j][c] * vv;
    }
    #pragma unroll
    for (int j = 0; j < 8; ++j) {
        const int o = o0 + j;
        const size_t off = ((size_t)b * C_ + o) * N_ + n;
        out[off] = acc[j] + pb[o] + x[off];
    }
}

extern "C" void kernel_launch(void* const* d_in, const int* in_sizes, int n_in,
                              void* d_out, int out_size, void* d_ws, size_t ws_size,
                              hipStream_t stream)
{
    const float* x    = (const float*)d_in[0];
    const float* fW   = (const float*)d_in[1];
    const float* fb   = (const float*)d_in[2];
    const float* fg   = (const float*)d_in[3];
    const float* fbe  = (const float*)d_in[4];
    const float* gW1  = (const float*)d_in[5];
    const float* gb1  = (const float*)d_in[6];
    const float* gg1  = (const float*)d_in[7];
    const float* gbe1 = (const float*)d_in[8];
    const float* gW2  = (const float*)d_in[9];
    const float* gb2  = (const float*)d_in[10];
    const float* gg2  = (const float*)d_in[11];
    const float* gbe2 = (const float*)d_in[12];
    const float* pW   = (const float*)d_in[13];
    const float* pb   = (const float*)d_in[14];
    const float* temp = (const float*)d_in[15];
    float* ws = (float*)d_ws;

    float* arena = ws;                 // Y pre-knn / 4 pd buffers / P',Q',GT,AV
    float* y    = ws + OFF_Y;
    unsigned short* Pb = (unsigned short*)(ws + OFF_P);
    unsigned short* Qb = (unsigned short*)(ws + OFF_Q);
    float* gT   = ws + OFF_GT;
    float* av   = ws + OFF_AV;
    float* sc   = ws + OFF_SC;
    float* sh   = ws + OFF_SH;
    float* xx   = ws + OFF_XX;
    int*   idxb = (int*)(ws + OFF_IDX);
    float* g    = ws + OFF_G;
    float* nrm  = ws + OFF_NRM;
    float* attn = ws + OFF_ATT;
    unsigned short* W2b = (unsigned short*)(ws + OFF_W2B);
    unsigned short* PWh = (unsigned short*)(ws + OFF_PWH);
    unsigned short* PWl = (unsigned short*)(ws + OFF_PWL);
    unsigned short* QWh = (unsigned short*)(ws + OFF_QWH);
    unsigned short* QWl = (unsigned short*)(ws + OFF_QWL);
    // bf16 hi/lo feature planes live in the (not-yet-written) OFF_G region
    unsigned short* fH = (unsigned short*)g;
    unsigned short* fL = fH + (size_t)12 * N_ * C_;

    k_filter_conv<<<dim3(N_/256, C_/8, 12), 256, 0, stream>>>(x, fW, fb, y);
    k_prep<<<3, 256, 0, stream>>>(gW2, gg2, gW1, W2b, PWh, PWl, QWh, QWl);
    k_rowstats<<<12 * C_, 256, 0, stream>>>(y, fg, fbe, sc, sh);
    k_norm_transpose<<<dim3(N_/32, C_/32, 12), dim3(32, 8), 0, stream>>>(y, sc, sh, fH, fL);
    k_xx<<<(12 * N_) / 256, 256, 0, stream>>>(fH, fL, xx);
    for (int g4 = 0; g4 < 3; ++g4) {   // 4-wide batched knn (Y is dead now)
        k_pd_mfma<<<dim3(N_/64, N_/64, 4), 256, 0, stream>>>(fH, fL, xx, arena, g4 * 4);
        k_topk<<<dim3(N_/4, 4), 256, 0, stream>>>(arena, idxb, g4 * 4);
    }
    k_pq_mfma<<<dim3(N_/64, 4, 12), 256, 0, stream>>>(fH, fL, PWh, PWl, QWh, QWl,
                                                      gg1, gb1, gbe1, Pb, Qb);
    k_edge2<<<dim3(N_/8, B_, 3), 256, 0, stream>>>(Pb, Qb, idxb, W2b,
                                                   gg2, gb2, gbe2, gT);
    k_transpose2<<<dim3(N_/32, C_/32, 12), dim3(32, 8), 0, stream>>>(gT, g);
    k_l2norm<<<2 * B_ * C_, 256, 0, stream>>>(g, nrm);
    k_attn<<<B_ * H_ * 32, 256, 0, stream>>>(g, nrm, temp, attn);
    k_av<<<dim3(N_/256, H_, B_), 256, 0, stream>>>(attn, g, av);
    k_proj<<<dim3(N_/256, C_/8, B_), 256, 0, stream>>>(av, pW, pb, x, (float*)d_out);
    (void)in_sizes; (void)n_in; (void)out_size; (void)ws_size;
}

// Round 8
// 435.608 us; speedup vs baseline: 2.9443x; 1.1235x over previous
//
#include <hip/hip_runtime.h>
#include <math.h>

// R7: k_topk rewrite (was 3x65.7us = 40% of total, VALU/serial-bound).
// Hierarchical argmax: 8 incrementally-maintained per-group (max,idx) pairs
// replace the 32-deep serial scan; winner index readfirstlane'd to SGPR so
// removal+group-recompute is scalar-branched (off the VALU pipe). Exact same
// selection semantics (max value, ties -> lowest global index). Rest = R6.

#define B_ 4
#define C_ 128
#define N_ 2048
#define H_ 4
#define K_ 20

typedef __bf16 bf16x8 __attribute__((ext_vector_type(8)));
typedef float f32x4 __attribute__((ext_vector_type(4)));
typedef unsigned int u32x4 __attribute__((ext_vector_type(4)));

__device__ __forceinline__ unsigned short f2bf(float f) {
    unsigned int u = __builtin_bit_cast(unsigned int, f);
    u += 0x7fffu + ((u >> 16) & 1u);       // RNE
    return (unsigned short)(u >> 16);
}
__device__ __forceinline__ float bf2f(unsigned short s) {
    return __builtin_bit_cast(float, (unsigned int)s << 16);
}
__device__ __forceinline__ float bflo(unsigned int u) {   // low bf16 of pair
    return __builtin_bit_cast(float, u << 16);
}
__device__ __forceinline__ float bfhi(unsigned int u) {   // high bf16 of pair
    return __builtin_bit_cast(float, u & 0xFFFF0000u);
}

// ---- workspace layout (float offsets) ----
// ARENA [0, 16777216): Y pre-knn | 4 pd buffers during knn | P',Q',GT,AV after.
#define PD_STRIDE 4194304
#define OFF_Y     0
#define OFF_P     0          // u16 [3B][N][C] = 1572864 floats
#define OFF_Q     1572864    // u16 [3B][N][C]
#define OFF_GT    6291456
#define OFF_AV    9437184
#define OFF_SC    19922944   // 1536
#define OFF_SH    19924480   // 1536
#define OFF_XX    19926016   // 24576
#define OFF_IDX   19950592   // 3*B*N*K ints (491520)
#define OFF_G     20442112   // 3145728: fH/fL bf16 planes during knn, g after
#define OFF_NRM   23587840   // 1024
#define OFF_ATT   23588864   // 16384
#define OFF_W2B   23605248   // u16 [3][128][128] W2*s2 bf16 (24576 floats)
#define OFF_PWH   23629824   // u16 [3][128][128] (W1a+W1b) hi
#define OFF_PWL   23654400   // lo
#define OFF_QWH   23678976   // (-W1b) hi
#define OFF_QWL   23703552   // lo
// total = 23,728,128 floats = 94.9 MB

// ---------------- filter: 1x1 conv ----------------
__global__ __launch_bounds__(256) void k_filter_conv(
    const float* __restrict__ x, const float* __restrict__ fW,
    const float* __restrict__ fb, float* __restrict__ y)
{
    __shared__ float Ws[8][C_];
    const int n = blockIdx.x * 256 + threadIdx.x;
    const int o0 = blockIdx.y * 8;
    const int iz = blockIdx.z;                 // i*B + b
    const int i = iz >> 2, b = iz & 3;
    for (int t = threadIdx.x; t < 8 * C_; t += 256) {
        const int j = t >> 7, c = t & 127;
        Ws[j][c] = fW[((size_t)i * C_ + o0 + j) * C_ + c];
    }
    __syncthreads();
    float acc[8] = {};
    const float* xb = x + ((size_t)b * C_) * N_ + n;
    #pragma unroll 4
    for (int c = 0; c < C_; ++c) {
        const float xv = xb[(size_t)c * N_];
        #pragma unroll
        for (int j = 0; j < 8; ++j) acc[j] += Ws[j][c] * xv;
    }
    float* yb = y + ((size_t)iz * C_ + o0) * N_ + n;
    #pragma unroll
    for (int j = 0; j < 8; ++j) yb[(size_t)j * N_] = acc[j] + fb[i * C_ + o0 + j];
}

// ---------------- weight prep: W2*s2 -> bf16; W1 combos -> hi/lo bf16 ----------------
__global__ __launch_bounds__(256) void k_prep(
    const float* __restrict__ gW2, const float* __restrict__ gg2,
    const float* __restrict__ gW1,
    unsigned short* __restrict__ W2b,
    unsigned short* __restrict__ PWh, unsigned short* __restrict__ PWl,
    unsigned short* __restrict__ QWh, unsigned short* __restrict__ QWl)
{
    const int i = blockIdx.x;
    const float bn = sqrtf(1.00001f);
    for (int id = threadIdx.x; id < 4096; id += 256) {
        const int o = id >> 5, c4 = (id & 31) * 4;
        const size_t eo = (size_t)i * C_ * C_ + o * C_ + c4;
        {   // W2 * s2
            const float s2 = gg2[i * C_ + o] / bn;
            const float4 wv = *(const float4*)(gW2 + ((size_t)i * C_ + o) * C_ + c4);
            uint2 pk;
            pk.x = (unsigned int)f2bf(wv.x * s2) | ((unsigned int)f2bf(wv.y * s2) << 16);
            pk.y = (unsigned int)f2bf(wv.z * s2) | ((unsigned int)f2bf(wv.w * s2) << 16);
            *(uint2*)(W2b + eo) = pk;
        }
        {   // W1 combos split hi/lo
            const float* wrow = gW1 + ((size_t)i * C_ + o) * (2 * C_);
            const float4 wa = *(const float4*)(wrow + c4);
            const float4 wb = *(const float4*)(wrow + C_ + c4);
            const float pv[4] = {wa.x + wb.x, wa.y + wb.y, wa.z + wb.z, wa.w + wb.w};
            const float qv[4] = {-wb.x, -wb.y, -wb.z, -wb.w};
            unsigned short ph[4], pl[4], qh[4], ql[4];
            #pragma unroll
            for (int e = 0; e < 4; ++e) {
                ph[e] = f2bf(pv[e]); pl[e] = f2bf(pv[e] - bf2f(ph[e]));
                qh[e] = f2bf(qv[e]); ql[e] = f2bf(qv[e] - bf2f(qh[e]));
            }
            *(uint2*)(PWh + eo) = (uint2){(unsigned int)ph[0] | ((unsigned int)ph[1] << 16),
                                          (unsigned int)ph[2] | ((unsigned int)ph[3] << 16)};
            *(uint2*)(PWl + eo) = (uint2){(unsigned int)pl[0] | ((unsigned int)pl[1] << 16),
                                          (unsigned int)pl[2] | ((unsigned int)pl[3] << 16)};
            *(uint2*)(QWh + eo) = (uint2){(unsigned int)qh[0] | ((unsigned int)qh[1] << 16),
                                          (unsigned int)qh[2] | ((unsigned int)qh[3] << 16)};
            *(uint2*)(QWl + eo) = (uint2){(unsigned int)ql[0] | ((unsigned int)ql[1] << 16),
                                          (unsigned int)ql[2] | ((unsigned int)ql[3] << 16)};
        }
    }
}

// ---------------- instance-norm row stats ----------------
__global__ __launch_bounds__(256) void k_rowstats(
    const float* __restrict__ y, const float* __restrict__ fg,
    const float* __restrict__ fbe, float* __restrict__ scale, float* __restrict__ shift)
{
    const int r = blockIdx.x;                  // (i*B+b)*C + o
    const int i = r >> 9, o = r & 127;
    const float* row = y + (size_t)r * N_;
    float s = 0.f, ss = 0.f;
    for (int n = threadIdx.x; n < N_; n += 256) {
        const float v = row[n];
        s += v; ss += v * v;
    }
    #pragma unroll
    for (int off = 32; off > 0; off >>= 1) {
        s += __shfl_down(s, off);
        ss += __shfl_down(ss, off);
    }
    __shared__ float red[2][4];
    const int wid = threadIdx.x >> 6;
    if ((threadIdx.x & 63) == 0) { red[0][wid] = s; red[1][wid] = ss; }
    __syncthreads();
    if (threadIdx.x == 0) {
        s = red[0][0] + red[0][1] + red[0][2] + red[0][3];
        ss = red[1][0] + red[1][1] + red[1][2] + red[1][3];
        const float mean = s * (1.f / N_);
        const float var = ss * (1.f / N_) - mean * mean;
        const float bn = sqrtf(1.00001f);
        const float sc = fg[i * C_ + o] / (bn * sqrtf(var + 1e-3f));
        scale[r] = sc;
        shift[r] = fbe[i * C_ + o] - mean * sc;
    }
}

// ------- normalize + relu + transpose to [n][c]; emit bf16 hi/lo planes -------
__global__ __launch_bounds__(256) void k_norm_transpose(
    const float* __restrict__ y, const float* __restrict__ scale,
    const float* __restrict__ shift,
    unsigned short* __restrict__ fH, unsigned short* __restrict__ fL)
{
    __shared__ float tile[32][33];
    const int n0 = blockIdx.x * 32, o0 = blockIdx.y * 32;
    const int iz = blockIdx.z;
    const int tx = threadIdx.x, ty = threadIdx.y;
    #pragma unroll
    for (int q = 0; q < 4; ++q) {
        const int o = o0 + ty + q * 8;
        const int r = iz * C_ + o;
        const float v = y[(size_t)r * N_ + n0 + tx] * scale[r] + shift[r];
        tile[ty + q * 8][tx] = fmaxf(v, 0.f);
    }
    __syncthreads();
    #pragma unroll
    for (int q = 0; q < 4; ++q) {
        const int n = n0 + ty + q * 8;
        const size_t idx = ((size_t)iz * N_ + n) * C_ + o0 + tx;
        const float v = tile[tx][ty + q * 8];
        const unsigned short hi = f2bf(v);
        fH[idx] = hi;
        fL[idx] = f2bf(v - bf2f(hi));
    }
}

// ---------------- per-point squared norm (from hi/lo planes) ----------------
__global__ __launch_bounds__(256) void k_xx(
    const unsigned short* __restrict__ fH, const unsigned short* __restrict__ fL,
    float* __restrict__ xx)
{
    const int r = blockIdx.x * 256 + threadIdx.x;   // [0, 3*B*N)
    const u32x4* rh = (const u32x4*)(fH + (size_t)r * C_);
    const u32x4* rl = (const u32x4*)(fL + (size_t)r * C_);
    float s = 0.f;
    #pragma unroll
    for (int q = 0; q < 16; ++q) {
        const u32x4 hv = rh[q], lv = rl[q];
        #pragma unroll
        for (int e = 0; e < 4; ++e) {
            const float v0 = bflo(hv[e]) + bflo(lv[e]);
            const float v1 = bfhi(hv[e]) + bfhi(lv[e]);
            s += v0 * v0 + v1 * v1;
        }
    }
    xx[r] = s;
}

// ------- pairwise -dist^2 via split-bf16 MFMA; z = buffer slot (ib = ib0+z) -------
__global__ __launch_bounds__(256) void k_pd_mfma(
    const unsigned short* __restrict__ fH, const unsigned short* __restrict__ fL,
    const float* __restrict__ xx, float* __restrict__ pdarena, int ib0)
{
    __shared__ __align__(16) unsigned short Ah[64 * C_], Al[64 * C_];
    __shared__ __align__(16) unsigned short Bh[64 * C_], Bl[64 * C_];
    const int j = blockIdx.z, ib = ib0 + j;
    const unsigned short* fHb = fH + (size_t)ib * N_ * C_;
    const unsigned short* fLb = fL + (size_t)ib * N_ * C_;
    const float* xxb = xx + ib * N_;
    float* pd = pdarena + (size_t)j * PD_STRIDE;
    const int n0 = blockIdx.x * 64, m0 = blockIdx.y * 64;
    const int t = threadIdx.x;
    {   // stage 4 bf16 planes (swizzle: byte ^= (row&15)<<4, bijective in 256B row)
        const int s = t & 15, rb = t >> 4;
        #pragma unroll
        for (int q = 0; q < 4; ++q) {
            const int r = rb + q * 16;
            const int ld = r * 256 + ((s * 16) ^ ((r & 15) << 4));
            *(u32x4*)((char*)Ah + ld) = *(const u32x4*)((const char*)fHb + (size_t)(n0 + r) * 256 + s * 16);
            *(u32x4*)((char*)Al + ld) = *(const u32x4*)((const char*)fLb + (size_t)(n0 + r) * 256 + s * 16);
            *(u32x4*)((char*)Bh + ld) = *(const u32x4*)((const char*)fHb + (size_t)(m0 + r) * 256 + s * 16);
            *(u32x4*)((char*)Bl + ld) = *(const u32x4*)((const char*)fLb + (size_t)(m0 + r) * 256 + s * 16);
        }
    }
    __syncthreads();
    const int lane = t & 63, w = t >> 6;       // wave w owns rows [w*16, w*16+16)
    const int lr = lane & 15, lg = lane >> 4;
    f32x4 acc[4];
    #pragma unroll
    for (int ct = 0; ct < 4; ++ct) acc[ct] = (f32x4){0.f, 0.f, 0.f, 0.f};
    #pragma unroll
    for (int ks = 0; ks < 4; ++ks) {           // K = 128, 32 per MFMA
        const int arow = w * 16 + lr;
        const int cb = ks * 64 + lg * 16;      // byte col within 256B row
        const bf16x8 ah = __builtin_bit_cast(bf16x8,
            *(const u32x4*)((const char*)Ah + arow * 256 + (cb ^ ((arow & 15) << 4))));
        const bf16x8 al = __builtin_bit_cast(bf16x8,
            *(const u32x4*)((const char*)Al + arow * 256 + (cb ^ ((arow & 15) << 4))));
        #pragma unroll
        for (int ct = 0; ct < 4; ++ct) {
            const int brow = ct * 16 + lr;
            const int boff = brow * 256 + (cb ^ ((brow & 15) << 4));
            const bf16x8 bh = __builtin_bit_cast(bf16x8, *(const u32x4*)((const char*)Bh + boff));
            const bf16x8 bl = __builtin_bit_cast(bf16x8, *(const u32x4*)((const char*)Bl + boff));
            acc[ct] = __builtin_amdgcn_mfma_f32_16x16x32_bf16(ah, bh, acc[ct], 0, 0, 0);
            acc[ct] = __builtin_amdgcn_mfma_f32_16x16x32_bf16(ah, bl, acc[ct], 0, 0, 0);
            acc[ct] = __builtin_amdgcn_mfma_f32_16x16x32_bf16(al, bh, acc[ct], 0, 0, 0);
        }
    }
    // epilogue: D col=lane&15, row=(lane>>4)*4+r  (m89/m91-verified mapping)
    #pragma unroll
    for (int ct = 0; ct < 4; ++ct) {
        const int m = m0 + ct * 16 + lr;
        const float xm = xxb[m];
        #pragma unroll
        for (int r = 0; r < 4; ++r) {
            const int n = n0 + w * 16 + lg * 4 + r;
            pd[(size_t)n * N_ + m] = 2.f * acc[ct][r] - xxb[n] - xm;
        }
    }
}

// ------- top-K=20 per row: hierarchical argmax, one wave per row -------
// Lane owns 32 consecutive cols (idx = lane*32 + j). 8 per-group (max,idx)
// pairs maintained incrementally; winner broadcast via readfirstlane so the
// removal unroll is scalar-branched. Ties -> lowest global index (== jax top_k).
__global__ __launch_bounds__(256) void k_topk(
    const float* __restrict__ pdarena, int* __restrict__ idxb, int ib0)
{
    const int jbuf = blockIdx.y;
    const float* pd = pdarena + (size_t)jbuf * PD_STRIDE;
    const int lane = threadIdx.x & 63;
    const int n = blockIdx.x * 4 + (threadIdx.x >> 6);
    int* out = idxb + ((size_t)(ib0 + jbuf) * N_ + n) * K_;
    const float* row = pd + (size_t)n * N_;
    const int ibase = lane * 32;
    float v[32];
    #pragma unroll
    for (int q = 0; q < 8; ++q) {
        const float4 vv = *(const float4*)(row + ibase + q * 4);
        v[q*4+0] = vv.x; v[q*4+1] = vv.y; v[q*4+2] = vv.z; v[q*4+3] = vv.w;
    }
    float gv[8]; int gi[8];
    #pragma unroll
    for (int k = 0; k < 8; ++k) {       // strict > ascending keeps lowest idx on tie
        float b = v[k*4]; int bi = ibase + k*4;
        #pragma unroll
        for (int e = 1; e < 4; ++e)
            if (v[k*4+e] > b) { b = v[k*4+e]; bi = ibase + k*4 + e; }
        gv[k] = b; gi[k] = bi;
    }
    for (int it = 0; it < K_; ++it) {
        float best = gv[0]; int bidx = gi[0];
        #pragma unroll
        for (int k = 1; k < 8; ++k)
            if (gv[k] > best) { best = gv[k]; bidx = gi[k]; }
        #pragma unroll
        for (int off = 1; off < 64; off <<= 1) {
            const float ov = __shfl_xor(best, off);
            const int   oi = __shfl_xor(bidx, off);
            if (ov > best || (ov == best && oi < bidx)) { best = ov; bidx = oi; }
        }
        if (lane == 0) out[it] = bidx;
        const int bm = __builtin_amdgcn_readfirstlane(bidx);   // wave-uniform -> SGPR
        const int owner = bm >> 5;        // scalar: owning lane
        const int jj = bm & 31;           // scalar: element within lane
        #pragma unroll
        for (int k = 0; k < 8; ++k) if (k == (jj >> 2)) {      // scalar branch
            #pragma unroll
            for (int e = 0; e < 4; ++e) if ((k*4 + e) == jj)   // scalar branch
                v[k*4+e] = (lane == owner) ? -3e38f : v[k*4+e];
            float b = v[k*4]; int bi = ibase + k*4;            // recompute group k
            #pragma unroll
            for (int e = 1; e < 4; ++e)
                if (v[k*4+e] > b) { b = v[k*4+e]; bi = ibase + k*4 + e; }
            gv[k] = b; gi[k] = bi;
        }
    }
}

// ------- P/Q GEMMs via split-bf16 MFMA; emits bf16 P'=P*s1+t1, Q'=Q*s1 -------
__global__ __launch_bounds__(256) void k_pq_mfma(
    const unsigned short* __restrict__ fH, const unsigned short* __restrict__ fL,
    const unsigned short* __restrict__ PWh, const unsigned short* __restrict__ PWl,
    const unsigned short* __restrict__ QWh, const unsigned short* __restrict__ QWl,
    const float* __restrict__ gg1, const float* __restrict__ gb1,
    const float* __restrict__ gbe1,
    unsigned short* __restrict__ Pb, unsigned short* __restrict__ Qb)
{
    __shared__ __align__(16) unsigned short Ah[64 * C_], Al[64 * C_];
    __shared__ __align__(16) unsigned short Bh[64 * C_], Bl[64 * C_];
    const int iz = blockIdx.z, i = iz >> 2;
    const int n0 = blockIdx.x * 64;
    const int yt = blockIdx.y;           // 0,1 -> P col-halves; 2,3 -> Q col-halves
    const bool isQ = (yt >= 2);
    const int oc0 = (yt & 1) * 64;
    const int t = threadIdx.x;
    const unsigned short* fHb = fH + (size_t)iz * N_ * C_;
    const unsigned short* fLb = fL + (size_t)iz * N_ * C_;
    const unsigned short* Wh = (isQ ? QWh : PWh) + (size_t)i * C_ * C_;
    const unsigned short* Wl = (isQ ? QWl : PWl) + (size_t)i * C_ * C_;
    {   // A: copy hi/lo feature planes; B: copy pre-split weight planes
        const int s = t & 15, rb = t >> 4;
        #pragma unroll
        for (int q = 0; q < 4; ++q) {
            const int r = rb + q * 16;
            const int ld = r * 256 + ((s * 16) ^ ((r & 15) << 4));
            *(u32x4*)((char*)Ah + ld) = *(const u32x4*)((const char*)fHb + (size_t)(n0 + r) * 256 + s * 16);
            *(u32x4*)((char*)Al + ld) = *(const u32x4*)((const char*)fLb + (size_t)(n0 + r) * 256 + s * 16);
            *(u32x4*)((char*)Bh + ld) = *(const u32x4*)((const char*)(Wh + (size_t)(oc0 + r) * C_) + s * 16);
            *(u32x4*)((char*)Bl + ld) = *(const u32x4*)((const char*)(Wl + (size_t)(oc0 + r) * C_) + s * 16);
        }
    }
    __syncthreads();
    const int lane = t & 63, w = t >> 6;
    const int lr = lane & 15, lg = lane >> 4;
    f32x4 acc[4];
    #pragma unroll
    for (int ct = 0; ct < 4; ++ct) acc[ct] = (f32x4){0.f, 0.f, 0.f, 0.f};
    #pragma unroll
    for (int ks = 0; ks < 4; ++ks) {
        const int arow = w * 16 + lr;
        const int cb = ks * 64 + lg * 16;
        const bf16x8 ah = __builtin_bit_cast(bf16x8,
            *(const u32x4*)((const char*)Ah + arow * 256 + (cb ^ ((arow & 15) << 4))));
        const bf16x8 al = __builtin_bit_cast(bf16x8,
            *(const u32x4*)((const char*)Al + arow * 256 + (cb ^ ((arow & 15) << 4))));
        #pragma unroll
        for (int ct = 0; ct < 4; ++ct) {
            const int brow = ct * 16 + lr;
            const int boff = brow * 256 + (cb ^ ((brow & 15) << 4));
            const bf16x8 bh = __builtin_bit_cast(bf16x8, *(const u32x4*)((const char*)Bh + boff));
            const bf16x8 bl = __builtin_bit_cast(bf16x8, *(const u32x4*)((const char*)Bl + boff));
            acc[ct] = __builtin_amdgcn_mfma_f32_16x16x32_bf16(ah, bh, acc[ct], 0, 0, 0);
            acc[ct] = __builtin_amdgcn_mfma_f32_16x16x32_bf16(ah, bl, acc[ct], 0, 0, 0);
            acc[ct] = __builtin_amdgcn_mfma_f32_16x16x32_bf16(al, bh, acc[ct], 0, 0, 0);
        }
    }
    const float bn = sqrtf(1.00001f);
    unsigned short* outp = (isQ ? Qb : Pb) + (size_t)iz * N_ * C_;
    #pragma unroll
    for (int ct = 0; ct < 4; ++ct) {
        const int col = oc0 + ct * 16 + lr;
        const float s1 = gg1[i * C_ + col] / bn;
        const float t1 = isQ ? 0.f : (gb1[i * C_ + col] * s1 + gbe1[i * C_ + col]);
        #pragma unroll
        for (int r = 0; r < 4; ++r) {
            const int n = n0 + w * 16 + lg * 4 + r;
            outp[(size_t)n * C_ + col] = f2bf(acc[ct][r] * s1 + t1);
        }
    }
}

// ------- edge conv2 + max over k : W2 B-frags direct global->reg, 3 blk/CU -------
__global__ __launch_bounds__(256, 3) void k_edge2(
    const unsigned short* __restrict__ Pb, const unsigned short* __restrict__ Qb,
    const int* __restrict__ idxb, const unsigned short* __restrict__ W2b,
    const float* __restrict__ gg2, const float* __restrict__ gb2,
    const float* __restrict__ gbe2, float* __restrict__ gT)
{
    __shared__ __align__(16) unsigned short h1s[160 * C_];  // 40 KB
    __shared__ float t2s[C_];
    __shared__ int idxs[160];
    const int i = blockIdx.z, b = blockIdx.y;
    const int p0 = blockIdx.x * 8;
    const int t = threadIdx.x;
    const size_t base = (size_t)(i * B_ + b) * N_;

    if (t < C_) {
        const float bn = sqrtf(1.00001f);
        const float s2 = gg2[i * C_ + t] / bn;        // s2 already folded into W2b
        t2s[t] = gb2[i * C_ + t] * s2 + gbe2[i * C_ + t];
    }
    if (t < 160) idxs[t] = idxb[base * K_ + p0 * K_ + t];
    __syncthreads();

    // ---- B-fragments: direct global->register from pre-converted W2b ----
    const int lane = t & 63, w = t >> 6;
    const int lr = lane & 15, lg = lane >> 4;
    const unsigned short* W2bi = W2b + (size_t)i * C_ * C_;
    bf16x8 Bf[2][4];
    #pragma unroll
    for (int nb = 0; nb < 2; ++nb)
        #pragma unroll
        for (int ks = 0; ks < 4; ++ks) {
            const int o = w * 32 + nb * 16 + lr;
            Bf[nb][ks] = __builtin_bit_cast(bf16x8,
                *(const u32x4*)(W2bi + (size_t)o * C_ + ks * 32 + lg * 8));
        }

    // ---- build h1 = relu(P'[n] + Q'[m]) (bf16 inputs, swizzled bf16 out) ----
    const int seg = t & 7;            // 16-element column segment
    const int rb = t >> 3;
    const unsigned short* Pr0 = Pb + base * C_;
    const unsigned short* Qr0 = Qb + base * C_;
    #pragma unroll
    for (int it = 0; it < 5; ++it) {
        const int row = rb + 32 * it;
        const int p = row / 20;
        const int m = idxs[row];
        const u32x4* Pr = (const u32x4*)(Pr0 + (size_t)(p0 + p) * C_ + seg * 16);
        const u32x4* Qr = (const u32x4*)(Qr0 + (size_t)m * C_ + seg * 16);
        const u32x4 pv0 = Pr[0], pv1 = Pr[1];
        const u32x4 qv0 = Qr[0], qv1 = Qr[1];
        unsigned int pk[8];
        #pragma unroll
        for (int e = 0; e < 4; ++e) {
            const float lo0 = fmaxf(bflo(pv0[e]) + bflo(qv0[e]), 0.f);
            const float hi0 = fmaxf(bfhi(pv0[e]) + bfhi(qv0[e]), 0.f);
            pk[e] = (unsigned int)f2bf(lo0) | ((unsigned int)f2bf(hi0) << 16);
            const float lo1 = fmaxf(bflo(pv1[e]) + bflo(qv1[e]), 0.f);
            const float hi1 = fmaxf(bfhi(pv1[e]) + bfhi(qv1[e]), 0.f);
            pk[e + 4] = (unsigned int)f2bf(lo1) | ((unsigned int)f2bf(hi1) << 16);
        }
        const int sw = (row & 15) << 4;
        char* bp = (char*)h1s + row * 256;
        *(u32x4*)(bp + ((seg * 32) ^ sw))      = (u32x4){pk[0], pk[1], pk[2], pk[3]};
        *(u32x4*)(bp + ((seg * 32 + 16) ^ sw)) = (u32x4){pk[4], pk[5], pk[6], pk[7]};
    }
    __syncthreads();

    // ---- MFMA: D[row][o] = sum_c h1[row][c] * W2'[o][c] ----
    f32x4 acc[10][2];
    #pragma unroll
    for (int mt = 0; mt < 10; ++mt)
        #pragma unroll
        for (int nb = 0; nb < 2; ++nb)
            acc[mt][nb] = (f32x4){0.f, 0.f, 0.f, 0.f};
    #pragma unroll
    for (int mt = 0; mt < 10; ++mt) {
        bf16x8 Af[4];
        #pragma unroll
        for (int ks = 0; ks < 4; ++ks) {
            const int row = mt * 16 + lr;
            const int cb = ks * 64 + lg * 16;
            Af[ks] = __builtin_bit_cast(bf16x8,
                *(const u32x4*)((const char*)h1s + row * 256 + (cb ^ ((row & 15) << 4))));
        }
        #pragma unroll
        for (int nb = 0; nb < 2; ++nb)
            #pragma unroll
            for (int ks = 0; ks < 4; ++ks)
                acc[mt][nb] = __builtin_amdgcn_mfma_f32_16x16x32_bf16(
                    Af[ks], Bf[nb][ks], acc[mt][nb], 0, 0, 0);
    }
    __syncthreads();   // all waves done reading h1s

    // ---- epilogue: +t2, relu, store h2 bf16 into h1s region ----
    #pragma unroll
    for (int mt = 0; mt < 10; ++mt)
        #pragma unroll
        for (int nb = 0; nb < 2; ++nb) {
            const int col = w * 32 + nb * 16 + lr;
            const float t2c = t2s[col];
            #pragma unroll
            for (int r = 0; r < 4; ++r) {
                const int row = mt * 16 + lg * 4 + r;
                const float v = fmaxf(acc[mt][nb][r] + t2c, 0.f);
                *(unsigned short*)((char*)h1s + row * 256 + ((col * 2) ^ ((row & 15) << 4))) = f2bf(v);
            }
        }
    __syncthreads();

    // ---- max over 20 neighbors per point ----
    const int oc = t & 127, ph = t >> 7;
    float* gp = gT + (base + p0) * C_;
    #pragma unroll
    for (int pp = 0; pp < 4; ++pp) {
        const int p = ph * 4 + pp;
        float mx = 0.f;
        #pragma unroll
        for (int j = 0; j < 20; ++j) {
            const int row = p * 20 + j;
            const unsigned short us =
                *(const unsigned short*)((const char*)h1s + row * 256 + ((oc * 2) ^ ((row & 15) << 4)));
            mx = fmaxf(mx, bf2f(us));
        }
        gp[(size_t)p * C_ + oc] = mx;
    }
}

// ---------------- transpose gT [n][c] -> g [c][n] ----------------
__global__ __launch_bounds__(256) void k_transpose2(
    const float* __restrict__ gT, float* __restrict__ g)
{
    __shared__ float tile[32][33];
    const int n0 = blockIdx.x * 32, o0 = blockIdx.y * 32;
    const int iz = blockIdx.z;
    const int tx = threadIdx.x, ty = threadIdx.y;
    #pragma unroll
    for (int q = 0; q < 4; ++q) {
        const int n = n0 + ty + q * 8;
        tile[ty + q * 8][tx] = gT[((size_t)iz * N_ + n) * C_ + o0 + tx];
    }
    __syncthreads();
    #pragma unroll
    for (int q = 0; q < 4; ++q) {
        const int o = o0 + ty + q * 8;
        g[((size_t)iz * C_ + o) * N_ + n0 + tx] = tile[tx][ty + q * 8];
    }
}

// ---------------- l2 norms over N for q,k branches ----------------
__global__ __launch_bounds__(256) void k_l2norm(const float* __restrict__ g, float* __restrict__ norms)
{
    const int r = blockIdx.x;       // [0, 2*B*C)
    const float* row = g + (size_t)r * N_;
    float s = 0.f;
    for (int n = threadIdx.x; n < N_; n += 256) { const float v = row[n]; s += v * v; }
    #pragma unroll
    for (int off = 32; off > 0; off >>= 1) s += __shfl_down(s, off);
    __shared__ float red[4];
    if ((threadIdx.x & 63) == 0) red[threadIdx.x >> 6] = s;
    __syncthreads();
    if (threadIdx.x == 0)
        norms[r] = fmaxf(sqrtf(red[0] + red[1] + red[2] + red[3]), 1e-12f);
}

// ---------------- attention scores + softmax (one q-row per block) ----------------
__global__ __launch_bounds__(256) void k_attn(
    const float* __restrict__ g, const float* __restrict__ norms,
    const float* __restrict__ temp, float* __restrict__ attn)
{
    __shared__ float qs[N_];
    __shared__ float rowv[32];
    const int r = blockIdx.x;                 // b*128 + h*32 + c
    const int c = r & 31, h = (r >> 5) & 3, b = r >> 7;
    const float* qrow  = g + ((size_t)(0 * B_ + b) * C_ + h * 32 + c) * N_;
    const float* krows = g + ((size_t)(1 * B_ + b) * C_ + h * 32) * N_;
    for (int n = threadIdx.x; n < N_; n += 256) qs[n] = qrow[n];
    __syncthreads();
    const int d = threadIdx.x >> 3, s = threadIdx.x & 7;
    const float* kr = krows + (size_t)d * N_;
    float acc = 0.f;
    for (int m = 0; m < N_ / 32; ++m) {
        const int n = (m * 8 + s) * 4;
        const float4 kv = *(const float4*)(kr + n);
        acc += qs[n] * kv.x + qs[n+1] * kv.y + qs[n+2] * kv.z + qs[n+3] * kv.w;
    }
    #pragma unroll
    for (int off = 1; off < 8; off <<= 1) acc += __shfl_xor(acc, off);
    if (s == 0) rowv[d] = acc;
    __syncthreads();
    if (threadIdx.x < 32) {
        const int dd = threadIdx.x;
        const float nq = norms[(size_t)(0 * B_ + b) * C_ + h * 32 + c];
        const float nk = norms[(size_t)(1 * B_ + b) * C_ + h * 32 + dd];
        const float v = rowv[dd] / (nq * nk) * temp[h];
        float mx = v;
        #pragma unroll
        for (int off = 1; off < 32; off <<= 1) mx = fmaxf(mx, __shfl_xor(mx, off));
        const float e = expf(v - mx);
        float sm = e;
        #pragma unroll
        for (int off = 1; off < 32; off <<= 1) sm += __shfl_xor(sm, off);
        attn[(size_t)r * 32 + dd] = e / sm;
    }
}

// ---------------- attn @ v ----------------
__global__ __launch_bounds__(256) void k_av(
    const float* __restrict__ attn, const float* __restrict__ g, float* __restrict__ av)
{
    __shared__ float at[32][32];
    const int n = blockIdx.x * 256 + threadIdx.x;
    const int h = blockIdx.y, b = blockIdx.z;
    for (int t2 = threadIdx.x; t2 < 1024; t2 += 256)
        at[t2 >> 5][t2 & 31] = attn[((size_t)(b * H_ + h)) * 1024 + t2];
    __syncthreads();
    const float* vrows = g + ((size_t)(2 * B_ + b) * C_ + h * 32) * N_;
    float acc[32] = {};
    for (int dd = 0; dd < 32; ++dd) {
        const float vv = vrows[(size_t)dd * N_ + n];
        #pragma unroll
        for (int cc = 0; cc < 32; ++cc) acc[cc] += at[cc][dd] * vv;
    }
    float* avb = av + ((size_t)b * C_ + h * 32) * N_ + n;
    #pragma unroll
    for (int cc = 0; cc < 32; ++cc) avb[(size_t)cc * N_] = acc[cc];
}

// ---------------- projection + bias + residual ----------------
__global__ __launch_bounds__(256) void k_proj(
    const float* __restrict__ av, const float* __restrict__ pW, const float* __restrict__ pb,
    const float* __restrict__ x, float* __restrict__ out)
{
    __shared__ float Ws[8][C_];
    const int n = blockIdx.x * 256 + threadIdx.x;
    const int o0 = blockIdx.y * 8;
    const int b = blockIdx.z;
    for (int t = threadIdx.x; t < 8 * C_; t += 256) {
        const int j = t >> 7, c = t & 127;
        Ws[j][c] = pW[(size_t)(o0 + j) * C_ + c];
    }
    __syncthreads();
    float acc[8] = {};
    const float* ab = av + ((size_t)b * C_) * N_ + n;
    #pragma unroll 4
    for (int c = 0; c < C_; ++c) {
        const float vv = ab[(size_t)c * N_];
        #pragma unroll
        for (int j = 0; j < 8; ++j) acc[j] += Ws[j][c] * vv;
    }
    #pragma unroll
    for (int j = 0; j < 8; ++j) {
        const int o = o0 + j;
        const size_t off = ((size_t)b * C_ + o) * N_ + n;
        out[off] = acc[j] + pb[o] + x[off];
    }
}

extern "C" void kernel_launch(void* const* d_in, const int* in_sizes, int n_in,
                              void* d_out, int out_size, void* d_ws, size_t ws_size,
                              hipStream_t stream)
{
    const float* x    = (const float*)d_in[0];
    const float* fW   = (const float*)d_in[1];
    const float* fb   = (const float*)d_in[2];
    const float* fg   = (const float*)d_in[3];
    const float* fbe  = (const float*)d_in[4];
    const float* gW1  = (const float*)d_in[5];
    const float* gb1  = (const float*)d_in[6];
    const float* gg1  = (const float*)d_in[7];
    const float* gbe1 = (const float*)d_in[8];
    const float* gW2  = (const float*)d_in[9];
    const float* gb2  = (const float*)d_in[10];
    const float* gg2  = (const float*)d_in[11];
    const float* gbe2 = (const float*)d_in[12];
    const float* pW   = (const float*)d_in[13];
    const float* pb   = (const float*)d_in[14];
    const float* temp = (const float*)d_in[15];
    float* ws = (float*)d_ws;

    float* arena = ws;                 // Y pre-knn / 4 pd buffers / P',Q',GT,AV
    float* y    = ws + OFF_Y;
    unsigned short* Pb = (unsigned short*)(ws + OFF_P);
    unsigned short* Qb = (unsigned short*)(ws + OFF_Q);
    float* gT   = ws + OFF_GT;
    float* av   = ws + OFF_AV;
    float* sc   = ws + OFF_SC;
    float* sh   = ws + OFF_SH;
    float* xx   = ws + OFF_XX;
    int*   idxb = (int*)(ws + OFF_IDX);
    float* g    = ws + OFF_G;
    float* nrm  = ws + OFF_NRM;
    float* attn = ws + OFF_ATT;
    unsigned short* W2b = (unsigned short*)(ws + OFF_W2B);
    unsigned short* PWh = (unsigned short*)(ws + OFF_PWH);
    unsigned short* PWl = (unsigned short*)(ws + OFF_PWL);
    unsigned short* QWh = (unsigned short*)(ws + OFF_QWH);
    unsigned short* QWl = (unsigned short*)(ws + OFF_QWL);
    // bf16 hi/lo feature planes live in the (not-yet-written) OFF_G region
    unsigned short* fH = (unsigned short*)g;
    unsigned short* fL = fH + (size_t)12 * N_ * C_;

    k_filter_conv<<<dim3(N_/256, C_/8, 12), 256, 0, stream>>>(x, fW, fb, y);
    k_prep<<<3, 256, 0, stream>>>(gW2, gg2, gW1, W2b, PWh, PWl, QWh, QWl);
    k_rowstats<<<12 * C_, 256, 0, stream>>>(y, fg, fbe, sc, sh);
    k_norm_transpose<<<dim3(N_/32, C_/32, 12), dim3(32, 8), 0, stream>>>(y, sc, sh, fH, fL);
    k_xx<<<(12 * N_) / 256, 256, 0, stream>>>(fH, fL, xx);
    for (int g4 = 0; g4 < 3; ++g4) {   // 4-wide batched knn (Y is dead now)
        k_pd_mfma<<<dim3(N_/64, N_/64, 4), 256, 0, stream>>>(fH, fL, xx, arena, g4 * 4);
        k_topk<<<dim3(N_/4, 4), 256, 0, stream>>>(arena, idxb, g4 * 4);
    }
    k_pq_mfma<<<dim3(N_/64, 4, 12), 256, 0, stream>>>(fH, fL, PWh, PWl, QWh, QWl,
                                                      gg1, gb1, gbe1, Pb, Qb);
    k_edge2<<<dim3(N_/8, B_, 3), 256, 0, stream>>>(Pb, Qb, idxb, W2b,
                                                   gg2, gb2, gbe2, gT);
    k_transpose2<<<dim3(N_/32, C_/32, 12), dim3(32, 8), 0, stream>>>(gT, g);
    k_l2norm<<<2 * B_ * C_, 256, 0, stream>>>(g, nrm);
    k_attn<<<B_ * H_ * 32, 256, 0, stream>>>(g, nrm, temp, attn);
    k_av<<<dim3(N_/256, H_, B_), 256, 0, stream>>>(attn, g, av);
    k_proj<<<dim3(N_/256, C_/8, B_), 256, 0, stream>>>(av, pW, pb, x, (float*)d_out);
    (void)in_sizes; (void)n_in; (void)out_size; (void)ws_size;
}

// Round 12
// 434.189 us; speedup vs baseline: 2.9539x; 1.0033x over previous
//
#include <hip/hip_runtime.h>
#include <math.h>

// R11 resubmit (4th attempt): R8 source unchanged — rounds 9-11 were GPU
// acquisition timeouts (broker at capacity), no kernel signal. Change under
// test remains k_edge2's in-register per-point max epilogue (static two-target
// fold over C/D fragment layout + shfl_xor(16/32) butterfly + direct gT
// store), dropping 2 barriers and all h2 LDS traffic. Rest identical to R7
// (absmax 0.03125, 435.6us).

#define B_ 4
#define C_ 128
#define N_ 2048
#define H_ 4
#define K_ 20

typedef __bf16 bf16x8 __attribute__((ext_vector_type(8)));
typedef float f32x4 __attribute__((ext_vector_type(4)));
typedef unsigned int u32x4 __attribute__((ext_vector_type(4)));

__device__ __forceinline__ unsigned short f2bf(float f) {
    unsigned int u = __builtin_bit_cast(unsigned int, f);
    u += 0x7fffu + ((u >> 16) & 1u);       // RNE
    return (unsigned short)(u >> 16);
}
__device__ __forceinline__ float bf2f(unsigned short s) {
    return __builtin_bit_cast(float, (unsigned int)s << 16);
}
__device__ __forceinline__ float bflo(unsigned int u) {   // low bf16 of pair
    return __builtin_bit_cast(float, u << 16);
}
__device__ __forceinline__ float bfhi(unsigned int u) {   // high bf16 of pair
    return __builtin_bit_cast(float, u & 0xFFFF0000u);
}

// ---- workspace layout (float offsets) ----
// ARENA [0, 16777216): Y pre-knn | 4 pd buffers during knn | P',Q',GT,AV after.
#define PD_STRIDE 4194304
#define OFF_Y     0
#define OFF_P     0          // u16 [3B][N][C] = 1572864 floats
#define OFF_Q     1572864    // u16 [3B][N][C]
#define OFF_GT    6291456
#define OFF_AV    9437184
#define OFF_SC    19922944   // 1536
#define OFF_SH    19924480   // 1536
#define OFF_XX    19926016   // 24576
#define OFF_IDX   19950592   // 3*B*N*K ints (491520)
#define OFF_G     20442112   // 3145728: fH/fL bf16 planes during knn, g after
#define OFF_NRM   23587840   // 1024
#define OFF_ATT   23588864   // 16384
#define OFF_W2B   23605248   // u16 [3][128][128] W2*s2 bf16 (24576 floats)
#define OFF_PWH   23629824   // u16 [3][128][128] (W1a+W1b) hi
#define OFF_PWL   23654400   // lo
#define OFF_QWH   23678976   // (-W1b) hi
#define OFF_QWL   23703552   // lo
// total = 23,728,128 floats = 94.9 MB

// ---------------- filter: 1x1 conv ----------------
__global__ __launch_bounds__(256) void k_filter_conv(
    const float* __restrict__ x, const float* __restrict__ fW,
    const float* __restrict__ fb, float* __restrict__ y)
{
    __shared__ float Ws[8][C_];
    const int n = blockIdx.x * 256 + threadIdx.x;
    const int o0 = blockIdx.y * 8;
    const int iz = blockIdx.z;                 // i*B + b
    const int i = iz >> 2, b = iz & 3;
    for (int t = threadIdx.x; t < 8 * C_; t += 256) {
        const int j = t >> 7, c = t & 127;
        Ws[j][c] = fW[((size_t)i * C_ + o0 + j) * C_ + c];
    }
    __syncthreads();
    float acc[8] = {};
    const float* xb = x + ((size_t)b * C_) * N_ + n;
    #pragma unroll 4
    for (int c = 0; c < C_; ++c) {
        const float xv = xb[(size_t)c * N_];
        #pragma unroll
        for (int j = 0; j < 8; ++j) acc[j] += Ws[j][c] * xv;
    }
    float* yb = y + ((size_t)iz * C_ + o0) * N_ + n;
    #pragma unroll
    for (int j = 0; j < 8; ++j) yb[(size_t)j * N_] = acc[j] + fb[i * C_ + o0 + j];
}

// ---------------- weight prep: W2*s2 -> bf16; W1 combos -> hi/lo bf16 ----------------
__global__ __launch_bounds__(256) void k_prep(
    const float* __restrict__ gW2, const float* __restrict__ gg2,
    const float* __restrict__ gW1,
    unsigned short* __restrict__ W2b,
    unsigned short* __restrict__ PWh, unsigned short* __restrict__ PWl,
    unsigned short* __restrict__ QWh, unsigned short* __restrict__ QWl)
{
    const int i = blockIdx.x;
    const float bn = sqrtf(1.00001f);
    for (int id = threadIdx.x; id < 4096; id += 256) {
        const int o = id >> 5, c4 = (id & 31) * 4;
        const size_t eo = (size_t)i * C_ * C_ + o * C_ + c4;
        {   // W2 * s2
            const float s2 = gg2[i * C_ + o] / bn;
            const float4 wv = *(const float4*)(gW2 + ((size_t)i * C_ + o) * C_ + c4);
            uint2 pk;
            pk.x = (unsigned int)f2bf(wv.x * s2) | ((unsigned int)f2bf(wv.y * s2) << 16);
            pk.y = (unsigned int)f2bf(wv.z * s2) | ((unsigned int)f2bf(wv.w * s2) << 16);
            *(uint2*)(W2b + eo) = pk;
        }
        {   // W1 combos split hi/lo
            const float* wrow = gW1 + ((size_t)i * C_ + o) * (2 * C_);
            const float4 wa = *(const float4*)(wrow + c4);
            const float4 wb = *(const float4*)(wrow + C_ + c4);
            const float pv[4] = {wa.x + wb.x, wa.y + wb.y, wa.z + wb.z, wa.w + wb.w};
            const float qv[4] = {-wb.x, -wb.y, -wb.z, -wb.w};
            unsigned short ph[4], pl[4], qh[4], ql[4];
            #pragma unroll
            for (int e = 0; e < 4; ++e) {
                ph[e] = f2bf(pv[e]); pl[e] = f2bf(pv[e] - bf2f(ph[e]));
                qh[e] = f2bf(qv[e]); ql[e] = f2bf(qv[e] - bf2f(qh[e]));
            }
            *(uint2*)(PWh + eo) = (uint2){(unsigned int)ph[0] | ((unsigned int)ph[1] << 16),
                                          (unsigned int)ph[2] | ((unsigned int)ph[3] << 16)};
            *(uint2*)(PWl + eo) = (uint2){(unsigned int)pl[0] | ((unsigned int)pl[1] << 16),
                                          (unsigned int)pl[2] | ((unsigned int)pl[3] << 16)};
            *(uint2*)(QWh + eo) = (uint2){(unsigned int)qh[0] | ((unsigned int)qh[1] << 16),
                                          (unsigned int)qh[2] | ((unsigned int)qh[3] << 16)};
            *(uint2*)(QWl + eo) = (uint2){(unsigned int)ql[0] | ((unsigned int)ql[1] << 16),
                                          (unsigned int)ql[2] | ((unsigned int)ql[3] << 16)};
        }
    }
}

// ---------------- instance-norm row stats ----------------
__global__ __launch_bounds__(256) void k_rowstats(
    const float* __restrict__ y, const float* __restrict__ fg,
    const float* __restrict__ fbe, float* __restrict__ scale, float* __restrict__ shift)
{
    const int r = blockIdx.x;                  // (i*B+b)*C + o
    const int i = r >> 9, o = r & 127;
    const float* row = y + (size_t)r * N_;
    float s = 0.f, ss = 0.f;
    for (int n = threadIdx.x; n < N_; n += 256) {
        const float v = row[n];
        s += v; ss += v * v;
    }
    #pragma unroll
    for (int off = 32; off > 0; off >>= 1) {
        s += __shfl_down(s, off);
        ss += __shfl_down(ss, off);
    }
    __shared__ float red[2][4];
    const int wid = threadIdx.x >> 6;
    if ((threadIdx.x & 63) == 0) { red[0][wid] = s; red[1][wid] = ss; }
    __syncthreads();
    if (threadIdx.x == 0) {
        s = red[0][0] + red[0][1] + red[0][2] + red[0][3];
        ss = red[1][0] + red[1][1] + red[1][2] + red[1][3];
        const float mean = s * (1.f / N_);
        const float var = ss * (1.f / N_) - mean * mean;
        const float bn = sqrtf(1.00001f);
        const float sc = fg[i * C_ + o] / (bn * sqrtf(var + 1e-3f));
        scale[r] = sc;
        shift[r] = fbe[i * C_ + o] - mean * sc;
    }
}

// ------- normalize + relu + transpose to [n][c]; emit bf16 hi/lo planes -------
__global__ __launch_bounds__(256) void k_norm_transpose(
    const float* __restrict__ y, const float* __restrict__ scale,
    const float* __restrict__ shift,
    unsigned short* __restrict__ fH, unsigned short* __restrict__ fL)
{
    __shared__ float tile[32][33];
    const int n0 = blockIdx.x * 32, o0 = blockIdx.y * 32;
    const int iz = blockIdx.z;
    const int tx = threadIdx.x, ty = threadIdx.y;
    #pragma unroll
    for (int q = 0; q < 4; ++q) {
        const int o = o0 + ty + q * 8;
        const int r = iz * C_ + o;
        const float v = y[(size_t)r * N_ + n0 + tx] * scale[r] + shift[r];
        tile[ty + q * 8][tx] = fmaxf(v, 0.f);
    }
    __syncthreads();
    #pragma unroll
    for (int q = 0; q < 4; ++q) {
        const int n = n0 + ty + q * 8;
        const size_t idx = ((size_t)iz * N_ + n) * C_ + o0 + tx;
        const float v = tile[tx][ty + q * 8];
        const unsigned short hi = f2bf(v);
        fH[idx] = hi;
        fL[idx] = f2bf(v - bf2f(hi));
    }
}

// ---------------- per-point squared norm (from hi/lo planes) ----------------
__global__ __launch_bounds__(256) void k_xx(
    const unsigned short* __restrict__ fH, const unsigned short* __restrict__ fL,
    float* __restrict__ xx)
{
    const int r = blockIdx.x * 256 + threadIdx.x;   // [0, 3*B*N)
    const u32x4* rh = (const u32x4*)(fH + (size_t)r * C_);
    const u32x4* rl = (const u32x4*)(fL + (size_t)r * C_);
    float s = 0.f;
    #pragma unroll
    for (int q = 0; q < 16; ++q) {
        const u32x4 hv = rh[q], lv = rl[q];
        #pragma unroll
        for (int e = 0; e < 4; ++e) {
            const float v0 = bflo(hv[e]) + bflo(lv[e]);
            const float v1 = bfhi(hv[e]) + bfhi(lv[e]);
            s += v0 * v0 + v1 * v1;
        }
    }
    xx[r] = s;
}

// ------- pairwise -dist^2 via split-bf16 MFMA; z = buffer slot (ib = ib0+z) -------
__global__ __launch_bounds__(256) void k_pd_mfma(
    const unsigned short* __restrict__ fH, const unsigned short* __restrict__ fL,
    const float* __restrict__ xx, float* __restrict__ pdarena, int ib0)
{
    __shared__ __align__(16) unsigned short Ah[64 * C_], Al[64 * C_];
    __shared__ __align__(16) unsigned short Bh[64 * C_], Bl[64 * C_];
    const int j = blockIdx.z, ib = ib0 + j;
    const unsigned short* fHb = fH + (size_t)ib * N_ * C_;
    const unsigned short* fLb = fL + (size_t)ib * N_ * C_;
    const float* xxb = xx + ib * N_;
    float* pd = pdarena + (size_t)j * PD_STRIDE;
    const int n0 = blockIdx.x * 64, m0 = blockIdx.y * 64;
    const int t = threadIdx.x;
    {   // stage 4 bf16 planes (swizzle: byte ^= (row&15)<<4, bijective in 256B row)
        const int s = t & 15, rb = t >> 4;
        #pragma unroll
        for (int q = 0; q < 4; ++q) {
            const int r = rb + q * 16;
            const int ld = r * 256 + ((s * 16) ^ ((r & 15) << 4));
            *(u32x4*)((char*)Ah + ld) = *(const u32x4*)((const char*)fHb + (size_t)(n0 + r) * 256 + s * 16);
            *(u32x4*)((char*)Al + ld) = *(const u32x4*)((const char*)fLb + (size_t)(n0 + r) * 256 + s * 16);
            *(u32x4*)((char*)Bh + ld) = *(const u32x4*)((const char*)fHb + (size_t)(m0 + r) * 256 + s * 16);
            *(u32x4*)((char*)Bl + ld) = *(const u32x4*)((const char*)fLb + (size_t)(m0 + r) * 256 + s * 16);
        }
    }
    __syncthreads();
    const int lane = t & 63, w = t >> 6;       // wave w owns rows [w*16, w*16+16)
    const int lr = lane & 15, lg = lane >> 4;
    f32x4 acc[4];
    #pragma unroll
    for (int ct = 0; ct < 4; ++ct) acc[ct] = (f32x4){0.f, 0.f, 0.f, 0.f};
    #pragma unroll
    for (int ks = 0; ks < 4; ++ks) {           // K = 128, 32 per MFMA
        const int arow = w * 16 + lr;
        const int cb = ks * 64 + lg * 16;      // byte col within 256B row
        const bf16x8 ah = __builtin_bit_cast(bf16x8,
            *(const u32x4*)((const char*)Ah + arow * 256 + (cb ^ ((arow & 15) << 4))));
        const bf16x8 al = __builtin_bit_cast(bf16x8,
            *(const u32x4*)((const char*)Al + arow * 256 + (cb ^ ((arow & 15) << 4))));
        #pragma unroll
        for (int ct = 0; ct < 4; ++ct) {
            const int brow = ct * 16 + lr;
            const int boff = brow * 256 + (cb ^ ((brow & 15) << 4));
            const bf16x8 bh = __builtin_bit_cast(bf16x8, *(const u32x4*)((const char*)Bh + boff));
            const bf16x8 bl = __builtin_bit_cast(bf16x8, *(const u32x4*)((const char*)Bl + boff));
            acc[ct] = __builtin_amdgcn_mfma_f32_16x16x32_bf16(ah, bh, acc[ct], 0, 0, 0);
            acc[ct] = __builtin_amdgcn_mfma_f32_16x16x32_bf16(ah, bl, acc[ct], 0, 0, 0);
            acc[ct] = __builtin_amdgcn_mfma_f32_16x16x32_bf16(al, bh, acc[ct], 0, 0, 0);
        }
    }
    // epilogue: D col=lane&15, row=(lane>>4)*4+r  (m89/m91-verified mapping)
    #pragma unroll
    for (int ct = 0; ct < 4; ++ct) {
        const int m = m0 + ct * 16 + lr;
        const float xm = xxb[m];
        #pragma unroll
        for (int r = 0; r < 4; ++r) {
            const int n = n0 + w * 16 + lg * 4 + r;
            pd[(size_t)n * N_ + m] = 2.f * acc[ct][r] - xxb[n] - xm;
        }
    }
}

// ------- top-K=20 per row: hierarchical argmax, one wave per row -------
__global__ __launch_bounds__(256) void k_topk(
    const float* __restrict__ pdarena, int* __restrict__ idxb, int ib0)
{
    const int jbuf = blockIdx.y;
    const float* pd = pdarena + (size_t)jbuf * PD_STRIDE;
    const int lane = threadIdx.x & 63;
    const int n = blockIdx.x * 4 + (threadIdx.x >> 6);
    int* out = idxb + ((size_t)(ib0 + jbuf) * N_ + n) * K_;
    const float* row = pd + (size_t)n * N_;
    const int ibase = lane * 32;
    float v[32];
    #pragma unroll
    for (int q = 0; q < 8; ++q) {
        const float4 vv = *(const float4*)(row + ibase + q * 4);
        v[q*4+0] = vv.x; v[q*4+1] = vv.y; v[q*4+2] = vv.z; v[q*4+3] = vv.w;
    }
    float gv[8]; int gi[8];
    #pragma unroll
    for (int k = 0; k < 8; ++k) {       // strict > ascending keeps lowest idx on tie
        float b = v[k*4]; int bi = ibase + k*4;
        #pragma unroll
        for (int e = 1; e < 4; ++e)
            if (v[k*4+e] > b) { b = v[k*4+e]; bi = ibase + k*4 + e; }
        gv[k] = b; gi[k] = bi;
    }
    for (int it = 0; it < K_; ++it) {
        float best = gv[0]; int bidx = gi[0];
        #pragma unroll
        for (int k = 1; k < 8; ++k)
            if (gv[k] > best) { best = gv[k]; bidx = gi[k]; }
        #pragma unroll
        for (int off = 1; off < 64; off <<= 1) {
            const float ov = __shfl_xor(best, off);
            const int   oi = __shfl_xor(bidx, off);
            if (ov > best || (ov == best && oi < bidx)) { best = ov; bidx = oi; }
        }
        if (lane == 0) out[it] = bidx;
        const int bm = __builtin_amdgcn_readfirstlane(bidx);   // wave-uniform -> SGPR
        const int owner = bm >> 5;        // scalar: owning lane
        const int jj = bm & 31;           // scalar: element within lane
        #pragma unroll
        for (int k = 0; k < 8; ++k) if (k == (jj >> 2)) {      // scalar branch
            #pragma unroll
            for (int e = 0; e < 4; ++e) if ((k*4 + e) == jj)   // scalar branch
                v[k*4+e] = (lane == owner) ? -3e38f : v[k*4+e];
            float b = v[k*4]; int bi = ibase + k*4;            // recompute group k
            #pragma unroll
            for (int e = 1; e < 4; ++e)
                if (v[k*4+e] > b) { b = v[k*4+e]; bi = ibase + k*4 + e; }
            gv[k] = b; gi[k] = bi;
        }
    }
}

// ------- P/Q GEMMs via split-bf16 MFMA; emits bf16 P'=P*s1+t1, Q'=Q*s1 -------
__global__ __launch_bounds__(256) void k_pq_mfma(
    const unsigned short* __restrict__ fH, const unsigned short* __restrict__ fL,
    const unsigned short* __restrict__ PWh, const unsigned short* __restrict__ PWl,
    const unsigned short* __restrict__ QWh, const unsigned short* __restrict__ QWl,
    const float* __restrict__ gg1, const float* __restrict__ gb1,
    const float* __restrict__ gbe1,
    unsigned short* __restrict__ Pb, unsigned short* __restrict__ Qb)
{
    __shared__ __align__(16) unsigned short Ah[64 * C_], Al[64 * C_];
    __shared__ __align__(16) unsigned short Bh[64 * C_], Bl[64 * C_];
    const int iz = blockIdx.z, i = iz >> 2;
    const int n0 = blockIdx.x * 64;
    const int yt = blockIdx.y;           // 0,1 -> P col-halves; 2,3 -> Q col-halves
    const bool isQ = (yt >= 2);
    const int oc0 = (yt & 1) * 64;
    const int t = threadIdx.x;
    const unsigned short* fHb = fH + (size_t)iz * N_ * C_;
    const unsigned short* fLb = fL + (size_t)iz * N_ * C_;
    const unsigned short* Wh = (isQ ? QWh : PWh) + (size_t)i * C_ * C_;
    const unsigned short* Wl = (isQ ? QWl : PWl) + (size_t)i * C_ * C_;
    {   // A: copy hi/lo feature planes; B: copy pre-split weight planes
        const int s = t & 15, rb = t >> 4;
        #pragma unroll
        for (int q = 0; q < 4; ++q) {
            const int r = rb + q * 16;
            const int ld = r * 256 + ((s * 16) ^ ((r & 15) << 4));
            *(u32x4*)((char*)Ah + ld) = *(const u32x4*)((const char*)fHb + (size_t)(n0 + r) * 256 + s * 16);
            *(u32x4*)((char*)Al + ld) = *(const u32x4*)((const char*)fLb + (size_t)(n0 + r) * 256 + s * 16);
            *(u32x4*)((char*)Bh + ld) = *(const u32x4*)((const char*)(Wh + (size_t)(oc0 + r) * C_) + s * 16);
            *(u32x4*)((char*)Bl + ld) = *(const u32x4*)((const char*)(Wl + (size_t)(oc0 + r) * C_) + s * 16);
        }
    }
    __syncthreads();
    const int lane = t & 63, w = t >> 6;
    const int lr = lane & 15, lg = lane >> 4;
    f32x4 acc[4];
    #pragma unroll
    for (int ct = 0; ct < 4; ++ct) acc[ct] = (f32x4){0.f, 0.f, 0.f, 0.f};
    #pragma unroll
    for (int ks = 0; ks < 4; ++ks) {
        const int arow = w * 16 + lr;
        const int cb = ks * 64 + lg * 16;
        const bf16x8 ah = __builtin_bit_cast(bf16x8,
            *(const u32x4*)((const char*)Ah + arow * 256 + (cb ^ ((arow & 15) << 4))));
        const bf16x8 al = __builtin_bit_cast(bf16x8,
            *(const u32x4*)((const char*)Al + arow * 256 + (cb ^ ((arow & 15) << 4))));
        #pragma unroll
        for (int ct = 0; ct < 4; ++ct) {
            const int brow = ct * 16 + lr;
            const int boff = brow * 256 + (cb ^ ((brow & 15) << 4));
            const bf16x8 bh = __builtin_bit_cast(bf16x8, *(const u32x4*)((const char*)Bh + boff));
            const bf16x8 bl = __builtin_bit_cast(bf16x8, *(const u32x4*)((const char*)Bl + boff));
            acc[ct] = __builtin_amdgcn_mfma_f32_16x16x32_bf16(ah, bh, acc[ct], 0, 0, 0);
            acc[ct] = __builtin_amdgcn_mfma_f32_16x16x32_bf16(ah, bl, acc[ct], 0, 0, 0);
            acc[ct] = __builtin_amdgcn_mfma_f32_16x16x32_bf16(al, bh, acc[ct], 0, 0, 0);
        }
    }
    const float bn = sqrtf(1.00001f);
    unsigned short* outp = (isQ ? Qb : Pb) + (size_t)iz * N_ * C_;
    #pragma unroll
    for (int ct = 0; ct < 4; ++ct) {
        const int col = oc0 + ct * 16 + lr;
        const float s1 = gg1[i * C_ + col] / bn;
        const float t1 = isQ ? 0.f : (gb1[i * C_ + col] * s1 + gbe1[i * C_ + col]);
        #pragma unroll
        for (int r = 0; r < 4; ++r) {
            const int n = n0 + w * 16 + lg * 4 + r;
            outp[(size_t)n * C_ + col] = f2bf(acc[ct][r] * s1 + t1);
        }
    }
}

// ------- edge conv2 + max over k : in-register per-point max epilogue -------
__global__ __launch_bounds__(256, 3) void k_edge2(
    const unsigned short* __restrict__ Pb, const unsigned short* __restrict__ Qb,
    const int* __restrict__ idxb, const unsigned short* __restrict__ W2b,
    const float* __restrict__ gg2, const float* __restrict__ gb2,
    const float* __restrict__ gbe2, float* __restrict__ gT)
{
    __shared__ __align__(16) unsigned short h1s[160 * C_];  // 40 KB
    __shared__ float t2s[C_];
    __shared__ int idxs[160];
    const int i = blockIdx.z, b = blockIdx.y;
    const int pb0 = blockIdx.x * 8;
    const int t = threadIdx.x;
    const size_t base = (size_t)(i * B_ + b) * N_;

    if (t < C_) {
        const float bn = sqrtf(1.00001f);
        const float s2 = gg2[i * C_ + t] / bn;        // s2 already folded into W2b
        t2s[t] = gb2[i * C_ + t] * s2 + gbe2[i * C_ + t];
    }
    if (t < 160) idxs[t] = idxb[base * K_ + pb0 * K_ + t];
    __syncthreads();

    // ---- B-fragments: direct global->register from pre-converted W2b ----
    const int lane = t & 63, w = t >> 6;
    const int lr = lane & 15, lg = lane >> 4;
    const unsigned short* W2bi = W2b + (size_t)i * C_ * C_;
    bf16x8 Bf[2][4];
    #pragma unroll
    for (int nb = 0; nb < 2; ++nb)
        #pragma unroll
        for (int ks = 0; ks < 4; ++ks) {
            const int o = w * 32 + nb * 16 + lr;
            Bf[nb][ks] = __builtin_bit_cast(bf16x8,
                *(const u32x4*)(W2bi + (size_t)o * C_ + ks * 32 + lg * 8));
        }

    // ---- build h1 = relu(P'[n] + Q'[m]) (bf16 inputs, swizzled bf16 out) ----
    const int seg = t & 7;            // 16-element column segment
    const int rb = t >> 3;
    const unsigned short* Pr0 = Pb + base * C_;
    const unsigned short* Qr0 = Qb + base * C_;
    #pragma unroll
    for (int it = 0; it < 5; ++it) {
        const int row = rb + 32 * it;
        const int p = row / 20;
        const int m = idxs[row];
        const u32x4* Pr = (const u32x4*)(Pr0 + (size_t)(pb0 + p) * C_ + seg * 16);
        const u32x4* Qr = (const u32x4*)(Qr0 + (size_t)m * C_ + seg * 16);
        const u32x4 pv0 = Pr[0], pv1 = Pr[1];
        const u32x4 qv0 = Qr[0], qv1 = Qr[1];
        unsigned int pk[8];
        #pragma unroll
        for (int e = 0; e < 4; ++e) {
            const float lo0 = fmaxf(bflo(pv0[e]) + bflo(qv0[e]), 0.f);
            const float hi0 = fmaxf(bfhi(pv0[e]) + bfhi(qv0[e]), 0.f);
            pk[e] = (unsigned int)f2bf(lo0) | ((unsigned int)f2bf(hi0) << 16);
            const float lo1 = fmaxf(bflo(pv1[e]) + bflo(qv1[e]), 0.f);
            const float hi1 = fmaxf(bfhi(pv1[e]) + bfhi(qv1[e]), 0.f);
            pk[e + 4] = (unsigned int)f2bf(lo1) | ((unsigned int)f2bf(hi1) << 16);
        }
        const int sw = (row & 15) << 4;
        char* bp = (char*)h1s + row * 256;
        *(u32x4*)(bp + ((seg * 32) ^ sw))      = (u32x4){pk[0], pk[1], pk[2], pk[3]};
        *(u32x4*)(bp + ((seg * 32 + 16) ^ sw)) = (u32x4){pk[4], pk[5], pk[6], pk[7]};
    }
    __syncthreads();

    // ---- MFMA: D[row][o] = sum_c h1[row][c] * W2'[o][c] ----
    f32x4 acc[10][2];
    #pragma unroll
    for (int mt = 0; mt < 10; ++mt)
        #pragma unroll
        for (int nb = 0; nb < 2; ++nb)
            acc[mt][nb] = (f32x4){0.f, 0.f, 0.f, 0.f};
    #pragma unroll
    for (int mt = 0; mt < 10; ++mt) {
        bf16x8 Af[4];
        #pragma unroll
        for (int ks = 0; ks < 4; ++ks) {
            const int row = mt * 16 + lr;
            const int cb = ks * 64 + lg * 16;
            Af[ks] = __builtin_bit_cast(bf16x8,
                *(const u32x4*)((const char*)h1s + row * 256 + (cb ^ ((row & 15) << 4))));
        }
        #pragma unroll
        for (int nb = 0; nb < 2; ++nb)
            #pragma unroll
            for (int ks = 0; ks < 4; ++ks)
                acc[mt][nb] = __builtin_amdgcn_mfma_f32_16x16x32_bf16(
                    Af[ks], Bf[nb][ks], acc[mt][nb], 0, 0, 0);
    }

    // ---- in-register epilogue: +t2, relu(0-init), per-point max ----
    // acc[mt][nb][e] holds row = mt*16 + lg*4 + e, col = w*32 + nb*16 + lr.
    // Point p owns rows [20p, 20p+20). For each (mt,e) the 4 lg-lanes span
    // rows rlo..rlo+12, touching at most two points pa, pa+1 (compile-time).
    const float t2a = t2s[w * 32 + lr];
    const float t2b = t2s[w * 32 + 16 + lr];
    float pmax[8][2];
    #pragma unroll
    for (int p = 0; p < 8; ++p) { pmax[p][0] = 0.f; pmax[p][1] = 0.f; }
    #pragma unroll
    for (int mt = 0; mt < 10; ++mt) {
        #pragma unroll
        for (int e = 0; e < 4; ++e) {
            const int rlo = mt * 16 + e;              // lg = 0 row
            const int pa = rlo / 20;                  // compile-time
            const int pz = (rlo + 12) / 20;           // compile-time
            const float v0 = acc[mt][0][e] + t2a;
            const float v1 = acc[mt][1][e] + t2b;
            if (pa == pz) {
                pmax[pa][0] = fmaxf(pmax[pa][0], v0);
                pmax[pa][1] = fmaxf(pmax[pa][1], v1);
            } else {
                const bool in1 = (mt * 16 + lg * 4 + e) >= pz * 20;
                pmax[pa][0] = in1 ? pmax[pa][0] : fmaxf(pmax[pa][0], v0);
                pmax[pa][1] = in1 ? pmax[pa][1] : fmaxf(pmax[pa][1], v1);
                pmax[pz][0] = in1 ? fmaxf(pmax[pz][0], v0) : pmax[pz][0];
                pmax[pz][1] = in1 ? fmaxf(pmax[pz][1], v1) : pmax[pz][1];
            }
        }
    }
    // combine the 4 lg lane-groups (lanes lr, lr+16, lr+32, lr+48)
    #pragma unroll
    for (int p = 0; p < 8; ++p)
        #pragma unroll
        for (int nb = 0; nb < 2; ++nb) {
            float m = pmax[p][nb];
            m = fmaxf(m, __shfl_xor(m, 16));
            m = fmaxf(m, __shfl_xor(m, 32));
            pmax[p][nb] = m;
        }
    if (lg == 0) {
        float* gp = gT + (base + pb0) * C_;
        #pragma unroll
        for (int p = 0; p < 8; ++p) {
            gp[(size_t)p * C_ + w * 32 + lr]      = pmax[p][0];
            gp[(size_t)p * C_ + w * 32 + 16 + lr] = pmax[p][1];
        }
    }
}

// ---------------- transpose gT [n][c] -> g [c][n] ----------------
__global__ __launch_bounds__(256) void k_transpose2(
    const float* __restrict__ gT, float* __restrict__ g)
{
    __shared__ float tile[32][33];
    const int n0 = blockIdx.x * 32, o0 = blockIdx.y * 32;
    const int iz = blockIdx.z;
    const int tx = threadIdx.x, ty = threadIdx.y;
    #pragma unroll
    for (int q = 0; q < 4; ++q) {
        const int n = n0 + ty + q * 8;
        tile[ty + q * 8][tx] = gT[((size_t)iz * N_ + n) * C_ + o0 + tx];
    }
    __syncthreads();
    #pragma unroll
    for (int q = 0; q < 4; ++q) {
        const int o = o0 + ty + q * 8;
        g[((size_t)iz * C_ + o) * N_ + n0 + tx] = tile[tx][ty + q * 8];
    }
}

// ---------------- l2 norms over N for q,k branches ----------------
__global__ __launch_bounds__(256) void k_l2norm(const float* __restrict__ g, float* __restrict__ norms)
{
    const int r = blockIdx.x;       // [0, 2*B*C)
    const float* row = g + (size_t)r * N_;
    float s = 0.f;
    for (int n = threadIdx.x; n < N_; n += 256) { const float v = row[n]; s += v * v; }
    #pragma unroll
    for (int off = 32; off > 0; off >>= 1) s += __shfl_down(s, off);
    __shared__ float red[4];
    if ((threadIdx.x & 63) == 0) red[threadIdx.x >> 6] = s;
    __syncthreads();
    if (threadIdx.x == 0)
        norms[r] = fmaxf(sqrtf(red[0] + red[1] + red[2] + red[3]), 1e-12f);
}

// ---------------- attention scores + softmax (one q-row per block) ----------------
__global__ __launch_bounds__(256) void k_attn(
    const float* __restrict__ g, const float* __restrict__ norms,
    const float* __restrict__ temp, float* __restrict__ attn)
{
    __shared__ float qs[N_];
    __shared__ float rowv[32];
    const int r = blockIdx.x;                 // b*128 + h*32 + c
    const int c = r & 31, h = (r >> 5) & 3, b = r >> 7;
    const float* qrow  = g + ((size_t)(0 * B_ + b) * C_ + h * 32 + c) * N_;
    const float* krows = g + ((size_t)(1 * B_ + b) * C_ + h * 32) * N_;
    for (int n = threadIdx.x; n < N_; n += 256) qs[n] = qrow[n];
    __syncthreads();
    const int d = threadIdx.x >> 3, s = threadIdx.x & 7;
    const float* kr = krows + (size_t)d * N_;
    float acc = 0.f;
    for (int m = 0; m < N_ / 32; ++m) {
        const int n = (m * 8 + s) * 4;
        const float4 kv = *(const float4*)(kr + n);
        acc += qs[n] * kv.x + qs[n+1] * kv.y + qs[n+2] * kv.z + qs[n+3] * kv.w;
    }
    #pragma unroll
    for (int off = 1; off < 8; off <<= 1) acc += __shfl_xor(acc, off);
    if (s == 0) rowv[d] = acc;
    __syncthreads();
    if (threadIdx.x < 32) {
        const int dd = threadIdx.x;
        const float nq = norms[(size_t)(0 * B_ + b) * C_ + h * 32 + c];
        const float nk = norms[(size_t)(1 * B_ + b) * C_ + h * 32 + dd];
        const float v = rowv[dd] / (nq * nk) * temp[h];
        float mx = v;
        #pragma unroll
        for (int off = 1; off < 32; off <<= 1) mx = fmaxf(mx, __shfl_xor(mx, off));
        const float e = expf(v - mx);
        float sm = e;
        #pragma unroll
        for (int off = 1; off < 32; off <<= 1) sm += __shfl_xor(sm, off);
        attn[(size_t)r * 32 + dd] = e / sm;
    }
}

// ---------------- attn @ v ----------------
__global__ __launch_bounds__(256) void k_av(
    const float* __restrict__ attn, const float* __restrict__ g, float* __restrict__ av)
{
    __shared__ float at[32][32];
    const int n = blockIdx.x * 256 + threadIdx.x;
    const int h = blockIdx.y, b = blockIdx.z;
    for (int t2 = threadIdx.x; t2 < 1024; t2 += 256)
        at[t2 >> 5][t2 & 31] = attn[((size_t)(b * H_ + h)) * 1024 + t2];
    __syncthreads();
    const float* vrows = g + ((size_t)(2 * B_ + b) * C_ + h * 32) * N_;
    float acc[32] = {};
    for (int dd = 0; dd < 32; ++dd) {
        const float vv = vrows[(size_t)dd * N_ + n];
        #pragma unroll
        for (int cc = 0; cc < 32; ++cc) acc[cc] += at[cc][dd] * vv;
    }
    float* avb = av + ((size_t)b * C_ + h * 32) * N_ + n;
    #pragma unroll
    for (int cc = 0; cc < 32; ++cc) avb[(size_t)cc * N_] = acc[cc];
}

// ---------------- projection + bias + residual ----------------
__global__ __launch_bounds__(256) void k_proj(
    const float* __restrict__ av, const float* __restrict__ pW, const float* __restrict__ pb,
    const float* __restrict__ x, float* __restrict__ out)
{
    __shared__ float Ws[8][C_];
    const int n = blockIdx.x * 256 + threadIdx.x;
    const int o0 = blockIdx.y * 8;
    const int b = blockIdx.z;
    for (int t = threadIdx.x; t < 8 * C_; t += 256) {
        const int j = t >> 7, c = t & 127;
        Ws[j][c] = pW[(size_t)(o0 + j) * C_ + c];
    }
    __syncthreads();
    float acc[8] = {};
    const float* ab = av + ((size_t)b * C_) * N_ + n;
    #pragma unroll 4
    for (int c = 0; c < C_; ++c) {
        const float vv = ab[(size_t)c * N_];
        #pragma unroll
        for (int j = 0; j < 8; ++j) acc[j] += Ws[j][c] * vv;
    }
    #pragma unroll
    for (int j = 0; j < 8; ++j) {
        const int o = o0 + j;
        const size_t off = ((size_t)b * C_ + o) * N_ + n;
        out[off] = acc[j] + pb[o] + x[off];
    }
}

extern "C" void kernel_launch(void* const* d_in, const int* in_sizes, int n_in,
                              void* d_out, int out_size, void* d_ws, size_t ws_size,
                              hipStream_t stream)
{
    const float* x    = (const float*)d_in[0];
    const float* fW   = (const float*)d_in[1];
    const float* fb   = (const float*)d_in[2];
    const float* fg   = (const float*)d_in[3];
    const float* fbe  = (const float*)d_in[4];
    const float* gW1  = (const float*)d_in[5];
    const float* gb1  = (const float*)d_in[6];
    const float* gg1  = (const float*)d_in[7];
    const float* gbe1 = (const float*)d_in[8];
    const float* gW2  = (const float*)d_in[9];
    const float* gb2  = (const float*)d_in[10];
    const float* gg2  = (const float*)d_in[11];
    const float* gbe2 = (const float*)d_in[12];
    const float* pW   = (const float*)d_in[13];
    const float* pb   = (const float*)d_in[14];
    const float* temp = (const float*)d_in[15];
    float* ws = (float*)d_ws;

    float* arena = ws;                 // Y pre-knn / 4 pd buffers / P',Q',GT,AV
    float* y    = ws + OFF_Y;
    unsigned short* Pb = (unsigned short*)(ws + OFF_P);
    unsigned short* Qb = (unsigned short*)(ws + OFF_Q);
    float* gT   = ws + OFF_GT;
    float* av   = ws + OFF_AV;
    float* sc   = ws + OFF_SC;
    float* sh   = ws + OFF_SH;
    float* xx   = ws + OFF_XX;
    int*   idxb = (int*)(ws + OFF_IDX);
    float* g    = ws + OFF_G;
    float* nrm  = ws + OFF_NRM;
    float* attn = ws + OFF_ATT;
    unsigned short* W2b = (unsigned short*)(ws + OFF_W2B);
    unsigned short* PWh = (unsigned short*)(ws + OFF_PWH);
    unsigned short* PWl = (unsigned short*)(ws + OFF_PWL);
    unsigned short* QWh = (unsigned short*)(ws + OFF_QWH);
    unsigned short* QWl = (unsigned short*)(ws + OFF_QWL);
    // bf16 hi/lo feature planes live in the (not-yet-written) OFF_G region
    unsigned short* fH = (unsigned short*)g;
    unsigned short* fL = fH + (size_t)12 * N_ * C_;

    k_filter_conv<<<dim3(N_/256, C_/8, 12), 256, 0, stream>>>(x, fW, fb, y);
    k_prep<<<3, 256, 0, stream>>>(gW2, gg2, gW1, W2b, PWh, PWl, QWh, QWl);
    k_rowstats<<<12 * C_, 256, 0, stream>>>(y, fg, fbe, sc, sh);
    k_norm_transpose<<<dim3(N_/32, C_/32, 12), dim3(32, 8), 0, stream>>>(y, sc, sh, fH, fL);
    k_xx<<<(12 * N_) / 256, 256, 0, stream>>>(fH, fL, xx);
    for (int g4 = 0; g4 < 3; ++g4) {   // 4-wide batched knn (Y is dead now)
        k_pd_mfma<<<dim3(N_/64, N_/64, 4), 256, 0, stream>>>(fH, fL, xx, arena, g4 * 4);
        k_topk<<<dim3(N_/4, 4), 256, 0, stream>>>(arena, idxb, g4 * 4);
    }
    k_pq_mfma<<<dim3(N_/64, 4, 12), 256, 0, stream>>>(fH, fL, PWh, PWl, QWh, QWl,
                                                      gg1, gb1, gbe1, Pb, Qb);
    k_edge2<<<dim3(N_/8, B_, 3), 256, 0, stream>>>(Pb, Qb, idxb, W2b,
                                                   gg2, gb2, gbe2, gT);
    k_transpose2<<<dim3(N_/32, C_/32, 12), dim3(32, 8), 0, stream>>>(gT, g);
    k_l2norm<<<2 * B_ * C_, 256, 0, stream>>>(g, nrm);
    k_attn<<<B_ * H_ * 32, 256, 0, stream>>>(g, nrm, temp, attn);
    k_av<<<dim3(N_/256, H_, B_), 256, 0, stream>>>(attn, g, av);
    k_proj<<<dim3(N_/256, C_/8, B_), 256, 0, stream>>>(av, pW, pb, x, (float*)d_out);
    (void)in_sizes; (void)n_in; (void)out_size; (void)ws_size;
}